// Round 2
// baseline (2303.245 us; speedup 1.0000x reference)
//
#include <hip/hip_runtime.h>
#include <math.h>

#define B_ 4
#define N_ 2048
#define D_ 512
#define M_ 1024
#define H_ 8
#define DH_ 64
#define I_ 512
#define FF_ 1024

// ---------------- zero accumulators (must run every launch) ----------------
__global__ void zero_init_kernel(float* counts, double* commit_sum) {
  int t = threadIdx.x;
  counts[t] = 0.f;
  if (t == 0) *commit_sum = 0.0;
}

// ---------------- mask dtype detection ----------------
// jax bool may arrive as int32 (harness "integer -> int*") or as uint8.
// For int32 little-endian 0/1 values, every byte at offset i%4!=0 is 0.
// For uint8 random 0/1 mask, ~3000 of those positions are 1. P(confusion)=2^-6144.
__global__ void mask_detect_kernel(const unsigned char* __restrict__ mb, int* flag) {
  __shared__ int any;
  if (threadIdx.x == 0) any = 0;
  __syncthreads();
  int acc = 0;
  for (int i = threadIdx.x; i < 8192; i += 256)
    if (i & 3) acc |= mb[i];
  if (acc) atomicOr(&any, 1);
  __syncthreads();
  if (threadIdx.x == 0) *flag = any;
}

__global__ void mask_norm_kernel(const void* __restrict__ mraw,
                                 const int* __restrict__ flag,
                                 int* __restrict__ mnorm) {
  int i = blockIdx.x * 256 + threadIdx.x;
  int v;
  if (*flag) v = ((const unsigned char*)mraw)[i];   // uint8 layout
  else       v = ((const int*)mraw)[i];             // int32 layout
  mnorm[i] = (v != 0) ? 1 : 0;
}

// ---------------- codebook row sum-of-squares (fp64) ----------------
__global__ __launch_bounds__(128) void code_sq_kernel(const float* __restrict__ cb,
                                                      double* __restrict__ csq) {
  int row = blockIdx.x, tid = threadIdx.x;
  const float4* r4 = (const float4*)(cb + (size_t)row * D_);
  float4 v = r4[tid];
  double s = (double)v.x * v.x + (double)v.y * v.y + (double)v.z * v.z + (double)v.w * v.w;
  for (int off = 32; off; off >>= 1) s += __shfl_down(s, off);
  __shared__ double red[2];
  if ((tid & 63) == 0) red[tid >> 6] = s;
  __syncthreads();
  if (tid == 0) csq[row] = red[0] + red[1];
}

// ---------------- VQ nearest-codebook assignment ----------------
// 8 tokens/block, 16-code LDS tiles, thread = (token, code, d-half).
// dist' = ||c||^2 - 2 x.c (same argmin as expanded distance). fp64 dot so the
// argmin is exact: best-vs-2nd gaps ~20, fp32 noise ~1e-2 flipped ~5 tokens.
__global__ __launch_bounds__(256) void vq_assign_kernel(
    const float* __restrict__ flat, const float* __restrict__ cb,
    const double* __restrict__ csq, int* __restrict__ out_idx)
{
  __shared__ float xs[8 * 512];
  __shared__ float cs_[16 * 516];
  int tid = threadIdx.x;
  int t0 = blockIdx.x * 8;
  {
    const float4* src = (const float4*)(flat + ((size_t)t0 << 9));
    float4* dst = (float4*)xs;
#pragma unroll
    for (int i = 0; i < 4; i++) dst[tid + i * 256] = src[tid + i * 256];
  }
  int tt = tid >> 5;            // token 0..7
  int cc = (tid >> 1) & 15;     // code-in-tile 0..15
  int half = tid & 1;           // which 256-wide d-half
  double best = 1e300; int bestIdx = 0;
  for (int c0 = 0; c0 < M_; c0 += 16) {
    __syncthreads();
#pragma unroll
    for (int i = 0; i < 8; i++) {
      int p = tid + i * 256;           // float4 slot 0..2047
      int r = p >> 7, d4 = p & 127;
      float4 v = ((const float4*)(cb + ((size_t)(c0 + r) << 9)))[d4];
      *(float4*)(cs_ + r * 516 + (d4 << 2)) = v;
    }
    __syncthreads();
    const float4* xr4 = (const float4*)(xs + tt * 512 + half * 256);
    const float4* cr4 = (const float4*)(cs_ + cc * 516 + half * 256);
    double a0 = 0.0, a1 = 0.0, a2 = 0.0, a3 = 0.0;
#pragma unroll 8
    for (int d4 = 0; d4 < 64; d4++) {
      float4 xv = xr4[d4];
      float4 cv = cr4[d4];
      a0 += (double)xv.x * cv.x; a1 += (double)xv.y * cv.y;
      a2 += (double)xv.z * cv.z; a3 += (double)xv.w * cv.w;
    }
    double dsum = (a0 + a1) + (a2 + a3);
    dsum += __shfl_xor(dsum, 1);                  // combine d-halves
    double dist = csq[c0 + cc] - 2.0 * dsum;
    if (dist < best) { best = dist; bestIdx = c0 + cc; }
  }
  for (int off = 1; off < 32; off <<= 1) {
    double ov = __shfl_xor(best, off);
    int oi = __shfl_xor(bestIdx, off);
    if (ov < best || (ov == best && oi < bestIdx)) { best = ov; bestIdx = oi; }
  }
  if ((tid & 31) == 0) out_idx[t0 + tt] = bestIdx;
}

// ---------------- commit loss partial + histogram ----------------
__global__ __launch_bounds__(128) void commit_hist_kernel(
    const float* __restrict__ flat, const float* __restrict__ cb,
    const int* __restrict__ idx, double* __restrict__ commit_sum,
    float* __restrict__ counts)
{
  int t = blockIdx.x, tid = threadIdx.x;
  int code = idx[t];
  float4 a = ((const float4*)(flat + ((size_t)t << 9)))[tid];
  float4 c = ((const float4*)(cb + ((size_t)code << 9)))[tid];
  float dx = a.x - c.x, dy = a.y - c.y, dz = a.z - c.z, dw = a.w - c.w;
  double s = (double)dx * dx + (double)dy * dy + (double)dz * dz + (double)dw * dw;
  for (int off = 32; off; off >>= 1) s += __shfl_down(s, off);
  __shared__ double red[2];
  if ((tid & 63) == 0) red[tid >> 6] = s;
  __syncthreads();
  if (tid == 0) {
    atomicAdd(commit_sum, red[0] + red[1]);
    atomicAdd(counts + code, 1.0f);
  }
}

// ---------------- LayerNorm over rows of 512 ----------------
__global__ __launch_bounds__(256) void ln_rows_kernel(
    const float* __restrict__ x, const float* __restrict__ g,
    const float* __restrict__ b, float* __restrict__ y)
{
  int row = blockIdx.x, tid = threadIdx.x;
  const float* xr = x + (size_t)row * D_;
  float v0 = xr[tid], v1 = xr[tid + 256];
  float s = v0 + v1;
  for (int off = 32; off; off >>= 1) s += __shfl_down(s, off);
  __shared__ float red[4];
  __shared__ float bcast[2];
  if ((tid & 63) == 0) red[tid >> 6] = s;
  __syncthreads();
  if (tid == 0) bcast[0] = (red[0] + red[1] + red[2] + red[3]) * (1.f / 512.f);
  __syncthreads();
  float mu = bcast[0];
  float d0 = v0 - mu, d1 = v1 - mu;
  float q = d0 * d0 + d1 * d1;
  for (int off = 32; off; off >>= 1) q += __shfl_down(q, off);
  if ((tid & 63) == 0) red[tid >> 6] = q;
  __syncthreads();
  if (tid == 0) bcast[1] = rsqrtf((red[0] + red[1] + red[2] + red[3]) * (1.f / 512.f) + 1e-5f);
  __syncthreads();
  float rs = bcast[1];
  float* yr = y + (size_t)row * D_;
  yr[tid]       = d0 * rs * g[tid] + b[tid];
  yr[tid + 256] = d1 * rs * g[tid + 256] + b[tid + 256];
}

// ---------------- generic fp32 GEMM: C = act(scale*A@B + bias) + resid ----------------
__device__ inline float gelu_f(float x) {
  float x3 = x * x * x;
  return 0.5f * x * (1.f + tanhf(0.7978845608028654f * (x + 0.044715f * x3)));
}

__global__ __launch_bounds__(256) void gemm_kernel(
    const float* __restrict__ A, const float* __restrict__ Bm,
    const float* __restrict__ bias, const float* __restrict__ resid,
    float* __restrict__ C, int M, int N, int K, float scale, int act)
{
  __shared__ float As[16][68];
  __shared__ float Bs[16][68];
  int tid = threadIdx.x;
  int row0 = blockIdx.y << 6, col0 = blockIdx.x << 6;
  int tx = tid & 15, ty = tid >> 4;
  int ar = tid >> 2, ak = (tid & 3) << 2;
  int bk = tid >> 4, bc = (tid & 15) << 2;
  float acc[4][4] = {};
  for (int k0 = 0; k0 < K; k0 += 16) {
    __syncthreads();
    float4 av = *(const float4*)(A + (size_t)(row0 + ar) * K + k0 + ak);
    As[ak + 0][ar] = av.x; As[ak + 1][ar] = av.y;
    As[ak + 2][ar] = av.z; As[ak + 3][ar] = av.w;
    *(float4*)&Bs[bk][bc] = *(const float4*)(Bm + (size_t)(k0 + bk) * N + col0 + bc);
    __syncthreads();
#pragma unroll
    for (int k = 0; k < 16; k++) {
      float4 a4 = *(const float4*)&As[k][ty << 2];
      float4 b4 = *(const float4*)&Bs[k][tx << 2];
      acc[0][0] += a4.x * b4.x; acc[0][1] += a4.x * b4.y; acc[0][2] += a4.x * b4.z; acc[0][3] += a4.x * b4.w;
      acc[1][0] += a4.y * b4.x; acc[1][1] += a4.y * b4.y; acc[1][2] += a4.y * b4.z; acc[1][3] += a4.y * b4.w;
      acc[2][0] += a4.z * b4.x; acc[2][1] += a4.z * b4.y; acc[2][2] += a4.z * b4.z; acc[2][3] += a4.z * b4.w;
      acc[3][0] += a4.w * b4.x; acc[3][1] += a4.w * b4.y; acc[3][2] += a4.w * b4.z; acc[3][3] += a4.w * b4.w;
    }
  }
#pragma unroll
  for (int i = 0; i < 4; i++) {
    int r = row0 + (ty << 2) + i;
#pragma unroll
    for (int j = 0; j < 4; j++) {
      int c = col0 + (tx << 2) + j;
      float v = acc[i][j] * scale;
      if (bias) v += bias[c];
      if (act == 1) v = gelu_f(v);
      if (resid) v += resid[(size_t)r * N + c];
      C[(size_t)r * N + c] = v;
    }
  }
}

// ---------------- flash-style attention (online softmax) ----------------
__global__ __launch_bounds__(256) void attn_kernel(
    const float* __restrict__ Q, int q_bs, int q_stride, float q_scale,
    const float* __restrict__ KV, int kv_bs, int kv_stride, int k_off, int v_off,
    const int* __restrict__ mask, int mask_bs,
    float* __restrict__ O, int o_bs, int n_keys)
{
  __shared__ float q_s[32][68];
  __shared__ float k_s[32][68];
  __shared__ float v_s[32][68];
  __shared__ float p_s[32][33];
  __shared__ int m_s[32];
  int tid = threadIdx.x;
  int b = blockIdx.z, h = blockIdx.y, m0 = blockIdx.x << 5;
  for (int i = tid; i < 32 * 64; i += 256) {
    int r = i >> 6, d = i & 63;
    q_s[r][d] = Q[(size_t)b * q_bs + (size_t)(m0 + r) * q_stride + h * 64 + d] * q_scale;
  }
  int r = tid >> 3, g = tid & 7;
  float m_run = -3.0e38f, l_run = 0.f;
  float o_acc[8] = {0.f,0.f,0.f,0.f,0.f,0.f,0.f,0.f};
  for (int n0 = 0; n0 < n_keys; n0 += 32) {
    __syncthreads();
    for (int i = tid; i < 32 * 64; i += 256) {
      int c = i >> 6, d = i & 63;
      size_t base = (size_t)b * kv_bs + (size_t)(n0 + c) * kv_stride + h * 64 + d;
      k_s[c][d] = KV[base + k_off];
      v_s[c][d] = KV[base + v_off];
    }
    if (tid < 32) m_s[tid] = mask ? mask[(size_t)b * mask_bs + n0 + tid] : 1;
    __syncthreads();
    float s0[4];
#pragma unroll
    for (int j = 0; j < 4; j++) {
      int c = (g << 2) + j;
      const float4* qr = (const float4*)&q_s[r][0];
      const float4* kr = (const float4*)&k_s[c][0];
      float acc = 0.f;
#pragma unroll
      for (int d4 = 0; d4 < 16; d4++) {
        float4 qv = qr[d4], kv = kr[d4];
        acc += qv.x * kv.x + qv.y * kv.y + qv.z * kv.z + qv.w * kv.w;
      }
      s0[j] = m_s[c] ? acc : -3.0e38f;
    }
    float tmax = fmaxf(fmaxf(s0[0], s0[1]), fmaxf(s0[2], s0[3]));
    tmax = fmaxf(tmax, __shfl_xor(tmax, 1));
    tmax = fmaxf(tmax, __shfl_xor(tmax, 2));
    tmax = fmaxf(tmax, __shfl_xor(tmax, 4));
    float m_new = fmaxf(m_run, tmax);
    float alpha = __expf(m_run - m_new);
    float psum = 0.f;
#pragma unroll
    for (int j = 0; j < 4; j++) {
      // guard: if masked (or everything so far masked), contribute 0, not exp(0)
      float p = (s0[j] < -1.0e37f) ? 0.f : __expf(s0[j] - m_new);
      p_s[r][(g << 2) + j] = p;
      psum += p;
    }
    psum += __shfl_xor(psum, 1);
    psum += __shfl_xor(psum, 2);
    psum += __shfl_xor(psum, 4);
    l_run = l_run * alpha + psum;
    m_run = m_new;
    __syncthreads();
#pragma unroll
    for (int d = 0; d < 8; d++) o_acc[d] *= alpha;
    for (int c = 0; c < 32; c++) {
      float p = p_s[r][c];
      const float* vr = &v_s[c][g << 3];
#pragma unroll
      for (int d = 0; d < 8; d++) o_acc[d] += p * vr[d];
    }
  }
  float inv = 1.f / l_run;
  size_t obase = (size_t)b * o_bs + (size_t)(m0 + r) * I_ + h * 64 + (g << 3);
#pragma unroll
  for (int d = 0; d < 8; d++) O[obase + d] = o_acc[d] * inv;
}

// ---------------- gather rows by VQ index ----------------
__global__ __launch_bounds__(128) void gather_kernel(
    const float* __restrict__ x2, const int* __restrict__ idx, float* __restrict__ out)
{
  int t = blockIdx.x;                 // b*2048 + n
  int b = t >> 11;
  int code = idx[t];
  const float4* src = (const float4*)(x2 + ((size_t)(b * M_ + code) << 9));
  float4* dst = (float4*)(out + ((size_t)t << 9));
  dst[threadIdx.x] = src[threadIdx.x];
}

// ---------------- scalars: commit_loss + perplexity ----------------
__global__ void scalars_kernel(const float* __restrict__ counts,
                               const double* __restrict__ commit_sum,
                               float* __restrict__ out_tail)
{
  int tid = threadIdx.x;   // 1024
  double p = (double)counts[tid] / 8192.0;
  double e = p * log(p + 1e-10);
  for (int off = 32; off; off >>= 1) e += __shfl_down(e, off);
  __shared__ double red[16];
  if ((tid & 63) == 0) red[tid >> 6] = e;
  __syncthreads();
  if (tid == 0) {
    double s = 0.0;
    for (int i = 0; i < 16; i++) s += red[i];
    out_tail[0] = (float)(*commit_sum / (8192.0 * 512.0));
    out_tail[1] = (float)exp(-s);
  }
}

extern "C" void kernel_launch(void* const* d_in, const int* in_sizes, int n_in,
                              void* d_out, int out_size, void* d_ws, size_t ws_size,
                              hipStream_t stream) {
  const float* ctx      = (const float*)d_in[0];
  const void*  mask_raw = d_in[1];
  const float* codebook = (const float*)d_in[2];
  const float* norm_g   = (const float*)d_in[3];
  const float* norm_b   = (const float*)d_in[4];
  const float* cnorm_g  = (const float*)d_in[5];
  const float* cnorm_b  = (const float*)d_in[6];
  const float* wq       = (const float*)d_in[7];
  const float* wkv      = (const float*)d_in[8];
  const float* wo       = (const float*)d_in[9];
  const float* wo_b     = (const float*)d_in[10];
  const float* a_norm_g = (const float*)d_in[11];
  const float* a_norm_b = (const float*)d_in[12];
  const float* a_qkv    = (const float*)d_in[13];
  const float* a_out    = (const float*)d_in[14];
  const float* f_norm_g = (const float*)d_in[15];
  const float* f_norm_b = (const float*)d_in[16];
  const float* f_w1     = (const float*)d_in[17];
  const float* f_w2     = (const float*)d_in[18];
  float* out = (float*)d_out;

  char* ws = (char*)d_ws;
  double* commit_sum = (double*)ws;                        // 8 B
  int*    mask_flag  = (int*)(ws + 32);
  float*  counts     = (float*)(ws + 64);                  // 4 KB
  double* code_sq    = (double*)(ws + 64 + 4096);          // 8 KB
  int*    indices    = (int*)(ws + 64 + 4096 + 8192);      // 32 KB
  int*    mask_norm  = (int*)(ws + 64 + 4096 + 8192 + 32768); // 32 KB
  size_t off = 128 * 1024;
  float* bufA = (float*)(ws + off); off += (size_t)32 << 20;  // kv [8192x1024] -> qkv2 [4096x1536]
  float* bufB = (float*)(ws + off); off += (size_t)16 << 20;  // ctx_ln [8192x512] -> g [4096x1024]
  float* bufC = (float*)(ws + off); off += (size_t)8  << 20;  // att_out -> o2 -> hf [4096x512]
  float* bufD = (float*)(ws + off); off += (size_t)8  << 20;  // x0 -> x2 [4096x512]
  float* bufE = (float*)(ws + off); off += (size_t)8  << 20;  // h -> x1 [4096x512]
  float* bufF = (float*)(ws + off); off += (size_t)2  << 20;  // xq [1024x512]
  float* bufG = (float*)(ws + off); off += (size_t)2  << 20;  // qs [1024x512]

  // ---- mask normalize + VQ ----
  zero_init_kernel<<<1, 1024, 0, stream>>>(counts, commit_sum);
  mask_detect_kernel<<<1, 256, 0, stream>>>((const unsigned char*)mask_raw, mask_flag);
  mask_norm_kernel<<<32, 256, 0, stream>>>(mask_raw, mask_flag, mask_norm);
  code_sq_kernel<<<1024, 128, 0, stream>>>(codebook, code_sq);
  vq_assign_kernel<<<1024, 256, 0, stream>>>(ctx, codebook, code_sq, indices);
  commit_hist_kernel<<<8192, 128, 0, stream>>>(ctx, codebook, indices, commit_sum, counts);

  // ---- Cross-attention ----
  ln_rows_kernel<<<1024, 256, 0, stream>>>(codebook, norm_g, norm_b, bufF);          // xq
  gemm_kernel<<<dim3(8, 16), 256, 0, stream>>>(bufF, wq, nullptr, nullptr, bufG,
                                               1024, 512, 512, 0.125f, 0);           // qs (scaled)
  ln_rows_kernel<<<8192, 256, 0, stream>>>(ctx, cnorm_g, cnorm_b, bufB);             // ctx_ln
  gemm_kernel<<<dim3(16, 128), 256, 0, stream>>>(bufB, wkv, nullptr, nullptr, bufA,
                                                 8192, 1024, 512, 1.f, 0);           // kv
  attn_kernel<<<dim3(32, 8, 4), 256, 0, stream>>>(bufG, 0, 512, 1.f,
                                                  bufA, 2048 * 1024, 1024, 0, 512,
                                                  mask_norm, 2048, bufC, 1024 * 512, 2048);
  gemm_kernel<<<dim3(8, 64), 256, 0, stream>>>(bufC, wo, wo_b, nullptr, bufD,
                                               4096, 512, 512, 1.f, 0);              // x0

  // ---- Transformer refinement ----
  ln_rows_kernel<<<4096, 256, 0, stream>>>(bufD, a_norm_g, a_norm_b, bufE);          // h
  gemm_kernel<<<dim3(24, 64), 256, 0, stream>>>(bufE, a_qkv, nullptr, nullptr, bufA,
                                                4096, 1536, 512, 1.f, 0);            // qkv2
  attn_kernel<<<dim3(32, 8, 4), 256, 0, stream>>>(bufA, 1024 * 1536, 1536, 0.125f,
                                                  bufA, 1024 * 1536, 1536, 512, 1024,
                                                  nullptr, 0, bufC, 1024 * 512, 1024);
  gemm_kernel<<<dim3(8, 64), 256, 0, stream>>>(bufC, a_out, nullptr, bufD, bufE,
                                               4096, 512, 512, 1.f, 0);              // x1 = x0 + o2@a_out
  ln_rows_kernel<<<4096, 256, 0, stream>>>(bufE, f_norm_g, f_norm_b, bufC);          // hf
  gemm_kernel<<<dim3(16, 64), 256, 0, stream>>>(bufC, f_w1, nullptr, nullptr, bufB,
                                                4096, 1024, 512, 1.f, 1);            // g = gelu(hf@w1)
  gemm_kernel<<<dim3(8, 64), 256, 0, stream>>>(bufB, f_w2, nullptr, bufE, bufD,
                                               4096, 512, 1024, 1.f, 0);             // x2 = x1 + g@w2

  // ---- Gather + scalars ----
  gather_kernel<<<8192, 128, 0, stream>>>(bufD, indices, out);
  scalars_kernel<<<1, 1024, 0, stream>>>(counts, commit_sum, out + (size_t)B_ * N_ * D_);
}

// Round 3
// 1101.713 us; speedup vs baseline: 2.0906x; 2.0906x over previous
//
#include <hip/hip_runtime.h>
#include <math.h>

#define B_ 4
#define N_ 2048
#define D_ 512
#define M_ 1024
#define H_ 8
#define DH_ 64
#define I_ 512
#define FF_ 1024

typedef unsigned short u16;
typedef __attribute__((ext_vector_type(8))) short bf16x8;
typedef __attribute__((ext_vector_type(4))) float f32x4;

__device__ inline u16 f2b(float f) {           // fp32 -> bf16 RNE
  union { float f; unsigned int u; } v; v.f = f;
  unsigned int u = v.u;
  u += 0x7fffu + ((u >> 16) & 1u);
  return (u16)(u >> 16);
}

__device__ inline float gelu_f(float x) {
  float x3 = x * x * x;
  return 0.5f * x * (1.f + tanhf(0.7978845608028654f * (x + 0.044715f * x3)));
}

// ---------------- zero accumulators ----------------
__global__ void zero_init_kernel(float* counts, double* commit_sum) {
  int t = threadIdx.x;
  counts[t] = 0.f;
  if (t == 0) *commit_sum = 0.0;
}

// ---------------- mask dtype detection / normalize ----------------
__global__ void mask_detect_kernel(const unsigned char* __restrict__ mb, int* flag) {
  __shared__ int any;
  if (threadIdx.x == 0) any = 0;
  __syncthreads();
  int acc = 0;
  for (int i = threadIdx.x; i < 8192; i += 256)
    if (i & 3) acc |= mb[i];
  if (acc) atomicOr(&any, 1);
  __syncthreads();
  if (threadIdx.x == 0) *flag = any;
}

__global__ void mask_norm_kernel(const void* __restrict__ mraw,
                                 const int* __restrict__ flag,
                                 int* __restrict__ mnorm) {
  int i = blockIdx.x * 256 + threadIdx.x;
  int v;
  if (*flag) v = ((const unsigned char*)mraw)[i];
  else       v = ((const int*)mraw)[i];
  mnorm[i] = (v != 0) ? 1 : 0;
}

// ---------------- codebook row sum-of-squares (fp64) ----------------
__global__ __launch_bounds__(128) void code_sq_kernel(const float* __restrict__ cb,
                                                      double* __restrict__ csq) {
  int row = blockIdx.x, tid = threadIdx.x;
  const float4* r4 = (const float4*)(cb + (size_t)row * D_);
  float4 v = r4[tid];
  double s = (double)v.x * v.x + (double)v.y * v.y + (double)v.z * v.z + (double)v.w * v.w;
  for (int off = 32; off; off >>= 1) s += __shfl_down(s, off);
  __shared__ double red[2];
  if ((tid & 63) == 0) red[tid >> 6] = s;
  __syncthreads();
  if (tid == 0) csq[row] = red[0] + red[1];
}

// ---------------- VQ pass 1: fp32, top-2 candidates per token ----------------
__device__ inline bool better(float d1, int i1, float d2, int i2) {
  return d1 < d2 || (d1 == d2 && i1 < i2);
}

__global__ __launch_bounds__(256) void vq_assign_kernel(
    const float* __restrict__ flat, const float* __restrict__ cb,
    const double* __restrict__ csq, int2* __restrict__ cand)
{
  __shared__ float xs[8 * 512];
  __shared__ float cs_[16 * 516];
  int tid = threadIdx.x;
  int t0 = blockIdx.x * 8;
  {
    const float4* src = (const float4*)(flat + ((size_t)t0 << 9));
    float4* dst = (float4*)xs;
#pragma unroll
    for (int i = 0; i < 4; i++) dst[tid + i * 256] = src[tid + i * 256];
  }
  int tt = tid >> 5;            // token 0..7
  int cc = (tid >> 1) & 15;     // code-in-tile
  int half = tid & 1;
  float b1 = 1e30f, b2 = 1e30f; int i1 = 1 << 20, i2 = 1 << 20;
  for (int c0 = 0; c0 < M_; c0 += 16) {
    __syncthreads();
#pragma unroll
    for (int i = 0; i < 8; i++) {
      int p = tid + i * 256;
      int r = p >> 7, d4 = p & 127;
      float4 v = ((const float4*)(cb + ((size_t)(c0 + r) << 9)))[d4];
      *(float4*)(cs_ + r * 516 + (d4 << 2)) = v;
    }
    __syncthreads();
    const float4* xr4 = (const float4*)(xs + tt * 512 + half * 256);
    const float4* cr4 = (const float4*)(cs_ + cc * 516 + half * 256);
    float a0 = 0.f, a1 = 0.f, a2 = 0.f, a3 = 0.f;
#pragma unroll 16
    for (int d4 = 0; d4 < 64; d4++) {
      float4 xv = xr4[d4];
      float4 cv = cr4[d4];
      a0 += xv.x * cv.x; a1 += xv.y * cv.y; a2 += xv.z * cv.z; a3 += xv.w * cv.w;
    }
    float dsum = (a0 + a1) + (a2 + a3);
    dsum += __shfl_xor(dsum, 1);      // combine halves (both lanes now identical)
    int c = c0 + cc;
    float dist = (float)csq[c] - 2.f * dsum;
    if (better(dist, c, b1, i1)) { b2 = b1; i2 = i1; b1 = dist; i1 = c; }
    else if (better(dist, c, b2, i2)) { b2 = dist; i2 = c; }
  }
  // merge top-2 across the 32 lanes of this token
  for (int off = 1; off < 32; off <<= 1) {
    float ob1 = __shfl_xor(b1, off), ob2 = __shfl_xor(b2, off);
    int   oi1 = __shfl_xor(i1, off), oi2 = __shfl_xor(i2, off);
    if (oi1 == i1) {                      // duplicate lists (the half-pair merge)
      if (better(ob2, oi2, b2, i2)) { b2 = ob2; i2 = oi2; }
    } else if (better(b1, i1, ob1, oi1)) {
      if (better(ob1, oi1, b2, i2)) { b2 = ob1; i2 = oi1; }
    } else {
      float nb2; int ni2;
      if (better(b1, i1, ob2, oi2)) { nb2 = b1; ni2 = i1; }
      else                          { nb2 = ob2; ni2 = oi2; }
      b1 = ob1; i1 = oi1; b2 = nb2; i2 = ni2;
    }
  }
  if ((tid & 31) == 0) cand[t0 + tt] = make_int2(i1, i2);
}

// ---------------- VQ pass 2: exact fp64 refine of the 2 candidates ----------------
__global__ __launch_bounds__(64) void vq_refine_kernel(
    const float* __restrict__ flat, const float* __restrict__ cb,
    const double* __restrict__ csq, const int2* __restrict__ cand,
    int* __restrict__ out_idx)
{
  int t = blockIdx.x, lane = threadIdx.x;
  int2 c = cand[t];
  const float* x = flat + ((size_t)t << 9);
  const float* c1 = cb + ((size_t)c.x << 9);
  const float* c2 = cb + ((size_t)c.y << 9);
  double s1 = 0.0, s2 = 0.0;
#pragma unroll
  for (int i = 0; i < 8; i++) {
    int d = lane + i * 64;
    double xv = x[d];
    s1 += xv * (double)c1[d];
    s2 += xv * (double)c2[d];
  }
  for (int off = 32; off; off >>= 1) { s1 += __shfl_down(s1, off); s2 += __shfl_down(s2, off); }
  if (lane == 0) {
    double d1 = csq[c.x] - 2.0 * s1;
    double d2 = csq[c.y] - 2.0 * s2;
    int bi = (d2 < d1 || (d2 == d1 && c.y < c.x)) ? c.y : c.x;
    out_idx[t] = bi;
  }
}

// ---------------- commit loss + histogram ----------------
__global__ __launch_bounds__(128) void commit_hist_kernel(
    const float* __restrict__ flat, const float* __restrict__ cb,
    const int* __restrict__ idx, double* __restrict__ commit_sum,
    float* __restrict__ counts)
{
  int t = blockIdx.x, tid = threadIdx.x;
  int code = idx[t];
  float4 a = ((const float4*)(flat + ((size_t)t << 9)))[tid];
  float4 c = ((const float4*)(cb + ((size_t)code << 9)))[tid];
  float dx = a.x - c.x, dy = a.y - c.y, dz = a.z - c.z, dw = a.w - c.w;
  double s = (double)dx * dx + (double)dy * dy + (double)dz * dz + (double)dw * dw;
  for (int off = 32; off; off >>= 1) s += __shfl_down(s, off);
  __shared__ double red[2];
  if ((tid & 63) == 0) red[tid >> 6] = s;
  __syncthreads();
  if (tid == 0) {
    atomicAdd(commit_sum, red[0] + red[1]);
    atomicAdd(counts + code, 1.0f);
  }
}

// ---------------- LayerNorm (fp32 in -> bf16 out) ----------------
__global__ __launch_bounds__(256) void ln_rows_kernel(
    const float* __restrict__ x, const float* __restrict__ g,
    const float* __restrict__ b, u16* __restrict__ y)
{
  int row = blockIdx.x, tid = threadIdx.x;
  const float* xr = x + (size_t)row * D_;
  float v0 = xr[tid], v1 = xr[tid + 256];
  float s = v0 + v1;
  for (int off = 32; off; off >>= 1) s += __shfl_down(s, off);
  __shared__ float red[4];
  __shared__ float bcast[2];
  if ((tid & 63) == 0) red[tid >> 6] = s;
  __syncthreads();
  if (tid == 0) bcast[0] = (red[0] + red[1] + red[2] + red[3]) * (1.f / 512.f);
  __syncthreads();
  float mu = bcast[0];
  float d0 = v0 - mu, d1 = v1 - mu;
  float q = d0 * d0 + d1 * d1;
  for (int off = 32; off; off >>= 1) q += __shfl_down(q, off);
  if ((tid & 63) == 0) red[tid >> 6] = q;
  __syncthreads();
  if (tid == 0) bcast[1] = rsqrtf((red[0] + red[1] + red[2] + red[3]) * (1.f / 512.f) + 1e-5f);
  __syncthreads();
  float rs = bcast[1];
  u16* yr = y + (size_t)row * D_;
  yr[tid]       = f2b(d0 * rs * g[tid] + b[tid]);
  yr[tid + 256] = f2b(d1 * rs * g[tid + 256] + b[tid + 256]);
}

// ---------------- weight convert fp32 [K][N] -> bf16 [N][K] ----------------
__global__ __launch_bounds__(256) void wconv_kernel(
    const float* __restrict__ W, u16* __restrict__ WT, int K, int N)
{
  __shared__ float tile[32][33];
  int t = threadIdx.x;
  int k0 = blockIdx.y * 32, n0 = blockIdx.x * 32;
  int ty = t >> 5, tx = t & 31;
#pragma unroll
  for (int i = 0; i < 4; i++)
    tile[ty + 8 * i][tx] = W[(size_t)(k0 + ty + 8 * i) * N + n0 + tx];
  __syncthreads();
#pragma unroll
  for (int i = 0; i < 4; i++)
    WT[(size_t)(n0 + ty + 8 * i) * K + k0 + tx] = f2b(tile[tx][ty + 8 * i]);
}

// ---------------- bf16 MFMA GEMM: C = act(A@B + bias) + resid ----------------
// A [M][K] bf16, BT [N][K] bf16. Outputs fp32 (Cf) and/or bf16 (Cb).
__global__ __launch_bounds__(256) void gemm_bf16_kernel(
    const u16* __restrict__ A, const u16* __restrict__ BT,
    const float* __restrict__ bias, const float* __restrict__ resid,
    float* __restrict__ Cf, u16* __restrict__ Cb,
    int M, int N, int K, int act)
{
  __shared__ __attribute__((aligned(16))) u16 As[128 * 40];
  __shared__ __attribute__((aligned(16))) u16 Bs[128 * 40];
  int tid = threadIdx.x;
  int lane = tid & 63, wave = tid >> 6;
  int wr = wave >> 1, wc = wave & 1;
  int row0 = blockIdx.y * 128, col0 = blockIdx.x * 128;
  int l15 = lane & 15, l4 = lane >> 4;
  int sr = tid >> 2, skc = tid & 3;          // staging: row, 8-elem k-chunk
  f32x4 acc[4][4] = {};
  for (int k0 = 0; k0 < K; k0 += 32) {
    __syncthreads();
    bf16x8 a0 = *(const bf16x8*)(A + (size_t)(row0 + sr) * K + k0 + skc * 8);
    bf16x8 a1 = *(const bf16x8*)(A + (size_t)(row0 + 64 + sr) * K + k0 + skc * 8);
    bf16x8 b0 = *(const bf16x8*)(BT + (size_t)(col0 + sr) * K + k0 + skc * 8);
    bf16x8 b1 = *(const bf16x8*)(BT + (size_t)(col0 + 64 + sr) * K + k0 + skc * 8);
    *(bf16x8*)&As[sr * 40 + skc * 8] = a0;
    *(bf16x8*)&As[(64 + sr) * 40 + skc * 8] = a1;
    *(bf16x8*)&Bs[sr * 40 + skc * 8] = b0;
    *(bf16x8*)&Bs[(64 + sr) * 40 + skc * 8] = b1;
    __syncthreads();
    bf16x8 af[4], bfr[4];
#pragma unroll
    for (int m = 0; m < 4; m++)
      af[m] = *(const bf16x8*)&As[(wr * 64 + m * 16 + l15) * 40 + l4 * 8];
#pragma unroll
    for (int n = 0; n < 4; n++)
      bfr[n] = *(const bf16x8*)&Bs[(wc * 64 + n * 16 + l15) * 40 + l4 * 8];
#pragma unroll
    for (int m = 0; m < 4; m++)
#pragma unroll
      for (int n = 0; n < 4; n++)
        acc[m][n] = __builtin_amdgcn_mfma_f32_16x16x32_bf16(af[m], bfr[n], acc[m][n], 0, 0, 0);
  }
#pragma unroll
  for (int m = 0; m < 4; m++) {
#pragma unroll
    for (int n = 0; n < 4; n++) {
      int col = col0 + wc * 64 + n * 16 + l15;
      float bv = bias ? bias[col] : 0.f;
#pragma unroll
      for (int r = 0; r < 4; r++) {
        int row = row0 + wr * 64 + m * 16 + l4 * 4 + r;
        float v = acc[m][n][r] + bv;
        if (act == 1) v = gelu_f(v);
        if (resid) v += resid[(size_t)row * N + col];
        if (Cf) Cf[(size_t)row * N + col] = v;
        if (Cb) Cb[(size_t)row * N + col] = f2b(v);
      }
    }
  }
}

// ---------------- V transpose: src rows [n][col0+h*64+d] -> Vt [b*8+h][64][n_rows] ----------------
__global__ __launch_bounds__(256) void vt_kernel(
    const u16* __restrict__ src, size_t b_stride, int row_stride, int col0,
    int n_rows, u16* __restrict__ dst)
{
  __shared__ __attribute__((aligned(16))) u16 tile[32][72];
  int t = threadIdx.x;
  int bh = blockIdx.y;
  int b = bh >> 3, h = bh & 7;
  int n0 = blockIdx.x * 32;
  int n = t >> 3, dc = t & 7;
  *(bf16x8*)&tile[n][dc * 8] =
      *(const bf16x8*)(src + (size_t)b * b_stride + (size_t)(n0 + n) * row_stride + col0 + h * 64 + dc * 8);
  __syncthreads();
  int d = t >> 2, ns = t & 3;
  bf16x8 o;
#pragma unroll
  for (int i = 0; i < 8; i++) o[i] = (short)tile[ns * 8 + i][d];
  *(bf16x8*)(dst + ((size_t)bh * 64 + d) * n_rows + n0 + ns * 8) = o;
}

// ---------------- MFMA flash attention ----------------
// Q rows at [b*q_bs + row*q_stride + h*64]; K rows at [b*k_bs + key*k_stride + k_extra + h*64];
// Vt [b*8+h][64][n_keys]; O bf16 [b*o_bs + row*512 + h*64].
__global__ __launch_bounds__(256) void attn_mfma_kernel(
    const u16* __restrict__ Q, size_t q_bs, int q_stride,
    const u16* __restrict__ Kp, size_t k_bs, int k_stride, int k_extra,
    const u16* __restrict__ Vt, const int* __restrict__ mask,
    float scale, u16* __restrict__ O, size_t o_bs, int n_keys)
{
  __shared__ __attribute__((aligned(16))) u16 Ks[32 * 72];
  __shared__ __attribute__((aligned(16))) u16 Vs[64 * 40];
  __shared__ __attribute__((aligned(16))) u16 Ps[4 * 16 * 40];
  __shared__ int m_sh[32];
  int tid = threadIdx.x, lane = tid & 63, wave = tid >> 6;
  int b = blockIdx.z, h = blockIdx.y, q0 = blockIdx.x * 64 + wave * 16;
  int l15 = lane & 15, l4 = lane >> 4;
  const u16* qrow = Q + (size_t)b * q_bs + (size_t)(q0 + l15) * q_stride + h * 64 + l4 * 8;
  bf16x8 qf0 = *(const bf16x8*)qrow;
  bf16x8 qf1 = *(const bf16x8*)(qrow + 32);
  f32x4 o_acc[4] = {};
  float m_run[4], l_run[4];
#pragma unroll
  for (int r = 0; r < 4; r++) { m_run[r] = -3.0e38f; l_run[r] = 0.f; }
  int skey = tid >> 3, sdc = tid & 7;
  int svd = tid >> 2, svk = tid & 3;
  const u16* kbase = Kp + (size_t)b * k_bs + k_extra + h * 64 + sdc * 8;
  const u16* vtbase = Vt + ((size_t)(b * 8 + h) * 64 + svd) * n_keys + svk * 8;

  for (int n0 = 0; n0 < n_keys; n0 += 32) {
    __syncthreads();
    bf16x8 kv_ = *(const bf16x8*)(kbase + (size_t)(n0 + skey) * k_stride);
    bf16x8 vv_ = *(const bf16x8*)(vtbase + n0);
    *(bf16x8*)&Ks[skey * 72 + sdc * 8] = kv_;
    *(bf16x8*)&Vs[svd * 40 + svk * 8] = vv_;
    if (mask && tid < 32) m_sh[tid] = mask[(size_t)b * n_keys + n0 + tid];
    __syncthreads();
    f32x4 sac[2] = {};
#pragma unroll
    for (int kb = 0; kb < 2; kb++) {
      bf16x8 kf0 = *(const bf16x8*)&Ks[(kb * 16 + l15) * 72 + l4 * 8];
      bf16x8 kf1 = *(const bf16x8*)&Ks[(kb * 16 + l15) * 72 + 32 + l4 * 8];
      sac[kb] = __builtin_amdgcn_mfma_f32_16x16x32_bf16(qf0, kf0, sac[kb], 0, 0, 0);
      sac[kb] = __builtin_amdgcn_mfma_f32_16x16x32_bf16(qf1, kf1, sac[kb], 0, 0, 0);
    }
    int mk0 = 1, mk1 = 1;
    if (mask) { mk0 = m_sh[l15]; mk1 = m_sh[16 + l15]; }
#pragma unroll
    for (int r = 0; r < 4; r++) {
      float s0 = mk0 ? sac[0][r] * scale : -3.0e38f;
      float s1 = mk1 ? sac[1][r] * scale : -3.0e38f;
      float tm = fmaxf(s0, s1);
      tm = fmaxf(tm, __shfl_xor(tm, 1));
      tm = fmaxf(tm, __shfl_xor(tm, 2));
      tm = fmaxf(tm, __shfl_xor(tm, 4));
      tm = fmaxf(tm, __shfl_xor(tm, 8));
      float mnew = fmaxf(m_run[r], tm);
      float al = __expf(m_run[r] - mnew);
      float p0 = (s0 < -1.0e37f) ? 0.f : __expf(s0 - mnew);
      float p1 = (s1 < -1.0e37f) ? 0.f : __expf(s1 - mnew);
      float ps = p0 + p1;
      ps += __shfl_xor(ps, 1); ps += __shfl_xor(ps, 2);
      ps += __shfl_xor(ps, 4); ps += __shfl_xor(ps, 8);
      l_run[r] = l_run[r] * al + ps;
      m_run[r] = mnew;
#pragma unroll
      for (int nb = 0; nb < 4; nb++) o_acc[nb][r] *= al;
      int qloc = l4 * 4 + r;
      Ps[wave * 640 + qloc * 40 + l15] = f2b(p0);
      Ps[wave * 640 + qloc * 40 + 16 + l15] = f2b(p1);
    }
    bf16x8 pf = *(const bf16x8*)&Ps[wave * 640 + l15 * 40 + l4 * 8];
#pragma unroll
    for (int nb = 0; nb < 4; nb++) {
      bf16x8 vf = *(const bf16x8*)&Vs[(nb * 16 + l15) * 40 + l4 * 8];
      o_acc[nb] = __builtin_amdgcn_mfma_f32_16x16x32_bf16(pf, vf, o_acc[nb], 0, 0, 0);
    }
  }
#pragma unroll
  for (int nb = 0; nb < 4; nb++) {
#pragma unroll
    for (int r = 0; r < 4; r++) {
      int row = q0 + l4 * 4 + r;
      int col = h * 64 + nb * 16 + l15;
      O[(size_t)b * o_bs + (size_t)row * 512 + col] = f2b(o_acc[nb][r] / l_run[r]);
    }
  }
}

// ---------------- gather rows by VQ index (fp32) ----------------
__global__ __launch_bounds__(128) void gather_kernel(
    const float* __restrict__ x2, const int* __restrict__ idx, float* __restrict__ out)
{
  int t = blockIdx.x;
  int b = t >> 11;
  int code = idx[t];
  const float4* src = (const float4*)(x2 + ((size_t)(b * M_ + code) << 9));
  float4* dst = (float4*)(out + ((size_t)t << 9));
  dst[threadIdx.x] = src[threadIdx.x];
}

// ---------------- scalars ----------------
__global__ void scalars_kernel(const float* __restrict__ counts,
                               const double* __restrict__ commit_sum,
                               float* __restrict__ out_tail)
{
  int tid = threadIdx.x;
  double p = (double)counts[tid] / 8192.0;
  double e = p * log(p + 1e-10);
  for (int off = 32; off; off >>= 1) e += __shfl_down(e, off);
  __shared__ double red[16];
  if ((tid & 63) == 0) red[tid >> 6] = e;
  __syncthreads();
  if (tid == 0) {
    double s = 0.0;
    for (int i = 0; i < 16; i++) s += red[i];
    out_tail[0] = (float)(*commit_sum / (8192.0 * 512.0));
    out_tail[1] = (float)exp(-s);
  }
}

extern "C" void kernel_launch(void* const* d_in, const int* in_sizes, int n_in,
                              void* d_out, int out_size, void* d_ws, size_t ws_size,
                              hipStream_t stream) {
  const float* ctx      = (const float*)d_in[0];
  const void*  mask_raw = d_in[1];
  const float* codebook = (const float*)d_in[2];
  const float* norm_g   = (const float*)d_in[3];
  const float* norm_b   = (const float*)d_in[4];
  const float* cnorm_g  = (const float*)d_in[5];
  const float* cnorm_b  = (const float*)d_in[6];
  const float* wq       = (const float*)d_in[7];
  const float* wkv      = (const float*)d_in[8];
  const float* wo       = (const float*)d_in[9];
  const float* wo_b     = (const float*)d_in[10];
  const float* a_norm_g = (const float*)d_in[11];
  const float* a_norm_b = (const float*)d_in[12];
  const float* a_qkv    = (const float*)d_in[13];
  const float* a_out    = (const float*)d_in[14];
  const float* f_norm_g = (const float*)d_in[15];
  const float* f_norm_b = (const float*)d_in[16];
  const float* f_w1     = (const float*)d_in[17];
  const float* f_w2     = (const float*)d_in[18];
  float* out = (float*)d_out;

  char* ws = (char*)d_ws;
  double* commit_sum = (double*)(ws + 0);
  int*    mask_flag  = (int*)(ws + 64);
  float*  counts     = (float*)(ws + 128);
  double* code_sq    = (double*)(ws + 128 + 4096);
  int*    indices    = (int*)(ws + 128 + 4096 + 8192);
  int*    mask_norm  = (int*)(ws + 128 + 4096 + 8192 + 32768);
  int2*   cand       = (int2*)(ws + 128 + 4096 + 8192 + 32768 + 32768);
  size_t off = 256 * 1024;
  u16* wqT    = (u16*)(ws + off); off += (size_t)512 * 512 * 2;
  u16* wkvT   = (u16*)(ws + off); off += (size_t)1024 * 512 * 2;
  u16* woT    = (u16*)(ws + off); off += (size_t)512 * 512 * 2;
  u16* aqkvT  = (u16*)(ws + off); off += (size_t)1536 * 512 * 2;
  u16* aoutT  = (u16*)(ws + off); off += (size_t)512 * 512 * 2;
  u16* fw1T   = (u16*)(ws + off); off += (size_t)1024 * 512 * 2;
  u16* fw2T   = (u16*)(ws + off); off += (size_t)512 * 1024 * 2;
  u16* xq_b   = (u16*)(ws + off); off += (size_t)1024 * 512 * 2;
  u16* qs_b   = (u16*)(ws + off); off += (size_t)1024 * 512 * 2;
  char* regA  = ws + off; off += (size_t)16 << 20;   // kv_b -> qkv2_b
  char* regB  = ws + off; off += (size_t)8 << 20;    // ctx_ln_b -> VtS
  char* regC  = ws + off; off += (size_t)8 << 20;    // VtX -> x1_f
  char* regD  = ws + off; off += (size_t)8 << 20;    // x0_f
  char* regE  = ws + off; off += (size_t)4 << 20;    // att_out_b / h_b / o2_b / hf_b
  char* regF  = ws + off; off += (size_t)8 << 20;    // g_b
  char* regG  = ws + off; off += (size_t)8 << 20;    // x2_f

  u16* kv_b     = (u16*)regA;
  u16* qkv2_b   = (u16*)regA;
  u16* ctx_ln_b = (u16*)regB;
  u16* VtS      = (u16*)regB;
  u16* VtX      = (u16*)regC;
  float* x1_f   = (float*)regC;
  float* x0_f   = (float*)regD;
  u16* att_out_b = (u16*)regE;
  u16* h_b       = (u16*)regE;
  u16* o2_b      = (u16*)regE;
  u16* hf_b      = (u16*)regE;
  u16* g_b      = (u16*)regF;
  float* x2_f   = (float*)regG;

  // ---- VQ ----
  zero_init_kernel<<<1, 1024, 0, stream>>>(counts, commit_sum);
  mask_detect_kernel<<<1, 256, 0, stream>>>((const unsigned char*)mask_raw, mask_flag);
  mask_norm_kernel<<<32, 256, 0, stream>>>(mask_raw, mask_flag, mask_norm);
  code_sq_kernel<<<1024, 128, 0, stream>>>(codebook, code_sq);
  vq_assign_kernel<<<1024, 256, 0, stream>>>(ctx, codebook, code_sq, cand);
  vq_refine_kernel<<<8192, 64, 0, stream>>>(ctx, codebook, code_sq, cand, indices);
  commit_hist_kernel<<<8192, 128, 0, stream>>>(ctx, codebook, indices, commit_sum, counts);

  // ---- weight conversion (fp32 [K][N] -> bf16 [N][K]) ----
  wconv_kernel<<<dim3(16, 16), 256, 0, stream>>>(wq,    wqT,   512, 512);
  wconv_kernel<<<dim3(32, 16), 256, 0, stream>>>(wkv,   wkvT,  512, 1024);
  wconv_kernel<<<dim3(16, 16), 256, 0, stream>>>(wo,    woT,   512, 512);
  wconv_kernel<<<dim3(48, 16), 256, 0, stream>>>(a_qkv, aqkvT, 512, 1536);
  wconv_kernel<<<dim3(16, 16), 256, 0, stream>>>(a_out, aoutT, 512, 512);
  wconv_kernel<<<dim3(32, 16), 256, 0, stream>>>(f_w1,  fw1T,  512, 1024);
  wconv_kernel<<<dim3(16, 32), 256, 0, stream>>>(f_w2,  fw2T,  1024, 512);

  // ---- Cross-attention ----
  ln_rows_kernel<<<1024, 256, 0, stream>>>(codebook, norm_g, norm_b, xq_b);
  gemm_bf16_kernel<<<dim3(4, 8), 256, 0, stream>>>(xq_b, wqT, nullptr, nullptr,
                                                   nullptr, qs_b, 1024, 512, 512, 0);
  ln_rows_kernel<<<8192, 256, 0, stream>>>(ctx, cnorm_g, cnorm_b, ctx_ln_b);
  gemm_bf16_kernel<<<dim3(8, 64), 256, 0, stream>>>(ctx_ln_b, wkvT, nullptr, nullptr,
                                                    nullptr, kv_b, 8192, 1024, 512, 0);
  vt_kernel<<<dim3(64, 32), 256, 0, stream>>>(kv_b, (size_t)2048 * 1024, 1024, 512, 2048, VtX);
  attn_mfma_kernel<<<dim3(16, 8, 4), 256, 0, stream>>>(
      qs_b, 0, 512, kv_b, (size_t)2048 * 1024, 1024, 0, VtX, mask_norm,
      0.125f, att_out_b, (size_t)1024 * 512, 2048);
  gemm_bf16_kernel<<<dim3(4, 32), 256, 0, stream>>>(att_out_b, woT, wo_b, nullptr,
                                                    x0_f, nullptr, 4096, 512, 512, 0);

  // ---- Transformer refinement ----
  ln_rows_kernel<<<4096, 256, 0, stream>>>(x0_f, a_norm_g, a_norm_b, h_b);
  gemm_bf16_kernel<<<dim3(12, 32), 256, 0, stream>>>(h_b, aqkvT, nullptr, nullptr,
                                                     nullptr, qkv2_b, 4096, 1536, 512, 0);
  vt_kernel<<<dim3(32, 32), 256, 0, stream>>>(qkv2_b, (size_t)1024 * 1536, 1536, 1024, 1024, VtS);
  attn_mfma_kernel<<<dim3(16, 8, 4), 256, 0, stream>>>(
      qkv2_b, (size_t)1024 * 1536, 1536, qkv2_b, (size_t)1024 * 1536, 1536, 512, VtS, nullptr,
      0.125f, o2_b, (size_t)1024 * 512, 1024);
  gemm_bf16_kernel<<<dim3(4, 32), 256, 0, stream>>>(o2_b, aoutT, nullptr, x0_f,
                                                    x1_f, nullptr, 4096, 512, 512, 0);
  ln_rows_kernel<<<4096, 256, 0, stream>>>(x1_f, f_norm_g, f_norm_b, hf_b);
  gemm_bf16_kernel<<<dim3(8, 32), 256, 0, stream>>>(hf_b, fw1T, nullptr, nullptr,
                                                    nullptr, g_b, 4096, 1024, 512, 1);
  gemm_bf16_kernel<<<dim3(4, 32), 256, 0, stream>>>(g_b, fw2T, nullptr, x1_f,
                                                    x2_f, nullptr, 4096, 512, 1024, 0);

  // ---- Gather + scalars ----
  gather_kernel<<<8192, 128, 0, stream>>>(x2_f, indices, out);
  scalars_kernel<<<1, 1024, 0, stream>>>(counts, commit_sum, out + (size_t)B_ * N_ * D_);
}

// Round 4
// 627.870 us; speedup vs baseline: 3.6683x; 1.7547x over previous
//
#include <hip/hip_runtime.h>
#include <math.h>

#define B_ 4
#define N_ 2048
#define D_ 512
#define M_ 1024
#define H_ 8
#define DH_ 64
#define I_ 512
#define FF_ 1024

typedef unsigned short u16;
typedef __attribute__((ext_vector_type(8))) short bf16x8;
typedef __attribute__((ext_vector_type(4))) float f32x4;

__device__ inline u16 f2b(float f) {           // fp32 -> bf16 RNE
  union { float f; unsigned int u; } v; v.f = f;
  unsigned int u = v.u;
  u += 0x7fffu + ((u >> 16) & 1u);
  return (u16)(u >> 16);
}
__device__ inline float b2f(u16 h) {
  union { unsigned int u; float f; } v; v.u = ((unsigned int)h) << 16;
  return v.f;
}

__device__ inline float gelu_f(float x) {
  float x3 = x * x * x;
  return 0.5f * x * (1.f + tanhf(0.7978845608028654f * (x + 0.044715f * x3)));
}

// ---------------- zero accumulators ----------------
__global__ void zero_init_kernel(float* counts, double* commit_sum) {
  int t = threadIdx.x;
  counts[t] = 0.f;
  if (t == 0) *commit_sum = 0.0;
}

// ---------------- mask dtype detection / normalize ----------------
__global__ void mask_detect_kernel(const unsigned char* __restrict__ mb, int* flag) {
  __shared__ int any;
  if (threadIdx.x == 0) any = 0;
  __syncthreads();
  int acc = 0;
  for (int i = threadIdx.x; i < 8192; i += 256)
    if (i & 3) acc |= mb[i];
  if (acc) atomicOr(&any, 1);
  __syncthreads();
  if (threadIdx.x == 0) *flag = any;
}

__global__ void mask_norm_kernel(const void* __restrict__ mraw,
                                 const int* __restrict__ flag,
                                 int* __restrict__ mnorm) {
  int i = blockIdx.x * 256 + threadIdx.x;
  int v;
  if (*flag) v = ((const unsigned char*)mraw)[i];
  else       v = ((const int*)mraw)[i];
  mnorm[i] = (v != 0) ? 1 : 0;
}

// ---------------- codebook row sum-of-squares (fp64 + fp32 copy) ----------------
__global__ __launch_bounds__(128) void code_sq_kernel(const float* __restrict__ cb,
                                                      double* __restrict__ csq,
                                                      float* __restrict__ csqf) {
  int row = blockIdx.x, tid = threadIdx.x;
  const float4* r4 = (const float4*)(cb + (size_t)row * D_);
  float4 v = r4[tid];
  double s = (double)v.x * v.x + (double)v.y * v.y + (double)v.z * v.z + (double)v.w * v.w;
  for (int off = 32; off; off >>= 1) s += __shfl_down(s, off);
  __shared__ double red[2];
  if ((tid & 63) == 0) red[tid >> 6] = s;
  __syncthreads();
  if (tid == 0) { csq[row] = red[0] + red[1]; csqf[row] = (float)(red[0] + red[1]); }
}

// ---------------- VQ: hi/lo split builders ----------------
// A[t] = [x_hi | x_lo | x_hi]  (K=1536)
__global__ __launch_bounds__(256) void vq_split_x_kernel(
    const float* __restrict__ flat, u16* __restrict__ A)
{
  int t = blockIdx.x;
  const float* xr = flat + ((size_t)t << 9);
  u16* ar = A + (size_t)t * 1536;
#pragma unroll
  for (int i = 0; i < 2; i++) {
    int j = threadIdx.x + i * 256;
    float x = xr[j];
    u16 h = f2b(x);
    u16 l = f2b(x - b2f(h));
    ar[j] = h; ar[512 + j] = l; ar[1024 + j] = h;
  }
}
// BT[c] = [c_hi | c_hi | c_lo]  (K=1536)
__global__ __launch_bounds__(256) void vq_split_c_kernel(
    const float* __restrict__ cb, u16* __restrict__ BT)
{
  int c = blockIdx.x;
  const float* cr = cb + ((size_t)c << 9);
  u16* br = BT + (size_t)c * 1536;
#pragma unroll
  for (int i = 0; i < 2; i++) {
    int j = threadIdx.x + i * 256;
    float x = cr[j];
    u16 h = f2b(x);
    u16 l = f2b(x - b2f(h));
    br[j] = h; br[512 + j] = h; br[1024 + j] = l;
  }
}

// ---------------- VQ: per-token top-2 over S row ----------------
__device__ inline bool better(float d1, int i1, float d2, int i2) {
  return d1 < d2 || (d1 == d2 && i1 < i2);
}

__global__ __launch_bounds__(256) void vq_top2_kernel(
    const float* __restrict__ S, const float* __restrict__ csqf,
    int2* __restrict__ cand)
{
  int t = blockIdx.x, tid = threadIdx.x;
  float4 sv = ((const float4*)(S + ((size_t)t << 10)))[tid];
  float4 cq = ((const float4*)csqf)[tid];
  int c0 = tid << 2;
  float b1, b2; int i1, i2;
  b1 = cq.x - 2.f * sv.x; i1 = c0;
  b2 = 1e30f; i2 = 1 << 20;
  {
    float d; int c;
    d = cq.y - 2.f * sv.y; c = c0 + 1;
    if (better(d, c, b1, i1)) { b2 = b1; i2 = i1; b1 = d; i1 = c; }
    else if (better(d, c, b2, i2)) { b2 = d; i2 = c; }
    d = cq.z - 2.f * sv.z; c = c0 + 2;
    if (better(d, c, b1, i1)) { b2 = b1; i2 = i1; b1 = d; i1 = c; }
    else if (better(d, c, b2, i2)) { b2 = d; i2 = c; }
    d = cq.w - 2.f * sv.w; c = c0 + 3;
    if (better(d, c, b1, i1)) { b2 = b1; i2 = i1; b1 = d; i1 = c; }
    else if (better(d, c, b2, i2)) { b2 = d; i2 = c; }
  }
  // merge across 64 lanes (disjoint candidate sets)
  for (int off = 1; off < 64; off <<= 1) {
    float ob1 = __shfl_xor(b1, off), ob2 = __shfl_xor(b2, off);
    int   oi1 = __shfl_xor(i1, off), oi2 = __shfl_xor(i2, off);
    if (better(b1, i1, ob1, oi1)) {
      if (better(ob1, oi1, b2, i2)) { b2 = ob1; i2 = oi1; }
    } else {
      float nb2; int ni2;
      if (better(b1, i1, ob2, oi2)) { nb2 = b1; ni2 = i1; }
      else                          { nb2 = ob2; ni2 = oi2; }
      b1 = ob1; i1 = oi1; b2 = nb2; i2 = ni2;
    }
  }
  __shared__ float wb1[4], wb2[4];
  __shared__ int   wi1[4], wi2[4];
  if ((tid & 63) == 0) {
    int w = tid >> 6;
    wb1[w] = b1; wb2[w] = b2; wi1[w] = i1; wi2[w] = i2;
  }
  __syncthreads();
  if (tid == 0) {
    float B1 = wb1[0], B2 = wb2[0]; int I1 = wi1[0], I2 = wi2[0];
#pragma unroll
    for (int w = 1; w < 4; w++) {
      if (better(wb1[w], wi1[w], B1, I1)) {
        float nb2; int ni2;
        if (better(B1, I1, wb2[w], wi2[w])) { nb2 = B1; ni2 = I1; }
        else                                { nb2 = wb2[w]; ni2 = wi2[w]; }
        B1 = wb1[w]; I1 = wi1[w]; B2 = nb2; I2 = ni2;
      } else if (better(wb1[w], wi1[w], B2, I2)) {
        B2 = wb1[w]; I2 = wi1[w];
      }
    }
    cand[t] = make_int2(I1, I2);
  }
}

// ---------------- VQ: exact fp64 refine of the 2 candidates ----------------
__global__ __launch_bounds__(64) void vq_refine_kernel(
    const float* __restrict__ flat, const float* __restrict__ cb,
    const double* __restrict__ csq, const int2* __restrict__ cand,
    int* __restrict__ out_idx)
{
  int t = blockIdx.x, lane = threadIdx.x;
  int2 c = cand[t];
  const float* x = flat + ((size_t)t << 9);
  const float* c1 = cb + ((size_t)c.x << 9);
  const float* c2 = cb + ((size_t)c.y << 9);
  double s1 = 0.0, s2 = 0.0;
#pragma unroll
  for (int i = 0; i < 8; i++) {
    int d = lane + i * 64;
    double xv = x[d];
    s1 += xv * (double)c1[d];
    s2 += xv * (double)c2[d];
  }
  for (int off = 32; off; off >>= 1) { s1 += __shfl_down(s1, off); s2 += __shfl_down(s2, off); }
  if (lane == 0) {
    double d1 = csq[c.x] - 2.0 * s1;
    double d2 = csq[c.y] - 2.0 * s2;
    int bi = (d2 < d1 || (d2 == d1 && c.y < c.x)) ? c.y : c.x;
    out_idx[t] = bi;
  }
}

// ---------------- commit loss + histogram ----------------
__global__ __launch_bounds__(128) void commit_hist_kernel(
    const float* __restrict__ flat, const float* __restrict__ cb,
    const int* __restrict__ idx, double* __restrict__ commit_sum,
    float* __restrict__ counts)
{
  int t = blockIdx.x, tid = threadIdx.x;
  int code = idx[t];
  float4 a = ((const float4*)(flat + ((size_t)t << 9)))[tid];
  float4 c = ((const float4*)(cb + ((size_t)code << 9)))[tid];
  float dx = a.x - c.x, dy = a.y - c.y, dz = a.z - c.z, dw = a.w - c.w;
  double s = (double)dx * dx + (double)dy * dy + (double)dz * dz + (double)dw * dw;
  for (int off = 32; off; off >>= 1) s += __shfl_down(s, off);
  __shared__ double red[2];
  if ((tid & 63) == 0) red[tid >> 6] = s;
  __syncthreads();
  if (tid == 0) {
    atomicAdd(commit_sum, red[0] + red[1]);
    atomicAdd(counts + code, 1.0f);
  }
}

// ---------------- LayerNorm (fp32 in -> bf16 out) ----------------
__global__ __launch_bounds__(256) void ln_rows_kernel(
    const float* __restrict__ x, const float* __restrict__ g,
    const float* __restrict__ b, u16* __restrict__ y)
{
  int row = blockIdx.x, tid = threadIdx.x;
  const float* xr = x + (size_t)row * D_;
  float v0 = xr[tid], v1 = xr[tid + 256];
  float s = v0 + v1;
  for (int off = 32; off; off >>= 1) s += __shfl_down(s, off);
  __shared__ float red[4];
  __shared__ float bcast[2];
  if ((tid & 63) == 0) red[tid >> 6] = s;
  __syncthreads();
  if (tid == 0) bcast[0] = (red[0] + red[1] + red[2] + red[3]) * (1.f / 512.f);
  __syncthreads();
  float mu = bcast[0];
  float d0 = v0 - mu, d1 = v1 - mu;
  float q = d0 * d0 + d1 * d1;
  for (int off = 32; off; off >>= 1) q += __shfl_down(q, off);
  if ((tid & 63) == 0) red[tid >> 6] = q;
  __syncthreads();
  if (tid == 0) bcast[1] = rsqrtf((red[0] + red[1] + red[2] + red[3]) * (1.f / 512.f) + 1e-5f);
  __syncthreads();
  float rs = bcast[1];
  u16* yr = y + (size_t)row * D_;
  yr[tid]       = f2b(d0 * rs * g[tid] + b[tid]);
  yr[tid + 256] = f2b(d1 * rs * g[tid + 256] + b[tid + 256]);
}

// ---------------- weight convert fp32 [K][N] -> bf16 [N][K] ----------------
__global__ __launch_bounds__(256) void wconv_kernel(
    const float* __restrict__ W, u16* __restrict__ WT, int K, int N)
{
  __shared__ float tile[32][33];
  int t = threadIdx.x;
  int k0 = blockIdx.y * 32, n0 = blockIdx.x * 32;
  int ty = t >> 5, tx = t & 31;
#pragma unroll
  for (int i = 0; i < 4; i++)
    tile[ty + 8 * i][tx] = W[(size_t)(k0 + ty + 8 * i) * N + n0 + tx];
  __syncthreads();
#pragma unroll
  for (int i = 0; i < 4; i++)
    WT[(size_t)(n0 + ty + 8 * i) * K + k0 + tx] = f2b(tile[tx][ty + 8 * i]);
}

// ---------------- bf16 MFMA GEMM: C = act(A@B + bias) + resid ----------------
// A [M][K] bf16, BT [N][K] bf16. Outputs fp32 (Cf) and/or bf16 (Cb).
__global__ __launch_bounds__(256) void gemm_bf16_kernel(
    const u16* __restrict__ A, const u16* __restrict__ BT,
    const float* __restrict__ bias, const float* __restrict__ resid,
    float* __restrict__ Cf, u16* __restrict__ Cb,
    int M, int N, int K, int act)
{
  __shared__ __attribute__((aligned(16))) u16 As[128 * 40];
  __shared__ __attribute__((aligned(16))) u16 Bs[128 * 40];
  int tid = threadIdx.x;
  int lane = tid & 63, wave = tid >> 6;
  int wr = wave >> 1, wc = wave & 1;
  int row0 = blockIdx.y * 128, col0 = blockIdx.x * 128;
  int l15 = lane & 15, l4 = lane >> 4;
  int sr = tid >> 2, skc = tid & 3;          // staging: row, 8-elem k-chunk
  f32x4 acc[4][4] = {};
  for (int k0 = 0; k0 < K; k0 += 32) {
    __syncthreads();
    bf16x8 a0 = *(const bf16x8*)(A + (size_t)(row0 + sr) * K + k0 + skc * 8);
    bf16x8 a1 = *(const bf16x8*)(A + (size_t)(row0 + 64 + sr) * K + k0 + skc * 8);
    bf16x8 b0 = *(const bf16x8*)(BT + (size_t)(col0 + sr) * K + k0 + skc * 8);
    bf16x8 b1 = *(const bf16x8*)(BT + (size_t)(col0 + 64 + sr) * K + k0 + skc * 8);
    *(bf16x8*)&As[sr * 40 + skc * 8] = a0;
    *(bf16x8*)&As[(64 + sr) * 40 + skc * 8] = a1;
    *(bf16x8*)&Bs[sr * 40 + skc * 8] = b0;
    *(bf16x8*)&Bs[(64 + sr) * 40 + skc * 8] = b1;
    __syncthreads();
    bf16x8 af[4], bfr[4];
#pragma unroll
    for (int m = 0; m < 4; m++)
      af[m] = *(const bf16x8*)&As[(wr * 64 + m * 16 + l15) * 40 + l4 * 8];
#pragma unroll
    for (int n = 0; n < 4; n++)
      bfr[n] = *(const bf16x8*)&Bs[(wc * 64 + n * 16 + l15) * 40 + l4 * 8];
#pragma unroll
    for (int m = 0; m < 4; m++)
#pragma unroll
      for (int n = 0; n < 4; n++)
        acc[m][n] = __builtin_amdgcn_mfma_f32_16x16x32_bf16(af[m], bfr[n], acc[m][n], 0, 0, 0);
  }
#pragma unroll
  for (int m = 0; m < 4; m++) {
#pragma unroll
    for (int n = 0; n < 4; n++) {
      int col = col0 + wc * 64 + n * 16 + l15;
      float bv = bias ? bias[col] : 0.f;
#pragma unroll
      for (int r = 0; r < 4; r++) {
        int row = row0 + wr * 64 + m * 16 + l4 * 4 + r;
        float v = acc[m][n][r] + bv;
        if (act == 1) v = gelu_f(v);
        if (resid) v += resid[(size_t)row * N + col];
        if (Cf) Cf[(size_t)row * N + col] = v;
        if (Cb) Cb[(size_t)row * N + col] = f2b(v);
      }
    }
  }
}

// ---------------- V transpose: src rows -> Vt [b*8+h][64][n_rows] ----------------
__global__ __launch_bounds__(256) void vt_kernel(
    const u16* __restrict__ src, size_t b_stride, int row_stride, int col0,
    int n_rows, u16* __restrict__ dst)
{
  __shared__ __attribute__((aligned(16))) u16 tile[32][72];
  int t = threadIdx.x;
  int bh = blockIdx.y;
  int b = bh >> 3, h = bh & 7;
  int n0 = blockIdx.x * 32;
  int n = t >> 3, dc = t & 7;
  *(bf16x8*)&tile[n][dc * 8] =
      *(const bf16x8*)(src + (size_t)b * b_stride + (size_t)(n0 + n) * row_stride + col0 + h * 64 + dc * 8);
  __syncthreads();
  int d = t >> 2, ns = t & 3;
  bf16x8 o;
#pragma unroll
  for (int i = 0; i < 8; i++) o[i] = (short)tile[ns * 8 + i][d];
  *(bf16x8*)(dst + ((size_t)bh * 64 + d) * n_rows + n0 + ns * 8) = o;
}

// ---------------- MFMA flash attention ----------------
__global__ __launch_bounds__(256) void attn_mfma_kernel(
    const u16* __restrict__ Q, size_t q_bs, int q_stride,
    const u16* __restrict__ Kp, size_t k_bs, int k_stride, int k_extra,
    const u16* __restrict__ Vt, const int* __restrict__ mask,
    float scale, u16* __restrict__ O, size_t o_bs, int n_keys)
{
  __shared__ __attribute__((aligned(16))) u16 Ks[32 * 72];
  __shared__ __attribute__((aligned(16))) u16 Vs[64 * 40];
  __shared__ __attribute__((aligned(16))) u16 Ps[4 * 16 * 40];
  __shared__ int m_sh[32];
  int tid = threadIdx.x, lane = tid & 63, wave = tid >> 6;
  int b = blockIdx.z, h = blockIdx.y, q0 = blockIdx.x * 64 + wave * 16;
  int l15 = lane & 15, l4 = lane >> 4;
  const u16* qrow = Q + (size_t)b * q_bs + (size_t)(q0 + l15) * q_stride + h * 64 + l4 * 8;
  bf16x8 qf0 = *(const bf16x8*)qrow;
  bf16x8 qf1 = *(const bf16x8*)(qrow + 32);
  f32x4 o_acc[4] = {};
  float m_run[4], l_run[4];
#pragma unroll
  for (int r = 0; r < 4; r++) { m_run[r] = -3.0e38f; l_run[r] = 0.f; }
  int skey = tid >> 3, sdc = tid & 7;
  int svd = tid >> 2, svk = tid & 3;
  const u16* kbase = Kp + (size_t)b * k_bs + k_extra + h * 64 + sdc * 8;
  const u16* vtbase = Vt + ((size_t)(b * 8 + h) * 64 + svd) * n_keys + svk * 8;

  for (int n0 = 0; n0 < n_keys; n0 += 32) {
    __syncthreads();
    bf16x8 kv_ = *(const bf16x8*)(kbase + (size_t)(n0 + skey) * k_stride);
    bf16x8 vv_ = *(const bf16x8*)(vtbase + n0);
    *(bf16x8*)&Ks[skey * 72 + sdc * 8] = kv_;
    *(bf16x8*)&Vs[svd * 40 + svk * 8] = vv_;
    if (mask && tid < 32) m_sh[tid] = mask[(size_t)b * n_keys + n0 + tid];
    __syncthreads();
    f32x4 sac[2] = {};
#pragma unroll
    for (int kb = 0; kb < 2; kb++) {
      bf16x8 kf0 = *(const bf16x8*)&Ks[(kb * 16 + l15) * 72 + l4 * 8];
      bf16x8 kf1 = *(const bf16x8*)&Ks[(kb * 16 + l15) * 72 + 32 + l4 * 8];
      sac[kb] = __builtin_amdgcn_mfma_f32_16x16x32_bf16(qf0, kf0, sac[kb], 0, 0, 0);
      sac[kb] = __builtin_amdgcn_mfma_f32_16x16x32_bf16(qf1, kf1, sac[kb], 0, 0, 0);
    }
    int mk0 = 1, mk1 = 1;
    if (mask) { mk0 = m_sh[l15]; mk1 = m_sh[16 + l15]; }
#pragma unroll
    for (int r = 0; r < 4; r++) {
      float s0 = mk0 ? sac[0][r] * scale : -3.0e38f;
      float s1 = mk1 ? sac[1][r] * scale : -3.0e38f;
      float tm = fmaxf(s0, s1);
      tm = fmaxf(tm, __shfl_xor(tm, 1));
      tm = fmaxf(tm, __shfl_xor(tm, 2));
      tm = fmaxf(tm, __shfl_xor(tm, 4));
      tm = fmaxf(tm, __shfl_xor(tm, 8));
      float mnew = fmaxf(m_run[r], tm);
      float al = __expf(m_run[r] - mnew);
      float p0 = (s0 < -1.0e37f) ? 0.f : __expf(s0 - mnew);
      float p1 = (s1 < -1.0e37f) ? 0.f : __expf(s1 - mnew);
      float ps = p0 + p1;
      ps += __shfl_xor(ps, 1); ps += __shfl_xor(ps, 2);
      ps += __shfl_xor(ps, 4); ps += __shfl_xor(ps, 8);
      l_run[r] = l_run[r] * al + ps;
      m_run[r] = mnew;
#pragma unroll
      for (int nb = 0; nb < 4; nb++) o_acc[nb][r] *= al;
      int qloc = l4 * 4 + r;
      Ps[wave * 640 + qloc * 40 + l15] = f2b(p0);
      Ps[wave * 640 + qloc * 40 + 16 + l15] = f2b(p1);
    }
    bf16x8 pf = *(const bf16x8*)&Ps[wave * 640 + l15 * 40 + l4 * 8];
#pragma unroll
    for (int nb = 0; nb < 4; nb++) {
      bf16x8 vf = *(const bf16x8*)&Vs[(nb * 16 + l15) * 40 + l4 * 8];
      o_acc[nb] = __builtin_amdgcn_mfma_f32_16x16x32_bf16(pf, vf, o_acc[nb], 0, 0, 0);
    }
  }
#pragma unroll
  for (int nb = 0; nb < 4; nb++) {
#pragma unroll
    for (int r = 0; r < 4; r++) {
      int row = q0 + l4 * 4 + r;
      int col = h * 64 + nb * 16 + l15;
      O[(size_t)b * o_bs + (size_t)row * 512 + col] = f2b(o_acc[nb][r] / l_run[r]);
    }
  }
}

// ---------------- gather rows by VQ index (fp32) ----------------
__global__ __launch_bounds__(128) void gather_kernel(
    const float* __restrict__ x2, const int* __restrict__ idx, float* __restrict__ out)
{
  int t = blockIdx.x;
  int b = t >> 11;
  int code = idx[t];
  const float4* src = (const float4*)(x2 + ((size_t)(b * M_ + code) << 9));
  float4* dst = (float4*)(out + ((size_t)t << 9));
  dst[threadIdx.x] = src[threadIdx.x];
}

// ---------------- scalars ----------------
__global__ void scalars_kernel(const float* __restrict__ counts,
                               const double* __restrict__ commit_sum,
                               float* __restrict__ out_tail)
{
  int tid = threadIdx.x;
  double p = (double)counts[tid] / 8192.0;
  double e = p * log(p + 1e-10);
  for (int off = 32; off; off >>= 1) e += __shfl_down(e, off);
  __shared__ double red[16];
  if ((tid & 63) == 0) red[tid >> 6] = e;
  __syncthreads();
  if (tid == 0) {
    double s = 0.0;
    for (int i = 0; i < 16; i++) s += red[i];
    out_tail[0] = (float)(*commit_sum / (8192.0 * 512.0));
    out_tail[1] = (float)exp(-s);
  }
}

extern "C" void kernel_launch(void* const* d_in, const int* in_sizes, int n_in,
                              void* d_out, int out_size, void* d_ws, size_t ws_size,
                              hipStream_t stream) {
  const float* ctx      = (const float*)d_in[0];
  const void*  mask_raw = d_in[1];
  const float* codebook = (const float*)d_in[2];
  const float* norm_g   = (const float*)d_in[3];
  const float* norm_b   = (const float*)d_in[4];
  const float* cnorm_g  = (const float*)d_in[5];
  const float* cnorm_b  = (const float*)d_in[6];
  const float* wq       = (const float*)d_in[7];
  const float* wkv      = (const float*)d_in[8];
  const float* wo       = (const float*)d_in[9];
  const float* wo_b     = (const float*)d_in[10];
  const float* a_norm_g = (const float*)d_in[11];
  const float* a_norm_b = (const float*)d_in[12];
  const float* a_qkv    = (const float*)d_in[13];
  const float* a_out    = (const float*)d_in[14];
  const float* f_norm_g = (const float*)d_in[15];
  const float* f_norm_b = (const float*)d_in[16];
  const float* f_w1     = (const float*)d_in[17];
  const float* f_w2     = (const float*)d_in[18];
  float* out = (float*)d_out;

  char* ws = (char*)d_ws;
  double* commit_sum = (double*)(ws + 0);
  int*    mask_flag  = (int*)(ws + 64);
  float*  counts     = (float*)(ws + 128);
  double* code_sq    = (double*)(ws + 128 + 4096);
  float*  csqf       = (float*)(ws + 128 + 4096 + 8192);
  int*    indices    = (int*)(ws + 128 + 4096 + 8192 + 4096);
  int*    mask_norm  = (int*)(ws + 128 + 4096 + 8192 + 4096 + 32768);
  int2*   cand       = (int2*)(ws + 128 + 4096 + 8192 + 4096 + 32768 + 32768);

  // big aliased pool: VQ buffers (phase 1) overlap pipeline buffers (phase 2) —
  // safe because all phase-1 consumers complete before phase-2 writers (in-stream order).
  char* pool = ws + (1 << 20);
  u16*   vqA  = (u16*)(pool);                         // [8192][1536] bf16 = 25.2 MB
  u16*   vqBT = (u16*)(pool + ((size_t)26 << 20));    // [1024][1536] bf16 = 3.2 MB
  float* vqS  = (float*)(pool + ((size_t)30 << 20));  // [8192][1024] f32 = 33.6 MB
  char* regA  = pool;                              // 16 MB: kv_b -> qkv2_b
  char* regB  = pool + ((size_t)16 << 20);         // 8 MB: ctx_ln_b -> VtS
  char* regC  = pool + ((size_t)24 << 20);         // 8 MB: VtX -> x1_f
  char* regD  = pool + ((size_t)32 << 20);         // 8 MB: x0_f
  char* regE  = pool + ((size_t)40 << 20);         // 4 MB: att_out/h/o2/hf (bf16)
  char* regF  = pool + ((size_t)44 << 20);         // 8 MB: g_b
  char* regG  = pool + ((size_t)52 << 20);         // 8 MB: x2_f
  size_t woff = (1 << 20) + ((size_t)64 << 20);
  u16* wqT    = (u16*)(ws + woff); woff += (size_t)512 * 512 * 2;
  u16* wkvT   = (u16*)(ws + woff); woff += (size_t)1024 * 512 * 2;
  u16* woT    = (u16*)(ws + woff); woff += (size_t)512 * 512 * 2;
  u16* aqkvT  = (u16*)(ws + woff); woff += (size_t)1536 * 512 * 2;
  u16* aoutT  = (u16*)(ws + woff); woff += (size_t)512 * 512 * 2;
  u16* fw1T   = (u16*)(ws + woff); woff += (size_t)1024 * 512 * 2;
  u16* fw2T   = (u16*)(ws + woff); woff += (size_t)512 * 1024 * 2;
  u16* xq_b   = (u16*)(ws + woff); woff += (size_t)1024 * 512 * 2;
  u16* qs_b   = (u16*)(ws + woff); woff += (size_t)1024 * 512 * 2;

  u16* kv_b     = (u16*)regA;
  u16* qkv2_b   = (u16*)regA;
  u16* ctx_ln_b = (u16*)regB;
  u16* VtS      = (u16*)regB;
  u16* VtX      = (u16*)regC;
  float* x1_f   = (float*)regC;
  float* x0_f   = (float*)regD;
  u16* att_out_b = (u16*)regE;
  u16* h_b       = (u16*)regE;
  u16* o2_b      = (u16*)regE;
  u16* hf_b      = (u16*)regE;
  u16* g_b      = (u16*)regF;
  float* x2_f   = (float*)regG;

  // ---- VQ (phase 1, uses pool as vqA/vqBT/vqS) ----
  zero_init_kernel<<<1, 1024, 0, stream>>>(counts, commit_sum);
  mask_detect_kernel<<<1, 256, 0, stream>>>((const unsigned char*)mask_raw, mask_flag);
  mask_norm_kernel<<<32, 256, 0, stream>>>(mask_raw, mask_flag, mask_norm);
  code_sq_kernel<<<1024, 128, 0, stream>>>(codebook, code_sq, csqf);
  vq_split_x_kernel<<<8192, 256, 0, stream>>>(ctx, vqA);
  vq_split_c_kernel<<<1024, 256, 0, stream>>>(codebook, vqBT);
  gemm_bf16_kernel<<<dim3(8, 64), 256, 0, stream>>>(vqA, vqBT, nullptr, nullptr,
                                                    vqS, nullptr, 8192, 1024, 1536, 0);
  vq_top2_kernel<<<8192, 256, 0, stream>>>(vqS, csqf, cand);
  vq_refine_kernel<<<8192, 64, 0, stream>>>(ctx, codebook, code_sq, cand, indices);
  commit_hist_kernel<<<8192, 128, 0, stream>>>(ctx, codebook, indices, commit_sum, counts);

  // ---- weight conversion (fp32 [K][N] -> bf16 [N][K]) ----
  wconv_kernel<<<dim3(16, 16), 256, 0, stream>>>(wq,    wqT,   512, 512);
  wconv_kernel<<<dim3(32, 16), 256, 0, stream>>>(wkv,   wkvT,  512, 1024);
  wconv_kernel<<<dim3(16, 16), 256, 0, stream>>>(wo,    woT,   512, 512);
  wconv_kernel<<<dim3(48, 16), 256, 0, stream>>>(a_qkv, aqkvT, 512, 1536);
  wconv_kernel<<<dim3(16, 16), 256, 0, stream>>>(a_out, aoutT, 512, 512);
  wconv_kernel<<<dim3(32, 16), 256, 0, stream>>>(f_w1,  fw1T,  512, 1024);
  wconv_kernel<<<dim3(16, 32), 256, 0, stream>>>(f_w2,  fw2T,  1024, 512);

  // ---- Cross-attention (phase 2, pool reused as regA..regG) ----
  ln_rows_kernel<<<1024, 256, 0, stream>>>(codebook, norm_g, norm_b, xq_b);
  gemm_bf16_kernel<<<dim3(4, 8), 256, 0, stream>>>(xq_b, wqT, nullptr, nullptr,
                                                   nullptr, qs_b, 1024, 512, 512, 0);
  ln_rows_kernel<<<8192, 256, 0, stream>>>(ctx, cnorm_g, cnorm_b, ctx_ln_b);
  gemm_bf16_kernel<<<dim3(8, 64), 256, 0, stream>>>(ctx_ln_b, wkvT, nullptr, nullptr,
                                                    nullptr, kv_b, 8192, 1024, 512, 0);
  vt_kernel<<<dim3(64, 32), 256, 0, stream>>>(kv_b, (size_t)2048 * 1024, 1024, 512, 2048, VtX);
  attn_mfma_kernel<<<dim3(16, 8, 4), 256, 0, stream>>>(
      qs_b, 0, 512, kv_b, (size_t)2048 * 1024, 1024, 0, VtX, mask_norm,
      0.125f, att_out_b, (size_t)1024 * 512, 2048);
  gemm_bf16_kernel<<<dim3(4, 32), 256, 0, stream>>>(att_out_b, woT, wo_b, nullptr,
                                                    x0_f, nullptr, 4096, 512, 512, 0);

  // ---- Transformer refinement ----
  ln_rows_kernel<<<4096, 256, 0, stream>>>(x0_f, a_norm_g, a_norm_b, h_b);
  gemm_bf16_kernel<<<dim3(12, 32), 256, 0, stream>>>(h_b, aqkvT, nullptr, nullptr,
                                                     nullptr, qkv2_b, 4096, 1536, 512, 0);
  vt_kernel<<<dim3(32, 32), 256, 0, stream>>>(qkv2_b, (size_t)1024 * 1536, 1536, 1024, 1024, VtS);
  attn_mfma_kernel<<<dim3(16, 8, 4), 256, 0, stream>>>(
      qkv2_b, (size_t)1024 * 1536, 1536, qkv2_b, (size_t)1024 * 1536, 1536, 512, VtS, nullptr,
      0.125f, o2_b, (size_t)1024 * 512, 1024);
  gemm_bf16_kernel<<<dim3(4, 32), 256, 0, stream>>>(o2_b, aoutT, nullptr, x0_f,
                                                    x1_f, nullptr, 4096, 512, 512, 0);
  ln_rows_kernel<<<4096, 256, 0, stream>>>(x1_f, f_norm_g, f_norm_b, hf_b);
  gemm_bf16_kernel<<<dim3(8, 32), 256, 0, stream>>>(hf_b, fw1T, nullptr, nullptr,
                                                    nullptr, g_b, 4096, 1024, 512, 1);
  gemm_bf16_kernel<<<dim3(4, 32), 256, 0, stream>>>(g_b, fw2T, nullptr, x1_f,
                                                    x2_f, nullptr, 4096, 512, 1024, 0);

  // ---- Gather + scalars ----
  gather_kernel<<<8192, 128, 0, stream>>>(x2_f, indices, out);
  scalars_kernel<<<1, 1024, 0, stream>>>(counts, commit_sum, out + (size_t)B_ * N_ * D_);
}

// Round 5
// 525.256 us; speedup vs baseline: 4.3850x; 1.1954x over previous
//
#include <hip/hip_runtime.h>
#include <math.h>

#define B_ 4
#define N_ 2048
#define D_ 512
#define M_ 1024
#define H_ 8
#define DH_ 64
#define I_ 512
#define FF_ 1024

typedef unsigned short u16;
typedef __attribute__((ext_vector_type(8))) short bf16x8;
typedef __attribute__((ext_vector_type(4))) float f32x4;

__device__ inline u16 f2b(float f) {           // fp32 -> bf16 RNE
  union { float f; unsigned int u; } v; v.f = f;
  unsigned int u = v.u;
  u += 0x7fffu + ((u >> 16) & 1u);
  return (u16)(u >> 16);
}
__device__ inline float b2f(u16 h) {
  union { unsigned int u; float f; } v; v.u = ((unsigned int)h) << 16;
  return v.f;
}

__device__ inline float gelu_f(float x) {
  float x3 = x * x * x;
  return 0.5f * x * (1.f + tanhf(0.7978845608028654f * (x + 0.044715f * x3)));
}

// ---------------- zero accumulators ----------------
__global__ void zero_init_kernel(float* counts, double* commit_sum) {
  int t = threadIdx.x;
  counts[t] = 0.f;
  if (t == 0) *commit_sum = 0.0;
}

// ---------------- mask dtype detection / normalize ----------------
__global__ void mask_detect_kernel(const unsigned char* __restrict__ mb, int* flag) {
  __shared__ int any;
  if (threadIdx.x == 0) any = 0;
  __syncthreads();
  int acc = 0;
  for (int i = threadIdx.x; i < 8192; i += 256)
    if (i & 3) acc |= mb[i];
  if (acc) atomicOr(&any, 1);
  __syncthreads();
  if (threadIdx.x == 0) *flag = any;
}

__global__ void mask_norm_kernel(const void* __restrict__ mraw,
                                 const int* __restrict__ flag,
                                 int* __restrict__ mnorm) {
  int i = blockIdx.x * 256 + threadIdx.x;
  int v;
  if (*flag) v = ((const unsigned char*)mraw)[i];
  else       v = ((const int*)mraw)[i];
  mnorm[i] = (v != 0) ? 1 : 0;
}

// ---------------- codebook row sum-of-squares (fp64 + fp32 copy) ----------------
__global__ __launch_bounds__(128) void code_sq_kernel(const float* __restrict__ cb,
                                                      double* __restrict__ csq,
                                                      float* __restrict__ csqf) {
  int row = blockIdx.x, tid = threadIdx.x;
  const float4* r4 = (const float4*)(cb + (size_t)row * D_);
  float4 v = r4[tid];
  double s = (double)v.x * v.x + (double)v.y * v.y + (double)v.z * v.z + (double)v.w * v.w;
  for (int off = 32; off; off >>= 1) s += __shfl_down(s, off);
  __shared__ double red[2];
  if ((tid & 63) == 0) red[tid >> 6] = s;
  __syncthreads();
  if (tid == 0) { csq[row] = red[0] + red[1]; csqf[row] = (float)(red[0] + red[1]); }
}

// ---------------- VQ: hi/lo split builders ----------------
__global__ __launch_bounds__(256) void vq_split_x_kernel(
    const float* __restrict__ flat, u16* __restrict__ A)
{
  int t = blockIdx.x;
  const float* xr = flat + ((size_t)t << 9);
  u16* ar = A + (size_t)t * 1536;
#pragma unroll
  for (int i = 0; i < 2; i++) {
    int j = threadIdx.x + i * 256;
    float x = xr[j];
    u16 h = f2b(x);
    u16 l = f2b(x - b2f(h));
    ar[j] = h; ar[512 + j] = l; ar[1024 + j] = h;
  }
}
__global__ __launch_bounds__(256) void vq_split_c_kernel(
    const float* __restrict__ cb, u16* __restrict__ BT)
{
  int c = blockIdx.x;
  const float* cr = cb + ((size_t)c << 9);
  u16* br = BT + (size_t)c * 1536;
#pragma unroll
  for (int i = 0; i < 2; i++) {
    int j = threadIdx.x + i * 256;
    float x = cr[j];
    u16 h = f2b(x);
    u16 l = f2b(x - b2f(h));
    br[j] = h; br[512 + j] = h; br[1024 + j] = l;
  }
}

// ---------------- VQ: per-token top-2 over S row ----------------
__device__ inline bool better(float d1, int i1, float d2, int i2) {
  return d1 < d2 || (d1 == d2 && i1 < i2);
}

__global__ __launch_bounds__(256) void vq_top2_kernel(
    const float* __restrict__ S, const float* __restrict__ csqf,
    int2* __restrict__ cand)
{
  int t = blockIdx.x, tid = threadIdx.x;
  float4 sv = ((const float4*)(S + ((size_t)t << 10)))[tid];
  float4 cq = ((const float4*)csqf)[tid];
  int c0 = tid << 2;
  float b1, b2; int i1, i2;
  b1 = cq.x - 2.f * sv.x; i1 = c0;
  b2 = 1e30f; i2 = 1 << 20;
  {
    float d; int c;
    d = cq.y - 2.f * sv.y; c = c0 + 1;
    if (better(d, c, b1, i1)) { b2 = b1; i2 = i1; b1 = d; i1 = c; }
    else if (better(d, c, b2, i2)) { b2 = d; i2 = c; }
    d = cq.z - 2.f * sv.z; c = c0 + 2;
    if (better(d, c, b1, i1)) { b2 = b1; i2 = i1; b1 = d; i1 = c; }
    else if (better(d, c, b2, i2)) { b2 = d; i2 = c; }
    d = cq.w - 2.f * sv.w; c = c0 + 3;
    if (better(d, c, b1, i1)) { b2 = b1; i2 = i1; b1 = d; i1 = c; }
    else if (better(d, c, b2, i2)) { b2 = d; i2 = c; }
  }
  for (int off = 1; off < 64; off <<= 1) {
    float ob1 = __shfl_xor(b1, off), ob2 = __shfl_xor(b2, off);
    int   oi1 = __shfl_xor(i1, off), oi2 = __shfl_xor(i2, off);
    if (better(b1, i1, ob1, oi1)) {
      if (better(ob1, oi1, b2, i2)) { b2 = ob1; i2 = oi1; }
    } else {
      float nb2; int ni2;
      if (better(b1, i1, ob2, oi2)) { nb2 = b1; ni2 = i1; }
      else                          { nb2 = ob2; ni2 = oi2; }
      b1 = ob1; i1 = oi1; b2 = nb2; i2 = ni2;
    }
  }
  __shared__ float wb1[4], wb2[4];
  __shared__ int   wi1[4], wi2[4];
  if ((tid & 63) == 0) {
    int w = tid >> 6;
    wb1[w] = b1; wb2[w] = b2; wi1[w] = i1; wi2[w] = i2;
  }
  __syncthreads();
  if (tid == 0) {
    float B1 = wb1[0], B2 = wb2[0]; int I1 = wi1[0], I2 = wi2[0];
#pragma unroll
    for (int w = 1; w < 4; w++) {
      if (better(wb1[w], wi1[w], B1, I1)) {
        float nb2; int ni2;
        if (better(B1, I1, wb2[w], wi2[w])) { nb2 = B1; ni2 = I1; }
        else                                { nb2 = wb2[w]; ni2 = wi2[w]; }
        B1 = wb1[w]; I1 = wi1[w]; B2 = nb2; I2 = ni2;
      } else if (better(wb1[w], wi1[w], B2, I2)) {
        B2 = wb1[w]; I2 = wi1[w];
      }
    }
    cand[t] = make_int2(I1, I2);
  }
}

// ---------------- VQ: exact fp64 refine of the 2 candidates ----------------
__global__ __launch_bounds__(64) void vq_refine_kernel(
    const float* __restrict__ flat, const float* __restrict__ cb,
    const double* __restrict__ csq, const int2* __restrict__ cand,
    int* __restrict__ out_idx)
{
  int t = blockIdx.x, lane = threadIdx.x;
  int2 c = cand[t];
  const float* x = flat + ((size_t)t << 9);
  const float* c1 = cb + ((size_t)c.x << 9);
  const float* c2 = cb + ((size_t)c.y << 9);
  double s1 = 0.0, s2 = 0.0;
#pragma unroll
  for (int i = 0; i < 8; i++) {
    int d = lane + i * 64;
    double xv = x[d];
    s1 += xv * (double)c1[d];
    s2 += xv * (double)c2[d];
  }
  for (int off = 32; off; off >>= 1) { s1 += __shfl_down(s1, off); s2 += __shfl_down(s2, off); }
  if (lane == 0) {
    double d1 = csq[c.x] - 2.0 * s1;
    double d2 = csq[c.y] - 2.0 * s2;
    int bi = (d2 < d1 || (d2 == d1 && c.y < c.x)) ? c.y : c.x;
    out_idx[t] = bi;
  }
}

// ---------------- commit loss + histogram ----------------
__global__ __launch_bounds__(128) void commit_hist_kernel(
    const float* __restrict__ flat, const float* __restrict__ cb,
    const int* __restrict__ idx, double* __restrict__ commit_sum,
    float* __restrict__ counts)
{
  int t = blockIdx.x, tid = threadIdx.x;
  int code = idx[t];
  float4 a = ((const float4*)(flat + ((size_t)t << 9)))[tid];
  float4 c = ((const float4*)(cb + ((size_t)code << 9)))[tid];
  float dx = a.x - c.x, dy = a.y - c.y, dz = a.z - c.z, dw = a.w - c.w;
  double s = (double)dx * dx + (double)dy * dy + (double)dz * dz + (double)dw * dw;
  for (int off = 32; off; off >>= 1) s += __shfl_down(s, off);
  __shared__ double red[2];
  if ((tid & 63) == 0) red[tid >> 6] = s;
  __syncthreads();
  if (tid == 0) {
    atomicAdd(commit_sum, red[0] + red[1]);
    atomicAdd(counts + code, 1.0f);
  }
}

// ---------------- LayerNorm (fp32 in -> bf16 out) ----------------
__global__ __launch_bounds__(256) void ln_rows_kernel(
    const float* __restrict__ x, const float* __restrict__ g,
    const float* __restrict__ b, u16* __restrict__ y)
{
  int row = blockIdx.x, tid = threadIdx.x;
  const float* xr = x + (size_t)row * D_;
  float v0 = xr[tid], v1 = xr[tid + 256];
  float s = v0 + v1;
  for (int off = 32; off; off >>= 1) s += __shfl_down(s, off);
  __shared__ float red[4];
  __shared__ float bcast[2];
  if ((tid & 63) == 0) red[tid >> 6] = s;
  __syncthreads();
  if (tid == 0) bcast[0] = (red[0] + red[1] + red[2] + red[3]) * (1.f / 512.f);
  __syncthreads();
  float mu = bcast[0];
  float d0 = v0 - mu, d1 = v1 - mu;
  float q = d0 * d0 + d1 * d1;
  for (int off = 32; off; off >>= 1) q += __shfl_down(q, off);
  if ((tid & 63) == 0) red[tid >> 6] = q;
  __syncthreads();
  if (tid == 0) bcast[1] = rsqrtf((red[0] + red[1] + red[2] + red[3]) * (1.f / 512.f) + 1e-5f);
  __syncthreads();
  float rs = bcast[1];
  u16* yr = y + (size_t)row * D_;
  yr[tid]       = f2b(d0 * rs * g[tid] + b[tid]);
  yr[tid + 256] = f2b(d1 * rs * g[tid + 256] + b[tid + 256]);
}

// ---------------- weight convert fp32 [K][N] -> bf16 [N][K] ----------------
__global__ __launch_bounds__(256) void wconv_kernel(
    const float* __restrict__ W, u16* __restrict__ WT, int K, int N)
{
  __shared__ float tile[32][33];
  int t = threadIdx.x;
  int k0 = blockIdx.y * 32, n0 = blockIdx.x * 32;
  int ty = t >> 5, tx = t & 31;
#pragma unroll
  for (int i = 0; i < 4; i++)
    tile[ty + 8 * i][tx] = W[(size_t)(k0 + ty + 8 * i) * N + n0 + tx];
  __syncthreads();
#pragma unroll
  for (int i = 0; i < 4; i++)
    WT[(size_t)(n0 + ty + 8 * i) * K + k0 + tx] = f2b(tile[tx][ty + 8 * i]);
}

// ---------------- bf16 MFMA GEMM: C = act(A@B + bias) + resid ----------------
__global__ __launch_bounds__(256) void gemm_bf16_kernel(
    const u16* __restrict__ A, const u16* __restrict__ BT,
    const float* __restrict__ bias, const float* __restrict__ resid,
    float* __restrict__ Cf, u16* __restrict__ Cb,
    int M, int N, int K, int act)
{
  __shared__ __attribute__((aligned(16))) u16 As[128 * 40];
  __shared__ __attribute__((aligned(16))) u16 Bs[128 * 40];
  int tid = threadIdx.x;
  int lane = tid & 63, wave = tid >> 6;
  int wr = wave >> 1, wc = wave & 1;
  int row0 = blockIdx.y * 128, col0 = blockIdx.x * 128;
  int l15 = lane & 15, l4 = lane >> 4;
  int sr = tid >> 2, skc = tid & 3;
  f32x4 acc[4][4] = {};
  for (int k0 = 0; k0 < K; k0 += 32) {
    __syncthreads();
    bf16x8 a0 = *(const bf16x8*)(A + (size_t)(row0 + sr) * K + k0 + skc * 8);
    bf16x8 a1 = *(const bf16x8*)(A + (size_t)(row0 + 64 + sr) * K + k0 + skc * 8);
    bf16x8 b0 = *(const bf16x8*)(BT + (size_t)(col0 + sr) * K + k0 + skc * 8);
    bf16x8 b1 = *(const bf16x8*)(BT + (size_t)(col0 + 64 + sr) * K + k0 + skc * 8);
    *(bf16x8*)&As[sr * 40 + skc * 8] = a0;
    *(bf16x8*)&As[(64 + sr) * 40 + skc * 8] = a1;
    *(bf16x8*)&Bs[sr * 40 + skc * 8] = b0;
    *(bf16x8*)&Bs[(64 + sr) * 40 + skc * 8] = b1;
    __syncthreads();
    bf16x8 af[4], bfr[4];
#pragma unroll
    for (int m = 0; m < 4; m++)
      af[m] = *(const bf16x8*)&As[(wr * 64 + m * 16 + l15) * 40 + l4 * 8];
#pragma unroll
    for (int n = 0; n < 4; n++)
      bfr[n] = *(const bf16x8*)&Bs[(wc * 64 + n * 16 + l15) * 40 + l4 * 8];
#pragma unroll
    for (int m = 0; m < 4; m++)
#pragma unroll
      for (int n = 0; n < 4; n++)
        acc[m][n] = __builtin_amdgcn_mfma_f32_16x16x32_bf16(af[m], bfr[n], acc[m][n], 0, 0, 0);
  }
#pragma unroll
  for (int m = 0; m < 4; m++) {
#pragma unroll
    for (int n = 0; n < 4; n++) {
      int col = col0 + wc * 64 + n * 16 + l15;
      float bv = bias ? bias[col] : 0.f;
#pragma unroll
      for (int r = 0; r < 4; r++) {
        int row = row0 + wr * 64 + m * 16 + l4 * 4 + r;
        float v = acc[m][n][r] + bv;
        if (act == 1) v = gelu_f(v);
        if (resid) v += resid[(size_t)row * N + col];
        if (Cf) Cf[(size_t)row * N + col] = v;
        if (Cb) Cb[(size_t)row * N + col] = f2b(v);
      }
    }
  }
}

// ---------------- V transpose: src rows -> Vt [b*8+h][64][n_rows] ----------------
__global__ __launch_bounds__(256) void vt_kernel(
    const u16* __restrict__ src, size_t b_stride, int row_stride, int col0,
    int n_rows, u16* __restrict__ dst)
{
  __shared__ __attribute__((aligned(16))) u16 tile[32][72];
  int t = threadIdx.x;
  int bh = blockIdx.y;
  int b = bh >> 3, h = bh & 7;
  int n0 = blockIdx.x * 32;
  int n = t >> 3, dc = t & 7;
  *(bf16x8*)&tile[n][dc * 8] =
      *(const bf16x8*)(src + (size_t)b * b_stride + (size_t)(n0 + n) * row_stride + col0 + h * 64 + dc * 8);
  __syncthreads();
  int d = t >> 2, ns = t & 3;
  bf16x8 o;
#pragma unroll
  for (int i = 0; i < 8; i++) o[i] = (short)tile[ns * 8 + i][d];
  *(bf16x8*)(dst + ((size_t)bh * 64 + d) * n_rows + n0 + ns * 8) = o;
}

// ---------------- MFMA flash attention (swapped QK^T, KVBLK=64, defer-max) ----------------
// S^T = mfma(K_frag, Q_frag): query = lane&15, keys = kb*16 + (lane>>4)*4 + r.
// Softmax is lane-local over 16 reg values + 2 shfls (xor 16,32).
__global__ __launch_bounds__(256, 2) void attn_mfma_kernel(
    const u16* __restrict__ Q, size_t q_bs, int q_stride,
    const u16* __restrict__ Kp, size_t k_bs, int k_stride, int k_extra,
    const u16* __restrict__ Vt, const int* __restrict__ mask,
    float scale, u16* __restrict__ O, size_t o_bs, int n_keys)
{
  __shared__ __attribute__((aligned(16))) u16 Ks[64 * 72];
  __shared__ __attribute__((aligned(16))) u16 Vs[64 * 72];
  __shared__ __attribute__((aligned(16))) u16 Ps[4][16 * 72];
  __shared__ unsigned char msk[64];
  int tid = threadIdx.x, lane = tid & 63, wave = tid >> 6;
  int b = blockIdx.z, h = blockIdx.y, q0 = blockIdx.x * 64 + wave * 16;
  int l15 = lane & 15, l4 = lane >> 4;
  const u16* qrow = Q + (size_t)b * q_bs + (size_t)(q0 + l15) * q_stride + h * 64 + l4 * 8;
  bf16x8 qf0 = *(const bf16x8*)qrow;
  bf16x8 qf1 = *(const bf16x8*)(qrow + 32);
  f32x4 o_acc[4] = {};
  float m_run = -3.0e38f, l_run = 0.f;     // per-lane: query = l15 (replicated over l4)
  int srow = tid >> 2, schunk = tid & 3;
  const u16* kbase = Kp + (size_t)b * k_bs + k_extra + h * 64;
  const u16* vtbase = Vt + (size_t)(b * 8 + h) * 64 * n_keys;

  for (int n0 = 0; n0 < n_keys; n0 += 64) {
    __syncthreads();
    {
      const u16* krow = kbase + (size_t)(n0 + srow) * k_stride;
      *(bf16x8*)&Ks[srow * 72 + schunk * 8]       = *(const bf16x8*)(krow + schunk * 8);
      *(bf16x8*)&Ks[srow * 72 + (schunk + 4) * 8] = *(const bf16x8*)(krow + (schunk + 4) * 8);
      const u16* vrow = vtbase + (size_t)srow * n_keys + n0;
      *(bf16x8*)&Vs[srow * 72 + schunk * 8]       = *(const bf16x8*)(vrow + schunk * 8);
      *(bf16x8*)&Vs[srow * 72 + (schunk + 4) * 8] = *(const bf16x8*)(vrow + (schunk + 4) * 8);
      if (mask && tid < 64) msk[tid] = (unsigned char)(mask[(size_t)b * n_keys + n0 + tid] != 0);
    }
    __syncthreads();
    // swapped QK^T
    f32x4 sac[4];
#pragma unroll
    for (int kb = 0; kb < 4; kb++) {
      bf16x8 kf0 = *(const bf16x8*)&Ks[(kb * 16 + l15) * 72 + l4 * 8];
      bf16x8 kf1 = *(const bf16x8*)&Ks[(kb * 16 + l15) * 72 + 32 + l4 * 8];
      f32x4 z = {};
      z = __builtin_amdgcn_mfma_f32_16x16x32_bf16(kf0, qf0, z, 0, 0, 0);
      sac[kb] = __builtin_amdgcn_mfma_f32_16x16x32_bf16(kf1, qf1, z, 0, 0, 0);
    }
    // lane-local softmax over 16 values (keys kb*16 + l4*4 + r), query = l15
    float sv[16];
    float pmax = -3.0e38f;
#pragma unroll
    for (int kb = 0; kb < 4; kb++) {
      unsigned int mw = mask ? *(const unsigned int*)&msk[kb * 16 + l4 * 4] : 0x01010101u;
#pragma unroll
      for (int r = 0; r < 4; r++) {
        float s = sac[kb][r] * scale;
        if (!((mw >> (8 * r)) & 1u)) s = -3.0e38f;
        sv[kb * 4 + r] = s;
        pmax = fmaxf(pmax, s);
      }
    }
    pmax = fmaxf(pmax, __shfl_xor(pmax, 16));
    pmax = fmaxf(pmax, __shfl_xor(pmax, 32));
    // defer-max: only rescale when some query's max grew by > 8
    if (!__all(pmax - m_run <= 8.f)) {
      float mnew = fmaxf(m_run, pmax);
      float al = __expf(m_run - mnew);
      l_run *= al;
      m_run = mnew;
      float alr[4];
#pragma unroll
      for (int r = 0; r < 4; r++) alr[r] = __shfl(al, l4 * 4 + r, 64);
#pragma unroll
      for (int nb = 0; nb < 4; nb++)
#pragma unroll
        for (int r = 0; r < 4; r++) o_acc[nb][r] *= alr[r];
    }
    float psum = 0.f;
    u16 pb[16];
#pragma unroll
    for (int i = 0; i < 16; i++) {
      float p = (sv[i] < -1.0e37f) ? 0.f : __expf(sv[i] - m_run);
      psum += p;
      pb[i] = f2b(p);
    }
    psum += __shfl_xor(psum, 16);
    psum += __shfl_xor(psum, 32);
    l_run += psum;
    // store P^T into per-wave LDS: Ps[wave][q=l15][key]
#pragma unroll
    for (int kb = 0; kb < 4; kb++) {
      uint2 w;
      w.x = (unsigned int)pb[kb * 4 + 0] | ((unsigned int)pb[kb * 4 + 1] << 16);
      w.y = (unsigned int)pb[kb * 4 + 2] | ((unsigned int)pb[kb * 4 + 3] << 16);
      *(uint2*)&Ps[wave][l15 * 72 + kb * 16 + l4 * 4] = w;
    }
    // PV: O[q][d] += P[q][k] * V[k][d]
#pragma unroll
    for (int c = 0; c < 2; c++) {
      bf16x8 pf = *(const bf16x8*)&Ps[wave][l15 * 72 + c * 32 + l4 * 8];
#pragma unroll
      for (int nb = 0; nb < 4; nb++) {
        bf16x8 vf = *(const bf16x8*)&Vs[(nb * 16 + l15) * 72 + c * 32 + l4 * 8];
        o_acc[nb] = __builtin_amdgcn_mfma_f32_16x16x32_bf16(pf, vf, o_acc[nb], 0, 0, 0);
      }
    }
  }
  float lr[4];
#pragma unroll
  for (int r = 0; r < 4; r++) lr[r] = __shfl(l_run, l4 * 4 + r, 64);
#pragma unroll
  for (int nb = 0; nb < 4; nb++) {
#pragma unroll
    for (int r = 0; r < 4; r++) {
      int row = q0 + l4 * 4 + r;
      int col = h * 64 + nb * 16 + l15;
      O[(size_t)b * o_bs + (size_t)row * 512 + col] = f2b(o_acc[nb][r] / lr[r]);
    }
  }
}

// ---------------- gather rows by VQ index (fp32) ----------------
__global__ __launch_bounds__(128) void gather_kernel(
    const float* __restrict__ x2, const int* __restrict__ idx, float* __restrict__ out)
{
  int t = blockIdx.x;
  int b = t >> 11;
  int code = idx[t];
  const float4* src = (const float4*)(x2 + ((size_t)(b * M_ + code) << 9));
  float4* dst = (float4*)(out + ((size_t)t << 9));
  dst[threadIdx.x] = src[threadIdx.x];
}

// ---------------- scalars ----------------
__global__ void scalars_kernel(const float* __restrict__ counts,
                               const double* __restrict__ commit_sum,
                               float* __restrict__ out_tail)
{
  int tid = threadIdx.x;
  double p = (double)counts[tid] / 8192.0;
  double e = p * log(p + 1e-10);
  for (int off = 32; off; off >>= 1) e += __shfl_down(e, off);
  __shared__ double red[16];
  if ((tid & 63) == 0) red[tid >> 6] = e;
  __syncthreads();
  if (tid == 0) {
    double s = 0.0;
    for (int i = 0; i < 16; i++) s += red[i];
    out_tail[0] = (float)(*commit_sum / (8192.0 * 512.0));
    out_tail[1] = (float)exp(-s);
  }
}

extern "C" void kernel_launch(void* const* d_in, const int* in_sizes, int n_in,
                              void* d_out, int out_size, void* d_ws, size_t ws_size,
                              hipStream_t stream) {
  const float* ctx      = (const float*)d_in[0];
  const void*  mask_raw = d_in[1];
  const float* codebook = (const float*)d_in[2];
  const float* norm_g   = (const float*)d_in[3];
  const float* norm_b   = (const float*)d_in[4];
  const float* cnorm_g  = (const float*)d_in[5];
  const float* cnorm_b  = (const float*)d_in[6];
  const float* wq       = (const float*)d_in[7];
  const float* wkv      = (const float*)d_in[8];
  const float* wo       = (const float*)d_in[9];
  const float* wo_b     = (const float*)d_in[10];
  const float* a_norm_g = (const float*)d_in[11];
  const float* a_norm_b = (const float*)d_in[12];
  const float* a_qkv    = (const float*)d_in[13];
  const float* a_out    = (const float*)d_in[14];
  const float* f_norm_g = (const float*)d_in[15];
  const float* f_norm_b = (const float*)d_in[16];
  const float* f_w1     = (const float*)d_in[17];
  const float* f_w2     = (const float*)d_in[18];
  float* out = (float*)d_out;

  char* ws = (char*)d_ws;
  double* commit_sum = (double*)(ws + 0);
  int*    mask_flag  = (int*)(ws + 64);
  float*  counts     = (float*)(ws + 128);
  double* code_sq    = (double*)(ws + 128 + 4096);
  float*  csqf       = (float*)(ws + 128 + 4096 + 8192);
  int*    indices    = (int*)(ws + 128 + 4096 + 8192 + 4096);
  int*    mask_norm  = (int*)(ws + 128 + 4096 + 8192 + 4096 + 32768);
  int2*   cand       = (int2*)(ws + 128 + 4096 + 8192 + 4096 + 32768 + 32768);

  char* pool = ws + (1 << 20);
  u16*   vqA  = (u16*)(pool);
  u16*   vqBT = (u16*)(pool + ((size_t)26 << 20));
  float* vqS  = (float*)(pool + ((size_t)30 << 20));
  char* regA  = pool;
  char* regB  = pool + ((size_t)16 << 20);
  char* regC  = pool + ((size_t)24 << 20);
  char* regD  = pool + ((size_t)32 << 20);
  char* regE  = pool + ((size_t)40 << 20);
  char* regF  = pool + ((size_t)44 << 20);
  char* regG  = pool + ((size_t)52 << 20);
  size_t woff = (1 << 20) + ((size_t)64 << 20);
  u16* wqT    = (u16*)(ws + woff); woff += (size_t)512 * 512 * 2;
  u16* wkvT   = (u16*)(ws + woff); woff += (size_t)1024 * 512 * 2;
  u16* woT    = (u16*)(ws + woff); woff += (size_t)512 * 512 * 2;
  u16* aqkvT  = (u16*)(ws + woff); woff += (size_t)1536 * 512 * 2;
  u16* aoutT  = (u16*)(ws + woff); woff += (size_t)512 * 512 * 2;
  u16* fw1T   = (u16*)(ws + woff); woff += (size_t)1024 * 512 * 2;
  u16* fw2T   = (u16*)(ws + woff); woff += (size_t)512 * 1024 * 2;
  u16* xq_b   = (u16*)(ws + woff); woff += (size_t)1024 * 512 * 2;
  u16* qs_b   = (u16*)(ws + woff); woff += (size_t)1024 * 512 * 2;

  u16* kv_b     = (u16*)regA;
  u16* qkv2_b   = (u16*)regA;
  u16* ctx_ln_b = (u16*)regB;
  u16* VtS      = (u16*)regB;
  u16* VtX      = (u16*)regC;
  float* x1_f   = (float*)regC;
  float* x0_f   = (float*)regD;
  u16* att_out_b = (u16*)regE;
  u16* h_b       = (u16*)regE;
  u16* o2_b      = (u16*)regE;
  u16* hf_b      = (u16*)regE;
  u16* g_b      = (u16*)regF;
  float* x2_f   = (float*)regG;

  // ---- VQ ----
  zero_init_kernel<<<1, 1024, 0, stream>>>(counts, commit_sum);
  mask_detect_kernel<<<1, 256, 0, stream>>>((const unsigned char*)mask_raw, mask_flag);
  mask_norm_kernel<<<32, 256, 0, stream>>>(mask_raw, mask_flag, mask_norm);
  code_sq_kernel<<<1024, 128, 0, stream>>>(codebook, code_sq, csqf);
  vq_split_x_kernel<<<8192, 256, 0, stream>>>(ctx, vqA);
  vq_split_c_kernel<<<1024, 256, 0, stream>>>(codebook, vqBT);
  gemm_bf16_kernel<<<dim3(8, 64), 256, 0, stream>>>(vqA, vqBT, nullptr, nullptr,
                                                    vqS, nullptr, 8192, 1024, 1536, 0);
  vq_top2_kernel<<<8192, 256, 0, stream>>>(vqS, csqf, cand);
  vq_refine_kernel<<<8192, 64, 0, stream>>>(ctx, codebook, code_sq, cand, indices);
  commit_hist_kernel<<<8192, 128, 0, stream>>>(ctx, codebook, indices, commit_sum, counts);

  // ---- weight conversion ----
  wconv_kernel<<<dim3(16, 16), 256, 0, stream>>>(wq,    wqT,   512, 512);
  wconv_kernel<<<dim3(32, 16), 256, 0, stream>>>(wkv,   wkvT,  512, 1024);
  wconv_kernel<<<dim3(16, 16), 256, 0, stream>>>(wo,    woT,   512, 512);
  wconv_kernel<<<dim3(48, 16), 256, 0, stream>>>(a_qkv, aqkvT, 512, 1536);
  wconv_kernel<<<dim3(16, 16), 256, 0, stream>>>(a_out, aoutT, 512, 512);
  wconv_kernel<<<dim3(32, 16), 256, 0, stream>>>(f_w1,  fw1T,  512, 1024);
  wconv_kernel<<<dim3(16, 32), 256, 0, stream>>>(f_w2,  fw2T,  1024, 512);

  // ---- Cross-attention ----
  ln_rows_kernel<<<1024, 256, 0, stream>>>(codebook, norm_g, norm_b, xq_b);
  gemm_bf16_kernel<<<dim3(4, 8), 256, 0, stream>>>(xq_b, wqT, nullptr, nullptr,
                                                   nullptr, qs_b, 1024, 512, 512, 0);
  ln_rows_kernel<<<8192, 256, 0, stream>>>(ctx, cnorm_g, cnorm_b, ctx_ln_b);
  gemm_bf16_kernel<<<dim3(8, 64), 256, 0, stream>>>(ctx_ln_b, wkvT, nullptr, nullptr,
                                                    nullptr, kv_b, 8192, 1024, 512, 0);
  vt_kernel<<<dim3(64, 32), 256, 0, stream>>>(kv_b, (size_t)2048 * 1024, 1024, 512, 2048, VtX);
  attn_mfma_kernel<<<dim3(16, 8, 4), 256, 0, stream>>>(
      qs_b, 0, 512, kv_b, (size_t)2048 * 1024, 1024, 0, VtX, mask_norm,
      0.125f, att_out_b, (size_t)1024 * 512, 2048);
  gemm_bf16_kernel<<<dim3(4, 32), 256, 0, stream>>>(att_out_b, woT, wo_b, nullptr,
                                                    x0_f, nullptr, 4096, 512, 512, 0);

  // ---- Transformer refinement ----
  ln_rows_kernel<<<4096, 256, 0, stream>>>(x0_f, a_norm_g, a_norm_b, h_b);
  gemm_bf16_kernel<<<dim3(12, 32), 256, 0, stream>>>(h_b, aqkvT, nullptr, nullptr,
                                                     nullptr, qkv2_b, 4096, 1536, 512, 0);
  vt_kernel<<<dim3(32, 32), 256, 0, stream>>>(qkv2_b, (size_t)1024 * 1536, 1536, 1024, 1024, VtS);
  attn_mfma_kernel<<<dim3(16, 8, 4), 256, 0, stream>>>(
      qkv2_b, (size_t)1024 * 1536, 1536, qkv2_b, (size_t)1024 * 1536, 1536, 512, VtS, nullptr,
      0.125f, o2_b, (size_t)1024 * 512, 1024);
  gemm_bf16_kernel<<<dim3(4, 32), 256, 0, stream>>>(o2_b, aoutT, nullptr, x0_f,
                                                    x1_f, nullptr, 4096, 512, 512, 0);
  ln_rows_kernel<<<4096, 256, 0, stream>>>(x1_f, f_norm_g, f_norm_b, hf_b);
  gemm_bf16_kernel<<<dim3(8, 32), 256, 0, stream>>>(hf_b, fw1T, nullptr, nullptr,
                                                    nullptr, g_b, 4096, 1024, 512, 1);
  gemm_bf16_kernel<<<dim3(4, 32), 256, 0, stream>>>(g_b, fw2T, nullptr, x1_f,
                                                    x2_f, nullptr, 4096, 512, 1024, 0);

  // ---- Gather + scalars ----
  gather_kernel<<<8192, 128, 0, stream>>>(x2_f, indices, out);
  scalars_kernel<<<1, 1024, 0, stream>>>(counts, commit_sum, out + (size_t)B_ * N_ * D_);
}

// Round 6
// 426.642 us; speedup vs baseline: 5.3985x; 1.2311x over previous
//
#include <hip/hip_runtime.h>
#include <math.h>

#define B_ 4
#define N_ 2048
#define D_ 512
#define M_ 1024
#define H_ 8
#define DH_ 64
#define I_ 512
#define FF_ 1024

typedef unsigned short u16;
typedef __attribute__((ext_vector_type(8))) short bf16x8;
typedef __attribute__((ext_vector_type(4))) float f32x4;

__device__ inline u16 f2b(float f) {           // fp32 -> bf16 RNE
  union { float f; unsigned int u; } v; v.f = f;
  unsigned int u = v.u;
  u += 0x7fffu + ((u >> 16) & 1u);
  return (u16)(u >> 16);
}
__device__ inline float b2f(u16 h) {
  union { unsigned int u; float f; } v; v.u = ((unsigned int)h) << 16;
  return v.f;
}

__device__ inline float gelu_f(float x) {
  float x3 = x * x * x;
  return 0.5f * x * (1.f + tanhf(0.7978845608028654f * (x + 0.044715f * x3)));
}

// ---------------- zero accumulators ----------------
__global__ void zero_init_kernel(float* counts) {
  counts[threadIdx.x] = 0.f;
}

// ---------------- mask dtype detection / normalize ----------------
__global__ void mask_detect_kernel(const unsigned char* __restrict__ mb, int* flag) {
  __shared__ int any;
  if (threadIdx.x == 0) any = 0;
  __syncthreads();
  int acc = 0;
  for (int i = threadIdx.x; i < 8192; i += 256)
    if (i & 3) acc |= mb[i];
  if (acc) atomicOr(&any, 1);
  __syncthreads();
  if (threadIdx.x == 0) *flag = any;
}

__global__ void mask_norm_kernel(const void* __restrict__ mraw,
                                 const int* __restrict__ flag,
                                 int* __restrict__ mnorm) {
  int i = blockIdx.x * 256 + threadIdx.x;
  int v;
  if (*flag) v = ((const unsigned char*)mraw)[i];
  else       v = ((const int*)mraw)[i];
  mnorm[i] = (v != 0) ? 1 : 0;
}

// ---------------- codebook row sum-of-squares (fp64 + fp32 copy) ----------------
__global__ __launch_bounds__(128) void code_sq_kernel(const float* __restrict__ cb,
                                                      double* __restrict__ csq,
                                                      float* __restrict__ csqf) {
  int row = blockIdx.x, tid = threadIdx.x;
  const float4* r4 = (const float4*)(cb + (size_t)row * D_);
  float4 v = r4[tid];
  double s = (double)v.x * v.x + (double)v.y * v.y + (double)v.z * v.z + (double)v.w * v.w;
  for (int off = 32; off; off >>= 1) s += __shfl_down(s, off);
  __shared__ double red[2];
  if ((tid & 63) == 0) red[tid >> 6] = s;
  __syncthreads();
  if (tid == 0) { csq[row] = red[0] + red[1]; csqf[row] = (float)(red[0] + red[1]); }
}

// ---------------- VQ: hi/lo split builders ----------------
__global__ __launch_bounds__(256) void vq_split_x_kernel(
    const float* __restrict__ flat, u16* __restrict__ A)
{
  int t = blockIdx.x;
  const float* xr = flat + ((size_t)t << 9);
  u16* ar = A + (size_t)t * 1536;
#pragma unroll
  for (int i = 0; i < 2; i++) {
    int j = threadIdx.x + i * 256;
    float x = xr[j];
    u16 h = f2b(x);
    u16 l = f2b(x - b2f(h));
    ar[j] = h; ar[512 + j] = l; ar[1024 + j] = h;
  }
}
__global__ __launch_bounds__(256) void vq_split_c_kernel(
    const float* __restrict__ cb, u16* __restrict__ BT)
{
  int c = blockIdx.x;
  const float* cr = cb + ((size_t)c << 9);
  u16* br = BT + (size_t)c * 1536;
#pragma unroll
  for (int i = 0; i < 2; i++) {
    int j = threadIdx.x + i * 256;
    float x = cr[j];
    u16 h = f2b(x);
    u16 l = f2b(x - b2f(h));
    br[j] = h; br[512 + j] = h; br[1024 + j] = l;
  }
}

// ---------------- VQ: per-token top-2 over S row ----------------
__device__ inline bool better(float d1, int i1, float d2, int i2) {
  return d1 < d2 || (d1 == d2 && i1 < i2);
}

__global__ __launch_bounds__(256) void vq_top2_kernel(
    const float* __restrict__ S, const float* __restrict__ csqf,
    int2* __restrict__ cand)
{
  int t = blockIdx.x, tid = threadIdx.x;
  float4 sv = ((const float4*)(S + ((size_t)t << 10)))[tid];
  float4 cq = ((const float4*)csqf)[tid];
  int c0 = tid << 2;
  float b1, b2; int i1, i2;
  b1 = cq.x - 2.f * sv.x; i1 = c0;
  b2 = 1e30f; i2 = 1 << 20;
  {
    float d; int c;
    d = cq.y - 2.f * sv.y; c = c0 + 1;
    if (better(d, c, b1, i1)) { b2 = b1; i2 = i1; b1 = d; i1 = c; }
    else if (better(d, c, b2, i2)) { b2 = d; i2 = c; }
    d = cq.z - 2.f * sv.z; c = c0 + 2;
    if (better(d, c, b1, i1)) { b2 = b1; i2 = i1; b1 = d; i1 = c; }
    else if (better(d, c, b2, i2)) { b2 = d; i2 = c; }
    d = cq.w - 2.f * sv.w; c = c0 + 3;
    if (better(d, c, b1, i1)) { b2 = b1; i2 = i1; b1 = d; i1 = c; }
    else if (better(d, c, b2, i2)) { b2 = d; i2 = c; }
  }
  for (int off = 1; off < 64; off <<= 1) {
    float ob1 = __shfl_xor(b1, off), ob2 = __shfl_xor(b2, off);
    int   oi1 = __shfl_xor(i1, off), oi2 = __shfl_xor(i2, off);
    if (better(b1, i1, ob1, oi1)) {
      if (better(ob1, oi1, b2, i2)) { b2 = ob1; i2 = oi1; }
    } else {
      float nb2; int ni2;
      if (better(b1, i1, ob2, oi2)) { nb2 = b1; ni2 = i1; }
      else                          { nb2 = ob2; ni2 = oi2; }
      b1 = ob1; i1 = oi1; b2 = nb2; i2 = ni2;
    }
  }
  __shared__ float wb1[4], wb2[4];
  __shared__ int   wi1[4], wi2[4];
  if ((tid & 63) == 0) {
    int w = tid >> 6;
    wb1[w] = b1; wb2[w] = b2; wi1[w] = i1; wi2[w] = i2;
  }
  __syncthreads();
  if (tid == 0) {
    float B1 = wb1[0], B2 = wb2[0]; int I1 = wi1[0], I2 = wi2[0];
#pragma unroll
    for (int w = 1; w < 4; w++) {
      if (better(wb1[w], wi1[w], B1, I1)) {
        float nb2; int ni2;
        if (better(B1, I1, wb2[w], wi2[w])) { nb2 = B1; ni2 = I1; }
        else                                { nb2 = wb2[w]; ni2 = wi2[w]; }
        B1 = wb1[w]; I1 = wi1[w]; B2 = nb2; I2 = ni2;
      } else if (better(wb1[w], wi1[w], B2, I2)) {
        B2 = wb1[w]; I2 = wi1[w];
      }
    }
    cand[t] = make_int2(I1, I2);
  }
}

// ---------------- VQ: exact fp64 refine (4 tokens/block, 1 per wave) ----------------
__global__ __launch_bounds__(256) void vq_refine_kernel(
    const float* __restrict__ flat, const float* __restrict__ cb,
    const double* __restrict__ csq, const int2* __restrict__ cand,
    int* __restrict__ out_idx)
{
  int wave = threadIdx.x >> 6, lane = threadIdx.x & 63;
  int t = blockIdx.x * 4 + wave;
  int2 c = cand[t];
  const float* x = flat + ((size_t)t << 9);
  const float* c1 = cb + ((size_t)c.x << 9);
  const float* c2 = cb + ((size_t)c.y << 9);
  double s1 = 0.0, s2 = 0.0;
#pragma unroll
  for (int i = 0; i < 8; i++) {
    int d = lane + i * 64;
    double xv = x[d];
    s1 += xv * (double)c1[d];
    s2 += xv * (double)c2[d];
  }
  for (int off = 32; off; off >>= 1) { s1 += __shfl_down(s1, off); s2 += __shfl_down(s2, off); }
  if (lane == 0) {
    double d1 = csq[c.x] - 2.0 * s1;
    double d2 = csq[c.y] - 2.0 * s2;
    int bi = (d2 < d1 || (d2 == d1 && c.y < c.x)) ? c.y : c.x;
    out_idx[t] = bi;
  }
}

// ---------------- commit loss partials + histogram (no fp64 atomics) ----------------
__global__ __launch_bounds__(128) void commit_hist_kernel(
    const float* __restrict__ flat, const float* __restrict__ cb,
    const int* __restrict__ idx, double* __restrict__ commit_partial,
    float* __restrict__ counts)
{
  int t = blockIdx.x, tid = threadIdx.x;
  int code = idx[t];
  float4 a = ((const float4*)(flat + ((size_t)t << 9)))[tid];
  float4 c = ((const float4*)(cb + ((size_t)code << 9)))[tid];
  float dx = a.x - c.x, dy = a.y - c.y, dz = a.z - c.z, dw = a.w - c.w;
  double s = (double)dx * dx + (double)dy * dy + (double)dz * dz + (double)dw * dw;
  for (int off = 32; off; off >>= 1) s += __shfl_down(s, off);
  __shared__ double red[2];
  if ((tid & 63) == 0) red[tid >> 6] = s;
  __syncthreads();
  if (tid == 0) {
    commit_partial[t] = red[0] + red[1];
    atomicAdd(counts + code, 1.0f);
  }
}

// ---------------- LayerNorm (fp32 in -> bf16 out) ----------------
__global__ __launch_bounds__(256) void ln_rows_kernel(
    const float* __restrict__ x, const float* __restrict__ g,
    const float* __restrict__ b, u16* __restrict__ y)
{
  int row = blockIdx.x, tid = threadIdx.x;
  const float* xr = x + (size_t)row * D_;
  float v0 = xr[tid], v1 = xr[tid + 256];
  float s = v0 + v1;
  for (int off = 32; off; off >>= 1) s += __shfl_down(s, off);
  __shared__ float red[4];
  __shared__ float bcast[2];
  if ((tid & 63) == 0) red[tid >> 6] = s;
  __syncthreads();
  if (tid == 0) bcast[0] = (red[0] + red[1] + red[2] + red[3]) * (1.f / 512.f);
  __syncthreads();
  float mu = bcast[0];
  float d0 = v0 - mu, d1 = v1 - mu;
  float q = d0 * d0 + d1 * d1;
  for (int off = 32; off; off >>= 1) q += __shfl_down(q, off);
  if ((tid & 63) == 0) red[tid >> 6] = q;
  __syncthreads();
  if (tid == 0) bcast[1] = rsqrtf((red[0] + red[1] + red[2] + red[3]) * (1.f / 512.f) + 1e-5f);
  __syncthreads();
  float rs = bcast[1];
  u16* yr = y + (size_t)row * D_;
  yr[tid]       = f2b(d0 * rs * g[tid] + b[tid]);
  yr[tid + 256] = f2b(d1 * rs * g[tid + 256] + b[tid + 256]);
}

// ---------------- fused weight conversion: 7 matrices, one launch ----------------
struct WJobs {
  const float* src[7];
  u16* dst[7];
  int K[7], N[7], b0[8];
};

__global__ __launch_bounds__(256) void wconv_all_kernel(WJobs jobs) {
  __shared__ float tile[32][33];
  int bid = blockIdx.x;
  int j = 0;
#pragma unroll
  for (int i = 1; i < 7; i++) if (bid >= jobs.b0[i]) j = i;
  int tb = bid - jobs.b0[j];
  int K = jobs.K[j], Nn = jobs.N[j];
  int tiles_x = Nn >> 5;
  int n0 = (tb % tiles_x) << 5, k0 = (tb / tiles_x) << 5;
  const float* W = jobs.src[j];
  u16* WT = jobs.dst[j];
  int t = threadIdx.x;
  int ty = t >> 5, tx = t & 31;
#pragma unroll
  for (int i = 0; i < 4; i++)
    tile[ty + 8 * i][tx] = W[(size_t)(k0 + ty + 8 * i) * Nn + n0 + tx];
  __syncthreads();
#pragma unroll
  for (int i = 0; i < 4; i++)
    WT[(size_t)(n0 + ty + 8 * i) * K + k0 + tx] = f2b(tile[tx][ty + 8 * i]);
}

// ---------------- bf16 MFMA GEMM: C = act(A@B + bias) + resid ----------------
__global__ __launch_bounds__(256) void gemm_bf16_kernel(
    const u16* __restrict__ A, const u16* __restrict__ BT,
    const float* __restrict__ bias, const float* __restrict__ resid,
    float* __restrict__ Cf, u16* __restrict__ Cb,
    int M, int N, int K, int act)
{
  __shared__ __attribute__((aligned(16))) u16 As[128 * 40];
  __shared__ __attribute__((aligned(16))) u16 Bs[128 * 40];
  int tid = threadIdx.x;
  int lane = tid & 63, wave = tid >> 6;
  int wr = wave >> 1, wc = wave & 1;
  int row0 = blockIdx.y * 128, col0 = blockIdx.x * 128;
  int l15 = lane & 15, l4 = lane >> 4;
  int sr = tid >> 2, skc = tid & 3;
  f32x4 acc[4][4] = {};
  for (int k0 = 0; k0 < K; k0 += 32) {
    __syncthreads();
    bf16x8 a0 = *(const bf16x8*)(A + (size_t)(row0 + sr) * K + k0 + skc * 8);
    bf16x8 a1 = *(const bf16x8*)(A + (size_t)(row0 + 64 + sr) * K + k0 + skc * 8);
    bf16x8 b0 = *(const bf16x8*)(BT + (size_t)(col0 + sr) * K + k0 + skc * 8);
    bf16x8 b1 = *(const bf16x8*)(BT + (size_t)(col0 + 64 + sr) * K + k0 + skc * 8);
    *(bf16x8*)&As[sr * 40 + skc * 8] = a0;
    *(bf16x8*)&As[(64 + sr) * 40 + skc * 8] = a1;
    *(bf16x8*)&Bs[sr * 40 + skc * 8] = b0;
    *(bf16x8*)&Bs[(64 + sr) * 40 + skc * 8] = b1;
    __syncthreads();
    bf16x8 af[4], bfr[4];
#pragma unroll
    for (int m = 0; m < 4; m++)
      af[m] = *(const bf16x8*)&As[(wr * 64 + m * 16 + l15) * 40 + l4 * 8];
#pragma unroll
    for (int n = 0; n < 4; n++)
      bfr[n] = *(const bf16x8*)&Bs[(wc * 64 + n * 16 + l15) * 40 + l4 * 8];
#pragma unroll
    for (int m = 0; m < 4; m++)
#pragma unroll
      for (int n = 0; n < 4; n++)
        acc[m][n] = __builtin_amdgcn_mfma_f32_16x16x32_bf16(af[m], bfr[n], acc[m][n], 0, 0, 0);
  }
#pragma unroll
  for (int m = 0; m < 4; m++) {
#pragma unroll
    for (int n = 0; n < 4; n++) {
      int col = col0 + wc * 64 + n * 16 + l15;
      float bv = bias ? bias[col] : 0.f;
#pragma unroll
      for (int r = 0; r < 4; r++) {
        int row = row0 + wr * 64 + m * 16 + l4 * 4 + r;
        float v = acc[m][n][r] + bv;
        if (act == 1) v = gelu_f(v);
        if (resid) v += resid[(size_t)row * N + col];
        if (Cf) Cf[(size_t)row * N + col] = v;
        if (Cb) Cb[(size_t)row * N + col] = f2b(v);
      }
    }
  }
}

// ---------------- V transpose: src rows -> Vt [b*8+h][64][n_rows] ----------------
__global__ __launch_bounds__(256) void vt_kernel(
    const u16* __restrict__ src, size_t b_stride, int row_stride, int col0,
    int n_rows, u16* __restrict__ dst)
{
  __shared__ __attribute__((aligned(16))) u16 tile[32][72];
  int t = threadIdx.x;
  int bh = blockIdx.y;
  int b = bh >> 3, h = bh & 7;
  int n0 = blockIdx.x * 32;
  int n = t >> 3, dc = t & 7;
  *(bf16x8*)&tile[n][dc * 8] =
      *(const bf16x8*)(src + (size_t)b * b_stride + (size_t)(n0 + n) * row_stride + col0 + h * 64 + dc * 8);
  __syncthreads();
  int d = t >> 2, ns = t & 3;
  bf16x8 o;
#pragma unroll
  for (int i = 0; i < 8; i++) o[i] = (short)tile[ns * 8 + i][d];
  *(bf16x8*)(dst + ((size_t)bh * 64 + d) * n_rows + n0 + ns * 8) = o;
}

// ---------------- MFMA flash attention (swapped QK^T, KVBLK=64, defer-max) ----------------
__global__ __launch_bounds__(256, 2) void attn_mfma_kernel(
    const u16* __restrict__ Q, size_t q_bs, int q_stride,
    const u16* __restrict__ Kp, size_t k_bs, int k_stride, int k_extra,
    const u16* __restrict__ Vt, const int* __restrict__ mask,
    float scale, u16* __restrict__ O, size_t o_bs, int n_keys)
{
  __shared__ __attribute__((aligned(16))) u16 Ks[64 * 72];
  __shared__ __attribute__((aligned(16))) u16 Vs[64 * 72];
  __shared__ __attribute__((aligned(16))) u16 Ps[4][16 * 72];
  __shared__ unsigned char msk[64];
  int tid = threadIdx.x, lane = tid & 63, wave = tid >> 6;
  int b = blockIdx.z, h = blockIdx.y, q0 = blockIdx.x * 64 + wave * 16;
  int l15 = lane & 15, l4 = lane >> 4;
  const u16* qrow = Q + (size_t)b * q_bs + (size_t)(q0 + l15) * q_stride + h * 64 + l4 * 8;
  bf16x8 qf0 = *(const bf16x8*)qrow;
  bf16x8 qf1 = *(const bf16x8*)(qrow + 32);
  f32x4 o_acc[4] = {};
  float m_run = -3.0e38f, l_run = 0.f;
  int srow = tid >> 2, schunk = tid & 3;
  const u16* kbase = Kp + (size_t)b * k_bs + k_extra + h * 64;
  const u16* vtbase = Vt + (size_t)(b * 8 + h) * 64 * n_keys;

  for (int n0 = 0; n0 < n_keys; n0 += 64) {
    __syncthreads();
    {
      const u16* krow = kbase + (size_t)(n0 + srow) * k_stride;
      *(bf16x8*)&Ks[srow * 72 + schunk * 8]       = *(const bf16x8*)(krow + schunk * 8);
      *(bf16x8*)&Ks[srow * 72 + (schunk + 4) * 8] = *(const bf16x8*)(krow + (schunk + 4) * 8);
      const u16* vrow = vtbase + (size_t)srow * n_keys + n0;
      *(bf16x8*)&Vs[srow * 72 + schunk * 8]       = *(const bf16x8*)(vrow + schunk * 8);
      *(bf16x8*)&Vs[srow * 72 + (schunk + 4) * 8] = *(const bf16x8*)(vrow + (schunk + 4) * 8);
      if (mask && tid < 64) msk[tid] = (unsigned char)(mask[(size_t)b * n_keys + n0 + tid] != 0);
    }
    __syncthreads();
    f32x4 sac[4];
#pragma unroll
    for (int kb = 0; kb < 4; kb++) {
      bf16x8 kf0 = *(const bf16x8*)&Ks[(kb * 16 + l15) * 72 + l4 * 8];
      bf16x8 kf1 = *(const bf16x8*)&Ks[(kb * 16 + l15) * 72 + 32 + l4 * 8];
      f32x4 z = {};
      z = __builtin_amdgcn_mfma_f32_16x16x32_bf16(kf0, qf0, z, 0, 0, 0);
      sac[kb] = __builtin_amdgcn_mfma_f32_16x16x32_bf16(kf1, qf1, z, 0, 0, 0);
    }
    float sv[16];
    float pmax = -3.0e38f;
#pragma unroll
    for (int kb = 0; kb < 4; kb++) {
      unsigned int mw = mask ? *(const unsigned int*)&msk[kb * 16 + l4 * 4] : 0x01010101u;
#pragma unroll
      for (int r = 0; r < 4; r++) {
        float s = sac[kb][r] * scale;
        if (!((mw >> (8 * r)) & 1u)) s = -3.0e38f;
        sv[kb * 4 + r] = s;
        pmax = fmaxf(pmax, s);
      }
    }
    pmax = fmaxf(pmax, __shfl_xor(pmax, 16));
    pmax = fmaxf(pmax, __shfl_xor(pmax, 32));
    if (!__all(pmax - m_run <= 8.f)) {
      float mnew = fmaxf(m_run, pmax);
      float al = __expf(m_run - mnew);
      l_run *= al;
      m_run = mnew;
      float alr[4];
#pragma unroll
      for (int r = 0; r < 4; r++) alr[r] = __shfl(al, l4 * 4 + r, 64);
#pragma unroll
      for (int nb = 0; nb < 4; nb++)
#pragma unroll
        for (int r = 0; r < 4; r++) o_acc[nb][r] *= alr[r];
    }
    float psum = 0.f;
    u16 pb[16];
#pragma unroll
    for (int i = 0; i < 16; i++) {
      float p = (sv[i] < -1.0e37f) ? 0.f : __expf(sv[i] - m_run);
      psum += p;
      pb[i] = f2b(p);
    }
    psum += __shfl_xor(psum, 16);
    psum += __shfl_xor(psum, 32);
    l_run += psum;
#pragma unroll
    for (int kb = 0; kb < 4; kb++) {
      uint2 w;
      w.x = (unsigned int)pb[kb * 4 + 0] | ((unsigned int)pb[kb * 4 + 1] << 16);
      w.y = (unsigned int)pb[kb * 4 + 2] | ((unsigned int)pb[kb * 4 + 3] << 16);
      *(uint2*)&Ps[wave][l15 * 72 + kb * 16 + l4 * 4] = w;
    }
#pragma unroll
    for (int c = 0; c < 2; c++) {
      bf16x8 pf = *(const bf16x8*)&Ps[wave][l15 * 72 + c * 32 + l4 * 8];
#pragma unroll
      for (int nb = 0; nb < 4; nb++) {
        bf16x8 vf = *(const bf16x8*)&Vs[(nb * 16 + l15) * 72 + c * 32 + l4 * 8];
        o_acc[nb] = __builtin_amdgcn_mfma_f32_16x16x32_bf16(pf, vf, o_acc[nb], 0, 0, 0);
      }
    }
  }
  float lr[4];
#pragma unroll
  for (int r = 0; r < 4; r++) lr[r] = __shfl(l_run, l4 * 4 + r, 64);
#pragma unroll
  for (int nb = 0; nb < 4; nb++) {
#pragma unroll
    for (int r = 0; r < 4; r++) {
      int row = q0 + l4 * 4 + r;
      int col = h * 64 + nb * 16 + l15;
      O[(size_t)b * o_bs + (size_t)row * 512 + col] = f2b(o_acc[nb][r] / lr[r]);
    }
  }
}

// ---------------- gather rows by VQ index (fp32) ----------------
__global__ __launch_bounds__(128) void gather_kernel(
    const float* __restrict__ x2, const int* __restrict__ idx, float* __restrict__ out)
{
  int t = blockIdx.x;
  int b = t >> 11;
  int code = idx[t];
  const float4* src = (const float4*)(x2 + ((size_t)(b * M_ + code) << 9));
  float4* dst = (float4*)(out + ((size_t)t << 9));
  dst[threadIdx.x] = src[threadIdx.x];
}

// ---------------- scalars: reduce commit partials + entropy ----------------
__global__ void scalars_kernel(const float* __restrict__ counts,
                               const double* __restrict__ commit_partial,
                               float* __restrict__ out_tail)
{
  int tid = threadIdx.x;   // 1024
  double cs = 0.0;
#pragma unroll
  for (int i = 0; i < 8; i++) cs += commit_partial[tid + i * 1024];
  double p = (double)counts[tid] / 8192.0;
  double e = p * log(p + 1e-10);
  for (int off = 32; off; off >>= 1) {
    cs += __shfl_down(cs, off);
    e  += __shfl_down(e, off);
  }
  __shared__ double redc[16], rede[16];
  if ((tid & 63) == 0) { redc[tid >> 6] = cs; rede[tid >> 6] = e; }
  __syncthreads();
  if (tid == 0) {
    double sc = 0.0, se = 0.0;
    for (int i = 0; i < 16; i++) { sc += redc[i]; se += rede[i]; }
    out_tail[0] = (float)(sc / (8192.0 * 512.0));
    out_tail[1] = (float)exp(-se);
  }
}

extern "C" void kernel_launch(void* const* d_in, const int* in_sizes, int n_in,
                              void* d_out, int out_size, void* d_ws, size_t ws_size,
                              hipStream_t stream) {
  const float* ctx      = (const float*)d_in[0];
  const void*  mask_raw = d_in[1];
  const float* codebook = (const float*)d_in[2];
  const float* norm_g   = (const float*)d_in[3];
  const float* norm_b   = (const float*)d_in[4];
  const float* cnorm_g  = (const float*)d_in[5];
  const float* cnorm_b  = (const float*)d_in[6];
  const float* wq       = (const float*)d_in[7];
  const float* wkv      = (const float*)d_in[8];
  const float* wo       = (const float*)d_in[9];
  const float* wo_b     = (const float*)d_in[10];
  const float* a_norm_g = (const float*)d_in[11];
  const float* a_norm_b = (const float*)d_in[12];
  const float* a_qkv    = (const float*)d_in[13];
  const float* a_out    = (const float*)d_in[14];
  const float* f_norm_g = (const float*)d_in[15];
  const float* f_norm_b = (const float*)d_in[16];
  const float* f_w1     = (const float*)d_in[17];
  const float* f_w2     = (const float*)d_in[18];
  float* out = (float*)d_out;

  char* ws = (char*)d_ws;
  int*    mask_flag  = (int*)(ws + 64);
  float*  counts     = (float*)(ws + 128);
  double* code_sq    = (double*)(ws + 128 + 4096);
  float*  csqf       = (float*)(ws + 128 + 4096 + 8192);
  int*    indices    = (int*)(ws + 128 + 4096 + 8192 + 4096);
  int*    mask_norm  = (int*)(ws + 128 + 4096 + 8192 + 4096 + 32768);
  int2*   cand       = (int2*)(ws + 128 + 4096 + 8192 + 4096 + 32768 + 32768);
  double* commit_partial = (double*)(ws + 128 + 4096 + 8192 + 4096 + 32768 + 32768 + 65536);  // 64 KB

  char* pool = ws + (1 << 20);
  u16*   vqA  = (u16*)(pool);
  u16*   vqBT = (u16*)(pool + ((size_t)26 << 20));
  float* vqS  = (float*)(pool + ((size_t)30 << 20));
  char* regA  = pool;
  char* regB  = pool + ((size_t)16 << 20);
  char* regC  = pool + ((size_t)24 << 20);
  char* regD  = pool + ((size_t)32 << 20);
  char* regE  = pool + ((size_t)40 << 20);
  char* regF  = pool + ((size_t)44 << 20);
  char* regG  = pool + ((size_t)52 << 20);
  size_t woff = (1 << 20) + ((size_t)64 << 20);
  u16* wqT    = (u16*)(ws + woff); woff += (size_t)512 * 512 * 2;
  u16* wkvT   = (u16*)(ws + woff); woff += (size_t)1024 * 512 * 2;
  u16* woT    = (u16*)(ws + woff); woff += (size_t)512 * 512 * 2;
  u16* aqkvT  = (u16*)(ws + woff); woff += (size_t)1536 * 512 * 2;
  u16* aoutT  = (u16*)(ws + woff); woff += (size_t)512 * 512 * 2;
  u16* fw1T   = (u16*)(ws + woff); woff += (size_t)1024 * 512 * 2;
  u16* fw2T   = (u16*)(ws + woff); woff += (size_t)512 * 1024 * 2;
  u16* xq_b   = (u16*)(ws + woff); woff += (size_t)1024 * 512 * 2;
  u16* qs_b   = (u16*)(ws + woff); woff += (size_t)1024 * 512 * 2;

  u16* kv_b     = (u16*)regA;
  u16* qkv2_b   = (u16*)regA;
  u16* ctx_ln_b = (u16*)regB;
  u16* VtS      = (u16*)regB;
  u16* VtX      = (u16*)regC;
  float* x1_f   = (float*)regC;
  float* x0_f   = (float*)regD;
  u16* att_out_b = (u16*)regE;
  u16* h_b       = (u16*)regE;
  u16* o2_b      = (u16*)regE;
  u16* hf_b      = (u16*)regE;
  u16* g_b      = (u16*)regF;
  float* x2_f   = (float*)regG;

  // ---- VQ ----
  zero_init_kernel<<<1, 1024, 0, stream>>>(counts);
  mask_detect_kernel<<<1, 256, 0, stream>>>((const unsigned char*)mask_raw, mask_flag);
  mask_norm_kernel<<<32, 256, 0, stream>>>(mask_raw, mask_flag, mask_norm);
  code_sq_kernel<<<1024, 128, 0, stream>>>(codebook, code_sq, csqf);
  vq_split_x_kernel<<<8192, 256, 0, stream>>>(ctx, vqA);
  vq_split_c_kernel<<<1024, 256, 0, stream>>>(codebook, vqBT);
  gemm_bf16_kernel<<<dim3(8, 64), 256, 0, stream>>>(vqA, vqBT, nullptr, nullptr,
                                                    vqS, nullptr, 8192, 1024, 1536, 0);
  vq_top2_kernel<<<8192, 256, 0, stream>>>(vqS, csqf, cand);
  vq_refine_kernel<<<2048, 256, 0, stream>>>(ctx, codebook, code_sq, cand, indices);
  commit_hist_kernel<<<8192, 128, 0, stream>>>(ctx, codebook, indices, commit_partial, counts);

  // ---- weight conversion (one fused launch) ----
  WJobs jobs;
  jobs.src[0] = wq;    jobs.dst[0] = wqT;   jobs.K[0] = 512;  jobs.N[0] = 512;
  jobs.src[1] = wkv;   jobs.dst[1] = wkvT;  jobs.K[1] = 512;  jobs.N[1] = 1024;
  jobs.src[2] = wo;    jobs.dst[2] = woT;   jobs.K[2] = 512;  jobs.N[2] = 512;
  jobs.src[3] = a_qkv; jobs.dst[3] = aqkvT; jobs.K[3] = 512;  jobs.N[3] = 1536;
  jobs.src[4] = a_out; jobs.dst[4] = aoutT; jobs.K[4] = 512;  jobs.N[4] = 512;
  jobs.src[5] = f_w1;  jobs.dst[5] = fw1T;  jobs.K[5] = 512;  jobs.N[5] = 1024;
  jobs.src[6] = f_w2;  jobs.dst[6] = fw2T;  jobs.K[6] = 1024; jobs.N[6] = 512;
  int acc_b = 0;
  for (int i = 0; i < 7; i++) {
    jobs.b0[i] = acc_b;
    acc_b += (jobs.K[i] >> 5) * (jobs.N[i] >> 5);
  }
  jobs.b0[7] = acc_b;
  wconv_all_kernel<<<acc_b, 256, 0, stream>>>(jobs);

  // ---- Cross-attention ----
  ln_rows_kernel<<<1024, 256, 0, stream>>>(codebook, norm_g, norm_b, xq_b);
  gemm_bf16_kernel<<<dim3(4, 8), 256, 0, stream>>>(xq_b, wqT, nullptr, nullptr,
                                                   nullptr, qs_b, 1024, 512, 512, 0);
  ln_rows_kernel<<<8192, 256, 0, stream>>>(ctx, cnorm_g, cnorm_b, ctx_ln_b);
  gemm_bf16_kernel<<<dim3(8, 64), 256, 0, stream>>>(ctx_ln_b, wkvT, nullptr, nullptr,
                                                    nullptr, kv_b, 8192, 1024, 512, 0);
  vt_kernel<<<dim3(64, 32), 256, 0, stream>>>(kv_b, (size_t)2048 * 1024, 1024, 512, 2048, VtX);
  attn_mfma_kernel<<<dim3(16, 8, 4), 256, 0, stream>>>(
      qs_b, 0, 512, kv_b, (size_t)2048 * 1024, 1024, 0, VtX, mask_norm,
      0.125f, att_out_b, (size_t)1024 * 512, 2048);
  gemm_bf16_kernel<<<dim3(4, 32), 256, 0, stream>>>(att_out_b, woT, wo_b, nullptr,
                                                    x0_f, nullptr, 4096, 512, 512, 0);

  // ---- Transformer refinement ----
  ln_rows_kernel<<<4096, 256, 0, stream>>>(x0_f, a_norm_g, a_norm_b, h_b);
  gemm_bf16_kernel<<<dim3(12, 32), 256, 0, stream>>>(h_b, aqkvT, nullptr, nullptr,
                                                     nullptr, qkv2_b, 4096, 1536, 512, 0);
  vt_kernel<<<dim3(32, 32), 256, 0, stream>>>(qkv2_b, (size_t)1024 * 1536, 1536, 1024, 1024, VtS);
  attn_mfma_kernel<<<dim3(16, 8, 4), 256, 0, stream>>>(
      qkv2_b, (size_t)1024 * 1536, 1536, qkv2_b, (size_t)1024 * 1536, 1536, 512, VtS, nullptr,
      0.125f, o2_b, (size_t)1024 * 512, 1024);
  gemm_bf16_kernel<<<dim3(4, 32), 256, 0, stream>>>(o2_b, aoutT, nullptr, x0_f,
                                                    x1_f, nullptr, 4096, 512, 512, 0);
  ln_rows_kernel<<<4096, 256, 0, stream>>>(x1_f, f_norm_g, f_norm_b, hf_b);
  gemm_bf16_kernel<<<dim3(8, 32), 256, 0, stream>>>(hf_b, fw1T, nullptr, nullptr,
                                                    nullptr, g_b, 4096, 1024, 512, 1);
  gemm_bf16_kernel<<<dim3(4, 32), 256, 0, stream>>>(g_b, fw2T, nullptr, x1_f,
                                                    x2_f, nullptr, 4096, 512, 1024, 0);

  // ---- Gather + scalars ----
  gather_kernel<<<8192, 128, 0, stream>>>(x2_f, indices, out);
  scalars_kernel<<<1, 1024, 0, stream>>>(counts, commit_partial, out + (size_t)B_ * N_ * D_);
}

// Round 7
// 380.428 us; speedup vs baseline: 6.0544x; 1.1215x over previous
//
#include <hip/hip_runtime.h>
#include <math.h>

#define B_ 4
#define N_ 2048
#define D_ 512
#define M_ 1024
#define H_ 8
#define DH_ 64
#define I_ 512
#define FF_ 1024

typedef unsigned short u16;
typedef __attribute__((ext_vector_type(8))) short bf16x8;
typedef __attribute__((ext_vector_type(4))) float f32x4;

__device__ inline u16 f2b(float f) {           // fp32 -> bf16 RNE
  union { float f; unsigned int u; } v; v.f = f;
  unsigned int u = v.u;
  u += 0x7fffu + ((u >> 16) & 1u);
  return (u16)(u >> 16);
}
__device__ inline float b2f(u16 h) {
  union { unsigned int u; float f; } v; v.u = ((unsigned int)h) << 16;
  return v.f;
}

__device__ inline float gelu_f(float x) {
  float x3 = x * x * x;
  return 0.5f * x * (1.f + tanhf(0.7978845608028654f * (x + 0.044715f * x3)));
}

// ---------------- zero accumulators ----------------
__global__ void zero_init_kernel(float* counts) {
  counts[threadIdx.x] = 0.f;
}

// ---------------- mask dtype detection / normalize ----------------
__global__ void mask_detect_kernel(const unsigned char* __restrict__ mb, int* flag) {
  __shared__ int any;
  if (threadIdx.x == 0) any = 0;
  __syncthreads();
  int acc = 0;
  for (int i = threadIdx.x; i < 8192; i += 256)
    if (i & 3) acc |= mb[i];
  if (acc) atomicOr(&any, 1);
  __syncthreads();
  if (threadIdx.x == 0) *flag = any;
}

__global__ void mask_norm_kernel(const void* __restrict__ mraw,
                                 const int* __restrict__ flag,
                                 int* __restrict__ mnorm) {
  int i = blockIdx.x * 256 + threadIdx.x;
  int v;
  if (*flag) v = ((const unsigned char*)mraw)[i];
  else       v = ((const int*)mraw)[i];
  mnorm[i] = (v != 0) ? 1 : 0;
}

// ---------------- codebook row sum-of-squares (fp64 + fp32 copy) ----------------
__global__ __launch_bounds__(128) void code_sq_kernel(const float* __restrict__ cb,
                                                      double* __restrict__ csq,
                                                      float* __restrict__ csqf) {
  int row = blockIdx.x, tid = threadIdx.x;
  const float4* r4 = (const float4*)(cb + (size_t)row * D_);
  float4 v = r4[tid];
  double s = (double)v.x * v.x + (double)v.y * v.y + (double)v.z * v.z + (double)v.w * v.w;
  for (int off = 32; off; off >>= 1) s += __shfl_down(s, off);
  __shared__ double red[2];
  if ((tid & 63) == 0) red[tid >> 6] = s;
  __syncthreads();
  if (tid == 0) { csq[row] = red[0] + red[1]; csqf[row] = (float)(red[0] + red[1]); }
}

// ---------------- VQ: hi/lo split builders ----------------
__global__ __launch_bounds__(256) void vq_split_x_kernel(
    const float* __restrict__ flat, u16* __restrict__ A)
{
  int t = blockIdx.x;
  const float* xr = flat + ((size_t)t << 9);
  u16* ar = A + (size_t)t * 1536;
#pragma unroll
  for (int i = 0; i < 2; i++) {
    int j = threadIdx.x + i * 256;
    float x = xr[j];
    u16 h = f2b(x);
    u16 l = f2b(x - b2f(h));
    ar[j] = h; ar[512 + j] = l; ar[1024 + j] = h;
  }
}
__global__ __launch_bounds__(256) void vq_split_c_kernel(
    const float* __restrict__ cb, u16* __restrict__ BT)
{
  int c = blockIdx.x;
  const float* cr = cb + ((size_t)c << 9);
  u16* br = BT + (size_t)c * 1536;
#pragma unroll
  for (int i = 0; i < 2; i++) {
    int j = threadIdx.x + i * 256;
    float x = cr[j];
    u16 h = f2b(x);
    u16 l = f2b(x - b2f(h));
    br[j] = h; br[512 + j] = h; br[1024 + j] = l;
  }
}

// ---------------- VQ: per-token top-2 over S row ----------------
__device__ inline bool better(float d1, int i1, float d2, int i2) {
  return d1 < d2 || (d1 == d2 && i1 < i2);
}

__global__ __launch_bounds__(256) void vq_top2_kernel(
    const float* __restrict__ S, const float* __restrict__ csqf,
    int2* __restrict__ cand)
{
  int t = blockIdx.x, tid = threadIdx.x;
  float4 sv = ((const float4*)(S + ((size_t)t << 10)))[tid];
  float4 cq = ((const float4*)csqf)[tid];
  int c0 = tid << 2;
  float b1, b2; int i1, i2;
  b1 = cq.x - 2.f * sv.x; i1 = c0;
  b2 = 1e30f; i2 = 1 << 20;
  {
    float d; int c;
    d = cq.y - 2.f * sv.y; c = c0 + 1;
    if (better(d, c, b1, i1)) { b2 = b1; i2 = i1; b1 = d; i1 = c; }
    else if (better(d, c, b2, i2)) { b2 = d; i2 = c; }
    d = cq.z - 2.f * sv.z; c = c0 + 2;
    if (better(d, c, b1, i1)) { b2 = b1; i2 = i1; b1 = d; i1 = c; }
    else if (better(d, c, b2, i2)) { b2 = d; i2 = c; }
    d = cq.w - 2.f * sv.w; c = c0 + 3;
    if (better(d, c, b1, i1)) { b2 = b1; i2 = i1; b1 = d; i1 = c; }
    else if (better(d, c, b2, i2)) { b2 = d; i2 = c; }
  }
  for (int off = 1; off < 64; off <<= 1) {
    float ob1 = __shfl_xor(b1, off), ob2 = __shfl_xor(b2, off);
    int   oi1 = __shfl_xor(i1, off), oi2 = __shfl_xor(i2, off);
    if (better(b1, i1, ob1, oi1)) {
      if (better(ob1, oi1, b2, i2)) { b2 = ob1; i2 = oi1; }
    } else {
      float nb2; int ni2;
      if (better(b1, i1, ob2, oi2)) { nb2 = b1; ni2 = i1; }
      else                          { nb2 = ob2; ni2 = oi2; }
      b1 = ob1; i1 = oi1; b2 = nb2; i2 = ni2;
    }
  }
  __shared__ float wb1[4], wb2[4];
  __shared__ int   wi1[4], wi2[4];
  if ((tid & 63) == 0) {
    int w = tid >> 6;
    wb1[w] = b1; wb2[w] = b2; wi1[w] = i1; wi2[w] = i2;
  }
  __syncthreads();
  if (tid == 0) {
    float B1 = wb1[0], B2 = wb2[0]; int I1 = wi1[0], I2 = wi2[0];
#pragma unroll
    for (int w = 1; w < 4; w++) {
      if (better(wb1[w], wi1[w], B1, I1)) {
        float nb2; int ni2;
        if (better(B1, I1, wb2[w], wi2[w])) { nb2 = B1; ni2 = I1; }
        else                                { nb2 = wb2[w]; ni2 = wi2[w]; }
        B1 = wb1[w]; I1 = wi1[w]; B2 = nb2; I2 = ni2;
      } else if (better(wb1[w], wi1[w], B2, I2)) {
        B2 = wb1[w]; I2 = wi1[w];
      }
    }
    cand[t] = make_int2(I1, I2);
  }
}

// ---------------- VQ: exact fp64 refine (4 tokens/block, 1 per wave) ----------------
__global__ __launch_bounds__(256) void vq_refine_kernel(
    const float* __restrict__ flat, const float* __restrict__ cb,
    const double* __restrict__ csq, const int2* __restrict__ cand,
    int* __restrict__ out_idx)
{
  int wave = threadIdx.x >> 6, lane = threadIdx.x & 63;
  int t = blockIdx.x * 4 + wave;
  int2 c = cand[t];
  const float* x = flat + ((size_t)t << 9);
  const float* c1 = cb + ((size_t)c.x << 9);
  const float* c2 = cb + ((size_t)c.y << 9);
  double s1 = 0.0, s2 = 0.0;
#pragma unroll
  for (int i = 0; i < 8; i++) {
    int d = lane + i * 64;
    double xv = x[d];
    s1 += xv * (double)c1[d];
    s2 += xv * (double)c2[d];
  }
  for (int off = 32; off; off >>= 1) { s1 += __shfl_down(s1, off); s2 += __shfl_down(s2, off); }
  if (lane == 0) {
    double d1 = csq[c.x] - 2.0 * s1;
    double d2 = csq[c.y] - 2.0 * s2;
    int bi = (d2 < d1 || (d2 == d1 && c.y < c.x)) ? c.y : c.x;
    out_idx[t] = bi;
  }
}

// ---------------- commit loss partials + histogram ----------------
__global__ __launch_bounds__(128) void commit_hist_kernel(
    const float* __restrict__ flat, const float* __restrict__ cb,
    const int* __restrict__ idx, double* __restrict__ commit_partial,
    float* __restrict__ counts)
{
  int t = blockIdx.x, tid = threadIdx.x;
  int code = idx[t];
  float4 a = ((const float4*)(flat + ((size_t)t << 9)))[tid];
  float4 c = ((const float4*)(cb + ((size_t)code << 9)))[tid];
  float dx = a.x - c.x, dy = a.y - c.y, dz = a.z - c.z, dw = a.w - c.w;
  double s = (double)dx * dx + (double)dy * dy + (double)dz * dz + (double)dw * dw;
  for (int off = 32; off; off >>= 1) s += __shfl_down(s, off);
  __shared__ double red[2];
  if ((tid & 63) == 0) red[tid >> 6] = s;
  __syncthreads();
  if (tid == 0) {
    commit_partial[t] = red[0] + red[1];
    atomicAdd(counts + code, 1.0f);
  }
}

// ---------------- LayerNorm (fp32 in -> bf16 out) ----------------
__global__ __launch_bounds__(256) void ln_rows_kernel(
    const float* __restrict__ x, const float* __restrict__ g,
    const float* __restrict__ b, u16* __restrict__ y)
{
  int row = blockIdx.x, tid = threadIdx.x;
  const float* xr = x + (size_t)row * D_;
  float v0 = xr[tid], v1 = xr[tid + 256];
  float s = v0 + v1;
  for (int off = 32; off; off >>= 1) s += __shfl_down(s, off);
  __shared__ float red[4];
  __shared__ float bcast[2];
  if ((tid & 63) == 0) red[tid >> 6] = s;
  __syncthreads();
  if (tid == 0) bcast[0] = (red[0] + red[1] + red[2] + red[3]) * (1.f / 512.f);
  __syncthreads();
  float mu = bcast[0];
  float d0 = v0 - mu, d1 = v1 - mu;
  float q = d0 * d0 + d1 * d1;
  for (int off = 32; off; off >>= 1) q += __shfl_down(q, off);
  if ((tid & 63) == 0) red[tid >> 6] = q;
  __syncthreads();
  if (tid == 0) bcast[1] = rsqrtf((red[0] + red[1] + red[2] + red[3]) * (1.f / 512.f) + 1e-5f);
  __syncthreads();
  float rs = bcast[1];
  u16* yr = y + (size_t)row * D_;
  yr[tid]       = f2b(d0 * rs * g[tid] + b[tid]);
  yr[tid + 256] = f2b(d1 * rs * g[tid + 256] + b[tid + 256]);
}

// ---------------- fused weight conversion ----------------
struct WJobs {
  const float* src[7];
  u16* dst[7];
  int K[7], N[7], b0[8];
};

__global__ __launch_bounds__(256) void wconv_all_kernel(WJobs jobs) {
  __shared__ float tile[32][33];
  int bid = blockIdx.x;
  int j = 0;
#pragma unroll
  for (int i = 1; i < 7; i++) if (bid >= jobs.b0[i]) j = i;
  int tb = bid - jobs.b0[j];
  int K = jobs.K[j], Nn = jobs.N[j];
  int tiles_x = Nn >> 5;
  int n0 = (tb % tiles_x) << 5, k0 = (tb / tiles_x) << 5;
  const float* W = jobs.src[j];
  u16* WT = jobs.dst[j];
  int t = threadIdx.x;
  int ty = t >> 5, tx = t & 31;
#pragma unroll
  for (int i = 0; i < 4; i++)
    tile[ty + 8 * i][tx] = W[(size_t)(k0 + ty + 8 * i) * Nn + n0 + tx];
  __syncthreads();
#pragma unroll
  for (int i = 0; i < 4; i++)
    WT[(size_t)(n0 + ty + 8 * i) * K + k0 + tx] = f2b(tile[tx][ty + 8 * i]);
}

// ---------------- bf16 MFMA GEMM with K-tile register prefetch ----------------
__global__ __launch_bounds__(256) void gemm_bf16_kernel(
    const u16* __restrict__ A, const u16* __restrict__ BT,
    const float* __restrict__ bias, const float* __restrict__ resid,
    float* __restrict__ Cf, u16* __restrict__ Cb,
    int M, int N, int K, int act)
{
  __shared__ __attribute__((aligned(16))) u16 As[128 * 40];
  __shared__ __attribute__((aligned(16))) u16 Bs[128 * 40];
  int tid = threadIdx.x;
  int lane = tid & 63, wave = tid >> 6;
  int wr = wave >> 1, wc = wave & 1;
  int row0 = blockIdx.y * 128, col0 = blockIdx.x * 128;
  int l15 = lane & 15, l4 = lane >> 4;
  int sr = tid >> 2, skc = tid & 3;
  const u16* pA0 = A + (size_t)(row0 + sr) * K + skc * 8;
  const u16* pA1 = A + (size_t)(row0 + 64 + sr) * K + skc * 8;
  const u16* pB0 = BT + (size_t)(col0 + sr) * K + skc * 8;
  const u16* pB1 = BT + (size_t)(col0 + 64 + sr) * K + skc * 8;
  f32x4 acc[4][4] = {};
  bf16x8 a0 = *(const bf16x8*)pA0;
  bf16x8 a1 = *(const bf16x8*)pA1;
  bf16x8 b0 = *(const bf16x8*)pB0;
  bf16x8 b1 = *(const bf16x8*)pB1;
  for (int k0 = 0; k0 < K; k0 += 32) {
    __syncthreads();
    *(bf16x8*)&As[sr * 40 + skc * 8] = a0;
    *(bf16x8*)&As[(64 + sr) * 40 + skc * 8] = a1;
    *(bf16x8*)&Bs[sr * 40 + skc * 8] = b0;
    *(bf16x8*)&Bs[(64 + sr) * 40 + skc * 8] = b1;
    __syncthreads();
    if (k0 + 32 < K) {       // prefetch next K-tile; latency hides under MFMA below
      a0 = *(const bf16x8*)(pA0 + k0 + 32);
      a1 = *(const bf16x8*)(pA1 + k0 + 32);
      b0 = *(const bf16x8*)(pB0 + k0 + 32);
      b1 = *(const bf16x8*)(pB1 + k0 + 32);
    }
    bf16x8 af[4], bfr[4];
#pragma unroll
    for (int m = 0; m < 4; m++)
      af[m] = *(const bf16x8*)&As[(wr * 64 + m * 16 + l15) * 40 + l4 * 8];
#pragma unroll
    for (int n = 0; n < 4; n++)
      bfr[n] = *(const bf16x8*)&Bs[(wc * 64 + n * 16 + l15) * 40 + l4 * 8];
#pragma unroll
    for (int m = 0; m < 4; m++)
#pragma unroll
      for (int n = 0; n < 4; n++)
        acc[m][n] = __builtin_amdgcn_mfma_f32_16x16x32_bf16(af[m], bfr[n], acc[m][n], 0, 0, 0);
  }
#pragma unroll
  for (int m = 0; m < 4; m++) {
#pragma unroll
    for (int n = 0; n < 4; n++) {
      int col = col0 + wc * 64 + n * 16 + l15;
      float bv = bias ? bias[col] : 0.f;
#pragma unroll
      for (int r = 0; r < 4; r++) {
        int row = row0 + wr * 64 + m * 16 + l4 * 4 + r;
        float v = acc[m][n][r] + bv;
        if (act == 1) v = gelu_f(v);
        if (resid) v += resid[(size_t)row * N + col];
        if (Cf) Cf[(size_t)row * N + col] = v;
        if (Cb) Cb[(size_t)row * N + col] = f2b(v);
      }
    }
  }
}

// ---------------- V transpose: src rows -> Vt [b*8+h][64][n_rows] ----------------
__global__ __launch_bounds__(256) void vt_kernel(
    const u16* __restrict__ src, size_t b_stride, int row_stride, int col0,
    int n_rows, u16* __restrict__ dst)
{
  __shared__ __attribute__((aligned(16))) u16 tile[32][72];
  int t = threadIdx.x;
  int bh = blockIdx.y;
  int b = bh >> 3, h = bh & 7;
  int n0 = blockIdx.x * 32;
  int n = t >> 3, dc = t & 7;
  *(bf16x8*)&tile[n][dc * 8] =
      *(const bf16x8*)(src + (size_t)b * b_stride + (size_t)(n0 + n) * row_stride + col0 + h * 64 + dc * 8);
  __syncthreads();
  int d = t >> 2, ns = t & 3;
  bf16x8 o;
#pragma unroll
  for (int i = 0; i < 8; i++) o[i] = (short)tile[ns * 8 + i][d];
  *(bf16x8*)(dst + ((size_t)bh * 64 + d) * n_rows + n0 + ns * 8) = o;
}

// ---------------- MFMA flash attention: swapped QK^T, split-K 2-way, reg prefetch ----
// grid z = b + 4*split. Writes unnormalized fp32 partials (Opart, MLpart).
__global__ __launch_bounds__(256, 2) void attn_mfma_kernel(
    const u16* __restrict__ Q, size_t q_bs, int q_stride,
    const u16* __restrict__ Kp, size_t k_bs, int k_stride, int k_extra,
    const u16* __restrict__ Vt, const int* __restrict__ mask,
    float scale, float* __restrict__ Opart, float* __restrict__ MLpart,
    int n_keys)
{
  __shared__ __attribute__((aligned(16))) u16 Ks[64 * 72];
  __shared__ __attribute__((aligned(16))) u16 Vs[64 * 72];
  __shared__ __attribute__((aligned(16))) u16 Ps[4][16 * 72];
  __shared__ float mbias[64];
  int tid = threadIdx.x, lane = tid & 63, wave = tid >> 6;
  int z = blockIdx.z;
  int b = z & 3, split = z >> 2;
  int h = blockIdx.y, q0 = blockIdx.x * 64 + wave * 16;
  int l15 = lane & 15, l4 = lane >> 4;
  int nh = n_keys >> 1;
  int nstart = split * nh, nend = nstart + nh;

  const u16* qrow = Q + (size_t)b * q_bs + (size_t)(q0 + l15) * q_stride + h * 64 + l4 * 8;
  bf16x8 qf0 = *(const bf16x8*)qrow;
  bf16x8 qf1 = *(const bf16x8*)(qrow + 32);
  f32x4 o_acc[4] = {};
  float m_run = -3.0e38f, l_run = 0.f;
  int srow = tid >> 2, schunk = tid & 3;
  const u16* kbase = Kp + (size_t)b * k_bs + k_extra + h * 64;
  const u16* vtbase = Vt + (size_t)(b * 8 + h) * 64 * n_keys;

  // prefetch tile nstart
  bf16x8 pk0, pk1, pv0, pv1;
  int pmv = 1;
  {
    const u16* krow = kbase + (size_t)(nstart + srow) * k_stride;
    pk0 = *(const bf16x8*)(krow + schunk * 8);
    pk1 = *(const bf16x8*)(krow + (schunk + 4) * 8);
    const u16* vrow = vtbase + (size_t)srow * n_keys + nstart;
    pv0 = *(const bf16x8*)(vrow + schunk * 8);
    pv1 = *(const bf16x8*)(vrow + (schunk + 4) * 8);
    if (mask && tid < 64) pmv = mask[(size_t)b * n_keys + nstart + tid];
  }

  for (int n0 = nstart; n0 < nend; n0 += 64) {
    __syncthreads();
    *(bf16x8*)&Ks[srow * 72 + schunk * 8]       = pk0;
    *(bf16x8*)&Ks[srow * 72 + (schunk + 4) * 8] = pk1;
    *(bf16x8*)&Vs[srow * 72 + schunk * 8]       = pv0;
    *(bf16x8*)&Vs[srow * 72 + (schunk + 4) * 8] = pv1;
    if (tid < 64) mbias[tid] = (mask && !pmv) ? -3.0e38f : 0.f;
    __syncthreads();
    if (n0 + 64 < nend) {   // prefetch next tile; hides under the compute below
      const u16* krow = kbase + (size_t)(n0 + 64 + srow) * k_stride;
      pk0 = *(const bf16x8*)(krow + schunk * 8);
      pk1 = *(const bf16x8*)(krow + (schunk + 4) * 8);
      const u16* vrow = vtbase + (size_t)srow * n_keys + n0 + 64;
      pv0 = *(const bf16x8*)(vrow + schunk * 8);
      pv1 = *(const bf16x8*)(vrow + (schunk + 4) * 8);
      if (mask && tid < 64) pmv = mask[(size_t)b * n_keys + n0 + 64 + tid];
    }
    // swapped QK^T: query = l15, keys in regs
    f32x4 sac[4];
#pragma unroll
    for (int kb = 0; kb < 4; kb++) {
      bf16x8 kf0 = *(const bf16x8*)&Ks[(kb * 16 + l15) * 72 + l4 * 8];
      bf16x8 kf1 = *(const bf16x8*)&Ks[(kb * 16 + l15) * 72 + 32 + l4 * 8];
      f32x4 zz = {};
      zz = __builtin_amdgcn_mfma_f32_16x16x32_bf16(kf0, qf0, zz, 0, 0, 0);
      sac[kb] = __builtin_amdgcn_mfma_f32_16x16x32_bf16(kf1, qf1, zz, 0, 0, 0);
    }
    float sv[16];
    float pmax = -3.0e38f;
#pragma unroll
    for (int kb = 0; kb < 4; kb++) {
      float4 bs = *(const float4*)&mbias[kb * 16 + l4 * 4];
      sv[kb * 4 + 0] = fmaf(sac[kb][0], scale, bs.x);
      sv[kb * 4 + 1] = fmaf(sac[kb][1], scale, bs.y);
      sv[kb * 4 + 2] = fmaf(sac[kb][2], scale, bs.z);
      sv[kb * 4 + 3] = fmaf(sac[kb][3], scale, bs.w);
#pragma unroll
      for (int r = 0; r < 4; r++) pmax = fmaxf(pmax, sv[kb * 4 + r]);
    }
    pmax = fmaxf(pmax, __shfl_xor(pmax, 16));
    pmax = fmaxf(pmax, __shfl_xor(pmax, 32));
    if (!__all(pmax - m_run <= 8.f)) {
      float mnew = fmaxf(m_run, pmax);
      float al = __expf(m_run - mnew);
      l_run *= al;
      m_run = mnew;
      float alr[4];
#pragma unroll
      for (int r = 0; r < 4; r++) alr[r] = __shfl(al, l4 * 4 + r, 64);
#pragma unroll
      for (int nb = 0; nb < 4; nb++)
#pragma unroll
        for (int r = 0; r < 4; r++) o_acc[nb][r] *= alr[r];
    }
    float psum = 0.f;
    u16 pb[16];
#pragma unroll
    for (int i = 0; i < 16; i++) {
      float p = __expf(sv[i] - m_run);   // masked: exp(-huge) = 0
      psum += p;
      pb[i] = f2b(p);
    }
    psum += __shfl_xor(psum, 16);
    psum += __shfl_xor(psum, 32);
    l_run += psum;
#pragma unroll
    for (int kb = 0; kb < 4; kb++) {
      uint2 w;
      w.x = (unsigned int)pb[kb * 4 + 0] | ((unsigned int)pb[kb * 4 + 1] << 16);
      w.y = (unsigned int)pb[kb * 4 + 2] | ((unsigned int)pb[kb * 4 + 3] << 16);
      *(uint2*)&Ps[wave][l15 * 72 + kb * 16 + l4 * 4] = w;
    }
#pragma unroll
    for (int c = 0; c < 2; c++) {
      bf16x8 pf = *(const bf16x8*)&Ps[wave][l15 * 72 + c * 32 + l4 * 8];
#pragma unroll
      for (int nb = 0; nb < 4; nb++) {
        bf16x8 vf = *(const bf16x8*)&Vs[(nb * 16 + l15) * 72 + c * 32 + l4 * 8];
        o_acc[nb] = __builtin_amdgcn_mfma_f32_16x16x32_bf16(pf, vf, o_acc[nb], 0, 0, 0);
      }
    }
  }
  // write unnormalized partials
  int pr_base = ((split * 4 + b) * 8 + h) * 1024;
#pragma unroll
  for (int nb = 0; nb < 4; nb++)
#pragma unroll
    for (int r = 0; r < 4; r++)
      Opart[(size_t)(pr_base + q0 + l4 * 4 + r) * 64 + nb * 16 + l15] = o_acc[nb][r];
  if (lane < 16) {
    int pr = pr_base + q0 + lane;
    MLpart[2 * pr]     = m_run;
    MLpart[2 * pr + 1] = l_run;
  }
}

// ---------------- combine the 2 split-K partials ----------------
__global__ __launch_bounds__(256) void attn_combine_kernel(
    const float* __restrict__ Opart, const float* __restrict__ MLpart,
    u16* __restrict__ O, size_t o_bs)
{
  int idx = blockIdx.x * 256 + threadIdx.x;   // 4*8*1024*64 = 2097152 threads
  int d = idx & 63, gq = idx >> 6;
  int row = gq & 1023, bh = gq >> 10;
  int h = bh & 7, b = bh >> 3;
  float m0 = MLpart[2 * gq], l0 = MLpart[2 * gq + 1];
  float m1 = MLpart[2 * (32768 + gq)], l1 = MLpart[2 * (32768 + gq) + 1];
  float mmax = fmaxf(m0, m1);
  float w0 = __expf(m0 - mmax), w1 = __expf(m1 - mmax);
  float l = l0 * w0 + l1 * w1;
  float o = Opart[(size_t)gq * 64 + d] * w0 + Opart[(size_t)(32768 + gq) * 64 + d] * w1;
  O[(size_t)b * o_bs + (size_t)row * 512 + h * 64 + d] = f2b(o / l);
}

// ---------------- gather rows by VQ index (fp32) ----------------
__global__ __launch_bounds__(128) void gather_kernel(
    const float* __restrict__ x2, const int* __restrict__ idx, float* __restrict__ out)
{
  int t = blockIdx.x;
  int b = t >> 11;
  int code = idx[t];
  const float4* src = (const float4*)(x2 + ((size_t)(b * M_ + code) << 9));
  float4* dst = (float4*)(out + ((size_t)t << 9));
  dst[threadIdx.x] = src[threadIdx.x];
}

// ---------------- scalars ----------------
__global__ void scalars_kernel(const float* __restrict__ counts,
                               const double* __restrict__ commit_partial,
                               float* __restrict__ out_tail)
{
  int tid = threadIdx.x;   // 1024
  double cs = 0.0;
#pragma unroll
  for (int i = 0; i < 8; i++) cs += commit_partial[tid + i * 1024];
  double p = (double)counts[tid] / 8192.0;
  double e = p * log(p + 1e-10);
  for (int off = 32; off; off >>= 1) {
    cs += __shfl_down(cs, off);
    e  += __shfl_down(e, off);
  }
  __shared__ double redc[16], rede[16];
  if ((tid & 63) == 0) { redc[tid >> 6] = cs; rede[tid >> 6] = e; }
  __syncthreads();
  if (tid == 0) {
    double sc = 0.0, se = 0.0;
    for (int i = 0; i < 16; i++) { sc += redc[i]; se += rede[i]; }
    out_tail[0] = (float)(sc / (8192.0 * 512.0));
    out_tail[1] = (float)exp(-se);
  }
}

extern "C" void kernel_launch(void* const* d_in, const int* in_sizes, int n_in,
                              void* d_out, int out_size, void* d_ws, size_t ws_size,
                              hipStream_t stream) {
  const float* ctx      = (const float*)d_in[0];
  const void*  mask_raw = d_in[1];
  const float* codebook = (const float*)d_in[2];
  const float* norm_g   = (const float*)d_in[3];
  const float* norm_b   = (const float*)d_in[4];
  const float* cnorm_g  = (const float*)d_in[5];
  const float* cnorm_b  = (const float*)d_in[6];
  const float* wq       = (const float*)d_in[7];
  const float* wkv      = (const float*)d_in[8];
  const float* wo       = (const float*)d_in[9];
  const float* wo_b     = (const float*)d_in[10];
  const float* a_norm_g = (const float*)d_in[11];
  const float* a_norm_b = (const float*)d_in[12];
  const float* a_qkv    = (const float*)d_in[13];
  const float* a_out    = (const float*)d_in[14];
  const float* f_norm_g = (const float*)d_in[15];
  const float* f_norm_b = (const float*)d_in[16];
  const float* f_w1     = (const float*)d_in[17];
  const float* f_w2     = (const float*)d_in[18];
  float* out = (float*)d_out;

  char* ws = (char*)d_ws;
  int*    mask_flag  = (int*)(ws + 64);
  float*  counts     = (float*)(ws + 128);
  double* code_sq    = (double*)(ws + 128 + 4096);
  float*  csqf       = (float*)(ws + 128 + 4096 + 8192);
  int*    indices    = (int*)(ws + 128 + 4096 + 8192 + 4096);
  int*    mask_norm  = (int*)(ws + 128 + 4096 + 8192 + 4096 + 32768);
  int2*   cand       = (int2*)(ws + 128 + 4096 + 8192 + 4096 + 32768 + 32768);
  double* commit_partial = (double*)(ws + 128 + 4096 + 8192 + 4096 + 32768 + 32768 + 65536);
  float*  attn_ml    = (float*)(ws + 262144);       // 512 KB (2*32768*2 f32)

  char* pool = ws + (1 << 20);
  u16*   vqA  = (u16*)(pool);
  u16*   vqBT = (u16*)(pool + ((size_t)26 << 20));
  float* vqS  = (float*)(pool + ((size_t)30 << 20));
  char* regA  = pool;
  char* regB  = pool + ((size_t)16 << 20);
  char* regC  = pool + ((size_t)24 << 20);
  char* regD  = pool + ((size_t)32 << 20);
  char* regE  = pool + ((size_t)40 << 20);
  char* regF  = pool + ((size_t)44 << 20);
  size_t woff = (1 << 20) + ((size_t)64 << 20);
  u16* wqT    = (u16*)(ws + woff); woff += (size_t)512 * 512 * 2;
  u16* wkvT   = (u16*)(ws + woff); woff += (size_t)1024 * 512 * 2;
  u16* woT    = (u16*)(ws + woff); woff += (size_t)512 * 512 * 2;
  u16* aqkvT  = (u16*)(ws + woff); woff += (size_t)1536 * 512 * 2;
  u16* aoutT  = (u16*)(ws + woff); woff += (size_t)512 * 512 * 2;
  u16* fw1T   = (u16*)(ws + woff); woff += (size_t)1024 * 512 * 2;
  u16* fw2T   = (u16*)(ws + woff); woff += (size_t)512 * 1024 * 2;
  u16* xq_b   = (u16*)(ws + woff); woff += (size_t)1024 * 512 * 2;
  u16* qs_b   = (u16*)(ws + woff); woff += (size_t)1024 * 512 * 2;

  u16* kv_b     = (u16*)regA;
  u16* qkv2_b   = (u16*)regA;
  u16* ctx_ln_b = (u16*)regB;
  u16* VtS      = (u16*)regB;
  u16* VtX      = (u16*)regC;
  float* x1_f   = (float*)regC;
  float* x0_f   = (float*)regD;
  u16* att_out_b = (u16*)regE;
  u16* h_b       = (u16*)regE;
  u16* o2_b      = (u16*)regE;
  u16* hf_b      = (u16*)regE;
  u16* g_b      = (u16*)regF;
  float* x2_f   = (float*)(pool + ((size_t)52 << 20));
  float* attn_part = (float*)regF;   // 16 MB (regF+regG region, free during both attns)

  // ---- VQ ----
  zero_init_kernel<<<1, 1024, 0, stream>>>(counts);
  mask_detect_kernel<<<1, 256, 0, stream>>>((const unsigned char*)mask_raw, mask_flag);
  mask_norm_kernel<<<32, 256, 0, stream>>>(mask_raw, mask_flag, mask_norm);
  code_sq_kernel<<<1024, 128, 0, stream>>>(codebook, code_sq, csqf);
  vq_split_x_kernel<<<8192, 256, 0, stream>>>(ctx, vqA);
  vq_split_c_kernel<<<1024, 256, 0, stream>>>(codebook, vqBT);
  gemm_bf16_kernel<<<dim3(8, 64), 256, 0, stream>>>(vqA, vqBT, nullptr, nullptr,
                                                    vqS, nullptr, 8192, 1024, 1536, 0);
  vq_top2_kernel<<<8192, 256, 0, stream>>>(vqS, csqf, cand);
  vq_refine_kernel<<<2048, 256, 0, stream>>>(ctx, codebook, code_sq, cand, indices);
  commit_hist_kernel<<<8192, 128, 0, stream>>>(ctx, codebook, indices, commit_partial, counts);

  // ---- weight conversion ----
  WJobs jobs;
  jobs.src[0] = wq;    jobs.dst[0] = wqT;   jobs.K[0] = 512;  jobs.N[0] = 512;
  jobs.src[1] = wkv;   jobs.dst[1] = wkvT;  jobs.K[1] = 512;  jobs.N[1] = 1024;
  jobs.src[2] = wo;    jobs.dst[2] = woT;   jobs.K[2] = 512;  jobs.N[2] = 512;
  jobs.src[3] = a_qkv; jobs.dst[3] = aqkvT; jobs.K[3] = 512;  jobs.N[3] = 1536;
  jobs.src[4] = a_out; jobs.dst[4] = aoutT; jobs.K[4] = 512;  jobs.N[4] = 512;
  jobs.src[5] = f_w1;  jobs.dst[5] = fw1T;  jobs.K[5] = 512;  jobs.N[5] = 1024;
  jobs.src[6] = f_w2;  jobs.dst[6] = fw2T;  jobs.K[6] = 1024; jobs.N[6] = 512;
  int acc_b = 0;
  for (int i = 0; i < 7; i++) {
    jobs.b0[i] = acc_b;
    acc_b += (jobs.K[i] >> 5) * (jobs.N[i] >> 5);
  }
  jobs.b0[7] = acc_b;
  wconv_all_kernel<<<acc_b, 256, 0, stream>>>(jobs);

  // ---- Cross-attention ----
  ln_rows_kernel<<<1024, 256, 0, stream>>>(codebook, norm_g, norm_b, xq_b);
  gemm_bf16_kernel<<<dim3(4, 8), 256, 0, stream>>>(xq_b, wqT, nullptr, nullptr,
                                                   nullptr, qs_b, 1024, 512, 512, 0);
  ln_rows_kernel<<<8192, 256, 0, stream>>>(ctx, cnorm_g, cnorm_b, ctx_ln_b);
  gemm_bf16_kernel<<<dim3(8, 64), 256, 0, stream>>>(ctx_ln_b, wkvT, nullptr, nullptr,
                                                    nullptr, kv_b, 8192, 1024, 512, 0);
  vt_kernel<<<dim3(64, 32), 256, 0, stream>>>(kv_b, (size_t)2048 * 1024, 1024, 512, 2048, VtX);
  attn_mfma_kernel<<<dim3(16, 8, 8), 256, 0, stream>>>(
      qs_b, 0, 512, kv_b, (size_t)2048 * 1024, 1024, 0, VtX, mask_norm,
      0.125f, attn_part, attn_ml, 2048);
  attn_combine_kernel<<<8192, 256, 0, stream>>>(attn_part, attn_ml, att_out_b, (size_t)1024 * 512);
  gemm_bf16_kernel<<<dim3(4, 32), 256, 0, stream>>>(att_out_b, woT, wo_b, nullptr,
                                                    x0_f, nullptr, 4096, 512, 512, 0);

  // ---- Transformer refinement ----
  ln_rows_kernel<<<4096, 256, 0, stream>>>(x0_f, a_norm_g, a_norm_b, h_b);
  gemm_bf16_kernel<<<dim3(12, 32), 256, 0, stream>>>(h_b, aqkvT, nullptr, nullptr,
                                                     nullptr, qkv2_b, 4096, 1536, 512, 0);
  vt_kernel<<<dim3(32, 32), 256, 0, stream>>>(qkv2_b, (size_t)1024 * 1536, 1536, 1024, 1024, VtS);
  attn_mfma_kernel<<<dim3(16, 8, 8), 256, 0, stream>>>(
      qkv2_b, (size_t)1024 * 1536, 1536, qkv2_b, (size_t)1024 * 1536, 1536, 512, VtS, nullptr,
      0.125f, attn_part, attn_ml, 1024);
  attn_combine_kernel<<<8192, 256, 0, stream>>>(attn_part, attn_ml, o2_b, (size_t)1024 * 512);
  gemm_bf16_kernel<<<dim3(4, 32), 256, 0, stream>>>(o2_b, aoutT, nullptr, x0_f,
                                                    x1_f, nullptr, 4096, 512, 512, 0);
  ln_rows_kernel<<<4096, 256, 0, stream>>>(x1_f, f_norm_g, f_norm_b, hf_b);
  gemm_bf16_kernel<<<dim3(8, 32), 256, 0, stream>>>(hf_b, fw1T, nullptr, nullptr,
                                                    nullptr, g_b, 4096, 1024, 512, 1);
  gemm_bf16_kernel<<<dim3(4, 32), 256, 0, stream>>>(g_b, fw2T, nullptr, x1_f,
                                                    x2_f, nullptr, 4096, 512, 1024, 0);

  // ---- Gather + scalars ----
  gather_kernel<<<8192, 128, 0, stream>>>(x2_f, indices, out);
  scalars_kernel<<<1, 1024, 0, stream>>>(counts, commit_partial, out + (size_t)B_ * N_ * D_);
}

// Round 8
// 373.301 us; speedup vs baseline: 6.1699x; 1.0191x over previous
//
#include <hip/hip_runtime.h>
#include <math.h>

#define B_ 4
#define N_ 2048
#define D_ 512
#define M_ 1024
#define H_ 8
#define DH_ 64
#define I_ 512
#define FF_ 1024

typedef unsigned short u16;
typedef __attribute__((ext_vector_type(8))) short bf16x8;
typedef __attribute__((ext_vector_type(4))) float f32x4;

__device__ inline u16 f2b(float f) {           // fp32 -> bf16 RNE
  union { float f; unsigned int u; } v; v.f = f;
  unsigned int u = v.u;
  u += 0x7fffu + ((u >> 16) & 1u);
  return (u16)(u >> 16);
}
__device__ inline float b2f(u16 h) {
  union { unsigned int u; float f; } v; v.u = ((unsigned int)h) << 16;
  return v.f;
}

__device__ inline float gelu_f(float x) {
  float x3 = x * x * x;
  return 0.5f * x * (1.f + tanhf(0.7978845608028654f * (x + 0.044715f * x3)));
}

// ---------------- zero accumulators ----------------
__global__ void zero_init_kernel(float* counts) {
  counts[threadIdx.x] = 0.f;
}

// ---------------- mask dtype detection / normalize ----------------
__global__ void mask_detect_kernel(const unsigned char* __restrict__ mb, int* flag) {
  __shared__ int any;
  if (threadIdx.x == 0) any = 0;
  __syncthreads();
  int acc = 0;
  for (int i = threadIdx.x; i < 8192; i += 256)
    if (i & 3) acc |= mb[i];
  if (acc) atomicOr(&any, 1);
  __syncthreads();
  if (threadIdx.x == 0) *flag = any;
}

__global__ void mask_norm_kernel(const void* __restrict__ mraw,
                                 const int* __restrict__ flag,
                                 int* __restrict__ mnorm) {
  int i = blockIdx.x * 256 + threadIdx.x;
  int v;
  if (*flag) v = ((const unsigned char*)mraw)[i];
  else       v = ((const int*)mraw)[i];
  mnorm[i] = (v != 0) ? 1 : 0;
}

// ---------------- codebook row sum-of-squares (fp64 + fp32 copy) ----------------
__global__ __launch_bounds__(128) void code_sq_kernel(const float* __restrict__ cb,
                                                      double* __restrict__ csq,
                                                      float* __restrict__ csqf) {
  int row = blockIdx.x, tid = threadIdx.x;
  const float4* r4 = (const float4*)(cb + (size_t)row * D_);
  float4 v = r4[tid];
  double s = (double)v.x * v.x + (double)v.y * v.y + (double)v.z * v.z + (double)v.w * v.w;
  for (int off = 32; off; off >>= 1) s += __shfl_down(s, off);
  __shared__ double red[2];
  if ((tid & 63) == 0) red[tid >> 6] = s;
  __syncthreads();
  if (tid == 0) { csq[row] = red[0] + red[1]; csqf[row] = (float)(red[0] + red[1]); }
}

// ---------------- VQ: hi/lo split builders ----------------
__global__ __launch_bounds__(256) void vq_split_x_kernel(
    const float* __restrict__ flat, u16* __restrict__ A)
{
  int t = blockIdx.x;
  const float* xr = flat + ((size_t)t << 9);
  u16* ar = A + (size_t)t * 1536;
#pragma unroll
  for (int i = 0; i < 2; i++) {
    int j = threadIdx.x + i * 256;
    float x = xr[j];
    u16 h = f2b(x);
    u16 l = f2b(x - b2f(h));
    ar[j] = h; ar[512 + j] = l; ar[1024 + j] = h;
  }
}
__global__ __launch_bounds__(256) void vq_split_c_kernel(
    const float* __restrict__ cb, u16* __restrict__ BT)
{
  int c = blockIdx.x;
  const float* cr = cb + ((size_t)c << 9);
  u16* br = BT + (size_t)c * 1536;
#pragma unroll
  for (int i = 0; i < 2; i++) {
    int j = threadIdx.x + i * 256;
    float x = cr[j];
    u16 h = f2b(x);
    u16 l = f2b(x - b2f(h));
    br[j] = h; br[512 + j] = h; br[1024 + j] = l;
  }
}

// ---------------- VQ: per-token top-2 over S row ----------------
__device__ inline bool better(float d1, int i1, float d2, int i2) {
  return d1 < d2 || (d1 == d2 && i1 < i2);
}

__global__ __launch_bounds__(256) void vq_top2_kernel(
    const float* __restrict__ S, const float* __restrict__ csqf,
    int2* __restrict__ cand)
{
  int t = blockIdx.x, tid = threadIdx.x;
  float4 sv = ((const float4*)(S + ((size_t)t << 10)))[tid];
  float4 cq = ((const float4*)csqf)[tid];
  int c0 = tid << 2;
  float b1, b2; int i1, i2;
  b1 = cq.x - 2.f * sv.x; i1 = c0;
  b2 = 1e30f; i2 = 1 << 20;
  {
    float d; int c;
    d = cq.y - 2.f * sv.y; c = c0 + 1;
    if (better(d, c, b1, i1)) { b2 = b1; i2 = i1; b1 = d; i1 = c; }
    else if (better(d, c, b2, i2)) { b2 = d; i2 = c; }
    d = cq.z - 2.f * sv.z; c = c0 + 2;
    if (better(d, c, b1, i1)) { b2 = b1; i2 = i1; b1 = d; i1 = c; }
    else if (better(d, c, b2, i2)) { b2 = d; i2 = c; }
    d = cq.w - 2.f * sv.w; c = c0 + 3;
    if (better(d, c, b1, i1)) { b2 = b1; i2 = i1; b1 = d; i1 = c; }
    else if (better(d, c, b2, i2)) { b2 = d; i2 = c; }
  }
  for (int off = 1; off < 64; off <<= 1) {
    float ob1 = __shfl_xor(b1, off), ob2 = __shfl_xor(b2, off);
    int   oi1 = __shfl_xor(i1, off), oi2 = __shfl_xor(i2, off);
    if (better(b1, i1, ob1, oi1)) {
      if (better(ob1, oi1, b2, i2)) { b2 = ob1; i2 = oi1; }
    } else {
      float nb2; int ni2;
      if (better(b1, i1, ob2, oi2)) { nb2 = b1; ni2 = i1; }
      else                          { nb2 = ob2; ni2 = oi2; }
      b1 = ob1; i1 = oi1; b2 = nb2; i2 = ni2;
    }
  }
  __shared__ float wb1[4], wb2[4];
  __shared__ int   wi1[4], wi2[4];
  if ((tid & 63) == 0) {
    int w = tid >> 6;
    wb1[w] = b1; wb2[w] = b2; wi1[w] = i1; wi2[w] = i2;
  }
  __syncthreads();
  if (tid == 0) {
    float B1 = wb1[0], B2 = wb2[0]; int I1 = wi1[0], I2 = wi2[0];
#pragma unroll
    for (int w = 1; w < 4; w++) {
      if (better(wb1[w], wi1[w], B1, I1)) {
        float nb2; int ni2;
        if (better(B1, I1, wb2[w], wi2[w])) { nb2 = B1; ni2 = I1; }
        else                                { nb2 = wb2[w]; ni2 = wi2[w]; }
        B1 = wb1[w]; I1 = wi1[w]; B2 = nb2; I2 = ni2;
      } else if (better(wb1[w], wi1[w], B2, I2)) {
        B2 = wb1[w]; I2 = wi1[w];
      }
    }
    cand[t] = make_int2(I1, I2);
  }
}

// ---------------- VQ: exact fp64 refine (4 tokens/block, 1 per wave) ----------------
__global__ __launch_bounds__(256) void vq_refine_kernel(
    const float* __restrict__ flat, const float* __restrict__ cb,
    const double* __restrict__ csq, const int2* __restrict__ cand,
    int* __restrict__ out_idx)
{
  int wave = threadIdx.x >> 6, lane = threadIdx.x & 63;
  int t = blockIdx.x * 4 + wave;
  int2 c = cand[t];
  const float* x = flat + ((size_t)t << 9);
  const float* c1 = cb + ((size_t)c.x << 9);
  const float* c2 = cb + ((size_t)c.y << 9);
  double s1 = 0.0, s2 = 0.0;
#pragma unroll
  for (int i = 0; i < 8; i++) {
    int d = lane + i * 64;
    double xv = x[d];
    s1 += xv * (double)c1[d];
    s2 += xv * (double)c2[d];
  }
  for (int off = 32; off; off >>= 1) { s1 += __shfl_down(s1, off); s2 += __shfl_down(s2, off); }
  if (lane == 0) {
    double d1 = csq[c.x] - 2.0 * s1;
    double d2 = csq[c.y] - 2.0 * s2;
    int bi = (d2 < d1 || (d2 == d1 && c.y < c.x)) ? c.y : c.x;
    out_idx[t] = bi;
  }
}

// ---------------- commit loss partials + histogram ----------------
__global__ __launch_bounds__(128) void commit_hist_kernel(
    const float* __restrict__ flat, const float* __restrict__ cb,
    const int* __restrict__ idx, double* __restrict__ commit_partial,
    float* __restrict__ counts)
{
  int t = blockIdx.x, tid = threadIdx.x;
  int code = idx[t];
  float4 a = ((const float4*)(flat + ((size_t)t << 9)))[tid];
  float4 c = ((const float4*)(cb + ((size_t)code << 9)))[tid];
  float dx = a.x - c.x, dy = a.y - c.y, dz = a.z - c.z, dw = a.w - c.w;
  double s = (double)dx * dx + (double)dy * dy + (double)dz * dz + (double)dw * dw;
  for (int off = 32; off; off >>= 1) s += __shfl_down(s, off);
  __shared__ double red[2];
  if ((tid & 63) == 0) red[tid >> 6] = s;
  __syncthreads();
  if (tid == 0) {
    commit_partial[t] = red[0] + red[1];
    atomicAdd(counts + code, 1.0f);
  }
}

// ---------------- LayerNorm (fp32 in -> bf16 out) ----------------
__global__ __launch_bounds__(256) void ln_rows_kernel(
    const float* __restrict__ x, const float* __restrict__ g,
    const float* __restrict__ b, u16* __restrict__ y)
{
  int row = blockIdx.x, tid = threadIdx.x;
  const float* xr = x + (size_t)row * D_;
  float v0 = xr[tid], v1 = xr[tid + 256];
  float s = v0 + v1;
  for (int off = 32; off; off >>= 1) s += __shfl_down(s, off);
  __shared__ float red[4];
  __shared__ float bcast[2];
  if ((tid & 63) == 0) red[tid >> 6] = s;
  __syncthreads();
  if (tid == 0) bcast[0] = (red[0] + red[1] + red[2] + red[3]) * (1.f / 512.f);
  __syncthreads();
  float mu = bcast[0];
  float d0 = v0 - mu, d1 = v1 - mu;
  float q = d0 * d0 + d1 * d1;
  for (int off = 32; off; off >>= 1) q += __shfl_down(q, off);
  if ((tid & 63) == 0) red[tid >> 6] = q;
  __syncthreads();
  if (tid == 0) bcast[1] = rsqrtf((red[0] + red[1] + red[2] + red[3]) * (1.f / 512.f) + 1e-5f);
  __syncthreads();
  float rs = bcast[1];
  u16* yr = y + (size_t)row * D_;
  yr[tid]       = f2b(d0 * rs * g[tid] + b[tid]);
  yr[tid + 256] = f2b(d1 * rs * g[tid + 256] + b[tid + 256]);
}

// ---------------- fused weight conversion ----------------
struct WJobs {
  const float* src[7];
  u16* dst[7];
  int K[7], N[7], b0[8];
};

__global__ __launch_bounds__(256) void wconv_all_kernel(WJobs jobs) {
  __shared__ float tile[32][33];
  int bid = blockIdx.x;
  int j = 0;
#pragma unroll
  for (int i = 1; i < 7; i++) if (bid >= jobs.b0[i]) j = i;
  int tb = bid - jobs.b0[j];
  int K = jobs.K[j], Nn = jobs.N[j];
  int tiles_x = Nn >> 5;
  int n0 = (tb % tiles_x) << 5, k0 = (tb / tiles_x) << 5;
  const float* W = jobs.src[j];
  u16* WT = jobs.dst[j];
  int t = threadIdx.x;
  int ty = t >> 5, tx = t & 31;
#pragma unroll
  for (int i = 0; i < 4; i++)
    tile[ty + 8 * i][tx] = W[(size_t)(k0 + ty + 8 * i) * Nn + n0 + tx];
  __syncthreads();
#pragma unroll
  for (int i = 0; i < 4; i++)
    WT[(size_t)(n0 + ty + 8 * i) * K + k0 + tx] = f2b(tile[tx][ty + 8 * i]);
}

// ---------------- bf16 MFMA GEMM: XCD-chunked swizzle + K-tile reg prefetch ----------
__global__ __launch_bounds__(256) void gemm_bf16_kernel(
    const u16* __restrict__ A, const u16* __restrict__ BT,
    const float* __restrict__ bias, const float* __restrict__ resid,
    float* __restrict__ Cf, u16* __restrict__ Cb,
    int M, int N, int K, int act)
{
  __shared__ __attribute__((aligned(16))) u16 As[128 * 40];
  __shared__ __attribute__((aligned(16))) u16 Bs[128 * 40];
  int tid = threadIdx.x;
  int lane = tid & 63, wave = tid >> 6;
  int wr = wave >> 1, wc = wave & 1;
  // XCD-chunked bijective block swizzle: hw id i -> XCD i%8; give each XCD a
  // contiguous output chunk so row-panels/BT stay in its private L2.
  int nwgx = gridDim.x;
  int nwg = nwgx * gridDim.y;
  int flat = blockIdx.y * nwgx + blockIdx.x;
  if ((nwg & 7) == 0) flat = (flat & 7) * (nwg >> 3) + (flat >> 3);
  int row0 = (flat / nwgx) << 7, col0 = (flat % nwgx) << 7;
  int l15 = lane & 15, l4 = lane >> 4;
  int sr = tid >> 2, skc = tid & 3;
  const u16* pA0 = A + (size_t)(row0 + sr) * K + skc * 8;
  const u16* pA1 = A + (size_t)(row0 + 64 + sr) * K + skc * 8;
  const u16* pB0 = BT + (size_t)(col0 + sr) * K + skc * 8;
  const u16* pB1 = BT + (size_t)(col0 + 64 + sr) * K + skc * 8;
  f32x4 acc[4][4] = {};
  bf16x8 a0 = *(const bf16x8*)pA0;
  bf16x8 a1 = *(const bf16x8*)pA1;
  bf16x8 b0 = *(const bf16x8*)pB0;
  bf16x8 b1 = *(const bf16x8*)pB1;
  for (int k0 = 0; k0 < K; k0 += 32) {
    __syncthreads();
    *(bf16x8*)&As[sr * 40 + skc * 8] = a0;
    *(bf16x8*)&As[(64 + sr) * 40 + skc * 8] = a1;
    *(bf16x8*)&Bs[sr * 40 + skc * 8] = b0;
    *(bf16x8*)&Bs[(64 + sr) * 40 + skc * 8] = b1;
    __syncthreads();
    if (k0 + 32 < K) {
      a0 = *(const bf16x8*)(pA0 + k0 + 32);
      a1 = *(const bf16x8*)(pA1 + k0 + 32);
      b0 = *(const bf16x8*)(pB0 + k0 + 32);
      b1 = *(const bf16x8*)(pB1 + k0 + 32);
    }
    bf16x8 af[4], bfr[4];
#pragma unroll
    for (int m = 0; m < 4; m++)
      af[m] = *(const bf16x8*)&As[(wr * 64 + m * 16 + l15) * 40 + l4 * 8];
#pragma unroll
    for (int n = 0; n < 4; n++)
      bfr[n] = *(const bf16x8*)&Bs[(wc * 64 + n * 16 + l15) * 40 + l4 * 8];
#pragma unroll
    for (int m = 0; m < 4; m++)
#pragma unroll
      for (int n = 0; n < 4; n++)
        acc[m][n] = __builtin_amdgcn_mfma_f32_16x16x32_bf16(af[m], bfr[n], acc[m][n], 0, 0, 0);
  }
#pragma unroll
  for (int m = 0; m < 4; m++) {
#pragma unroll
    for (int n = 0; n < 4; n++) {
      int col = col0 + wc * 64 + n * 16 + l15;
      float bv = bias ? bias[col] : 0.f;
#pragma unroll
      for (int r = 0; r < 4; r++) {
        int row = row0 + wr * 64 + m * 16 + l4 * 4 + r;
        float v = acc[m][n][r] + bv;
        if (act == 1) v = gelu_f(v);
        if (resid) v += resid[(size_t)row * N + col];
        if (Cf) Cf[(size_t)row * N + col] = v;
        if (Cb) Cb[(size_t)row * N + col] = f2b(v);
      }
    }
  }
}

// ---------------- V transpose: src rows -> Vt [b*8+h][64][n_rows] ----------------
__global__ __launch_bounds__(256) void vt_kernel(
    const u16* __restrict__ src, size_t b_stride, int row_stride, int col0,
    int n_rows, u16* __restrict__ dst)
{
  __shared__ __attribute__((aligned(16))) u16 tile[32][72];
  int t = threadIdx.x;
  int bh = blockIdx.y;
  int b = bh >> 3, h = bh & 7;
  int n0 = blockIdx.x * 32;
  int n = t >> 3, dc = t & 7;
  *(bf16x8*)&tile[n][dc * 8] =
      *(const bf16x8*)(src + (size_t)b * b_stride + (size_t)(n0 + n) * row_stride + col0 + h * 64 + dc * 8);
  __syncthreads();
  int d = t >> 2, ns = t & 3;
  bf16x8 o;
#pragma unroll
  for (int i = 0; i < 8; i++) o[i] = (short)tile[ns * 8 + i][d];
  *(bf16x8*)(dst + ((size_t)bh * 64 + d) * n_rows + n0 + ns * 8) = o;
}

// ---------------- MFMA flash attention: swapped QK^T, split-K, XCD swizzle ----------
// grid (16, 8, 8): logical (q-block, head, z=b+4*split), XCD-chunk-swizzled.
__global__ __launch_bounds__(256, 2) void attn_mfma_kernel(
    const u16* __restrict__ Q, size_t q_bs, int q_stride,
    const u16* __restrict__ Kp, size_t k_bs, int k_stride, int k_extra,
    const u16* __restrict__ Vt, const int* __restrict__ mask,
    float scale, float* __restrict__ Opart, float* __restrict__ MLpart,
    int n_keys)
{
  __shared__ __attribute__((aligned(16))) u16 Ks[64 * 72];
  __shared__ __attribute__((aligned(16))) u16 Vs[64 * 72];
  __shared__ __attribute__((aligned(16))) u16 Ps[4][16 * 72];
  __shared__ float mbias[64];
  int tid = threadIdx.x, lane = tid & 63, wave = tid >> 6;
  // XCD swizzle: each XCD owns one z-slice (all q-blocks, all heads of one (b,split))
  int flat = blockIdx.x + (blockIdx.y << 4) + (blockIdx.z << 7);
  int swz = ((flat & 7) << 7) + (flat >> 3);
  int qb = swz & 15, h = (swz >> 4) & 7, z = swz >> 7;
  int b = z & 3, split = z >> 2;
  int q0 = qb * 64 + wave * 16;
  int l15 = lane & 15, l4 = lane >> 4;
  int nh = n_keys >> 1;
  int nstart = split * nh, nend = nstart + nh;

  const u16* qrow = Q + (size_t)b * q_bs + (size_t)(q0 + l15) * q_stride + h * 64 + l4 * 8;
  bf16x8 qf0 = *(const bf16x8*)qrow;
  bf16x8 qf1 = *(const bf16x8*)(qrow + 32);
  f32x4 o_acc[4] = {};
  float m_run = -3.0e38f, l_run = 0.f;
  int srow = tid >> 2, schunk = tid & 3;
  const u16* kbase = Kp + (size_t)b * k_bs + k_extra + h * 64;
  const u16* vtbase = Vt + (size_t)(b * 8 + h) * 64 * n_keys;

  bf16x8 pk0, pk1, pv0, pv1;
  int pmv = 1;
  {
    const u16* krow = kbase + (size_t)(nstart + srow) * k_stride;
    pk0 = *(const bf16x8*)(krow + schunk * 8);
    pk1 = *(const bf16x8*)(krow + (schunk + 4) * 8);
    const u16* vrow = vtbase + (size_t)srow * n_keys + nstart;
    pv0 = *(const bf16x8*)(vrow + schunk * 8);
    pv1 = *(const bf16x8*)(vrow + (schunk + 4) * 8);
    if (mask && tid < 64) pmv = mask[(size_t)b * n_keys + nstart + tid];
  }

  for (int n0 = nstart; n0 < nend; n0 += 64) {
    __syncthreads();
    *(bf16x8*)&Ks[srow * 72 + schunk * 8]       = pk0;
    *(bf16x8*)&Ks[srow * 72 + (schunk + 4) * 8] = pk1;
    *(bf16x8*)&Vs[srow * 72 + schunk * 8]       = pv0;
    *(bf16x8*)&Vs[srow * 72 + (schunk + 4) * 8] = pv1;
    if (tid < 64) mbias[tid] = (mask && !pmv) ? -3.0e38f : 0.f;
    __syncthreads();
    if (n0 + 64 < nend) {
      const u16* krow = kbase + (size_t)(n0 + 64 + srow) * k_stride;
      pk0 = *(const bf16x8*)(krow + schunk * 8);
      pk1 = *(const bf16x8*)(krow + (schunk + 4) * 8);
      const u16* vrow = vtbase + (size_t)srow * n_keys + n0 + 64;
      pv0 = *(const bf16x8*)(vrow + schunk * 8);
      pv1 = *(const bf16x8*)(vrow + (schunk + 4) * 8);
      if (mask && tid < 64) pmv = mask[(size_t)b * n_keys + n0 + 64 + tid];
    }
    f32x4 sac[4];
#pragma unroll
    for (int kb = 0; kb < 4; kb++) {
      bf16x8 kf0 = *(const bf16x8*)&Ks[(kb * 16 + l15) * 72 + l4 * 8];
      bf16x8 kf1 = *(const bf16x8*)&Ks[(kb * 16 + l15) * 72 + 32 + l4 * 8];
      f32x4 zz = {};
      zz = __builtin_amdgcn_mfma_f32_16x16x32_bf16(kf0, qf0, zz, 0, 0, 0);
      sac[kb] = __builtin_amdgcn_mfma_f32_16x16x32_bf16(kf1, qf1, zz, 0, 0, 0);
    }
    float sv[16];
    float pmax = -3.0e38f;
#pragma unroll
    for (int kb = 0; kb < 4; kb++) {
      float4 bs = *(const float4*)&mbias[kb * 16 + l4 * 4];
      sv[kb * 4 + 0] = fmaf(sac[kb][0], scale, bs.x);
      sv[kb * 4 + 1] = fmaf(sac[kb][1], scale, bs.y);
      sv[kb * 4 + 2] = fmaf(sac[kb][2], scale, bs.z);
      sv[kb * 4 + 3] = fmaf(sac[kb][3], scale, bs.w);
#pragma unroll
      for (int r = 0; r < 4; r++) pmax = fmaxf(pmax, sv[kb * 4 + r]);
    }
    pmax = fmaxf(pmax, __shfl_xor(pmax, 16));
    pmax = fmaxf(pmax, __shfl_xor(pmax, 32));
    if (!__all(pmax - m_run <= 8.f)) {
      float mnew = fmaxf(m_run, pmax);
      float al = __expf(m_run - mnew);
      l_run *= al;
      m_run = mnew;
      float alr[4];
#pragma unroll
      for (int r = 0; r < 4; r++) alr[r] = __shfl(al, l4 * 4 + r, 64);
#pragma unroll
      for (int nb = 0; nb < 4; nb++)
#pragma unroll
        for (int r = 0; r < 4; r++) o_acc[nb][r] *= alr[r];
    }
    float psum = 0.f;
    u16 pb[16];
#pragma unroll
    for (int i = 0; i < 16; i++) {
      float p = __expf(sv[i] - m_run);
      psum += p;
      pb[i] = f2b(p);
    }
    psum += __shfl_xor(psum, 16);
    psum += __shfl_xor(psum, 32);
    l_run += psum;
#pragma unroll
    for (int kb = 0; kb < 4; kb++) {
      uint2 w;
      w.x = (unsigned int)pb[kb * 4 + 0] | ((unsigned int)pb[kb * 4 + 1] << 16);
      w.y = (unsigned int)pb[kb * 4 + 2] | ((unsigned int)pb[kb * 4 + 3] << 16);
      *(uint2*)&Ps[wave][l15 * 72 + kb * 16 + l4 * 4] = w;
    }
#pragma unroll
    for (int c = 0; c < 2; c++) {
      bf16x8 pf = *(const bf16x8*)&Ps[wave][l15 * 72 + c * 32 + l4 * 8];
#pragma unroll
      for (int nb = 0; nb < 4; nb++) {
        bf16x8 vf = *(const bf16x8*)&Vs[(nb * 16 + l15) * 72 + c * 32 + l4 * 8];
        o_acc[nb] = __builtin_amdgcn_mfma_f32_16x16x32_bf16(pf, vf, o_acc[nb], 0, 0, 0);
      }
    }
  }
  int pr_base = ((split * 4 + b) * 8 + h) * 1024;
#pragma unroll
  for (int nb = 0; nb < 4; nb++)
#pragma unroll
    for (int r = 0; r < 4; r++)
      Opart[(size_t)(pr_base + q0 + l4 * 4 + r) * 64 + nb * 16 + l15] = o_acc[nb][r];
  if (lane < 16) {
    int pr = pr_base + q0 + lane;
    MLpart[2 * pr]     = m_run;
    MLpart[2 * pr + 1] = l_run;
  }
}

// ---------------- combine the 2 split-K partials ----------------
__global__ __launch_bounds__(256) void attn_combine_kernel(
    const float* __restrict__ Opart, const float* __restrict__ MLpart,
    u16* __restrict__ O, size_t o_bs)
{
  int idx = blockIdx.x * 256 + threadIdx.x;
  int d = idx & 63, gq = idx >> 6;
  int row = gq & 1023, bh = gq >> 10;
  int h = bh & 7, b = bh >> 3;
  float m0 = MLpart[2 * gq], l0 = MLpart[2 * gq + 1];
  float m1 = MLpart[2 * (32768 + gq)], l1 = MLpart[2 * (32768 + gq) + 1];
  float mmax = fmaxf(m0, m1);
  float w0 = __expf(m0 - mmax), w1 = __expf(m1 - mmax);
  float l = l0 * w0 + l1 * w1;
  float o = Opart[(size_t)gq * 64 + d] * w0 + Opart[(size_t)(32768 + gq) * 64 + d] * w1;
  O[(size_t)b * o_bs + (size_t)row * 512 + h * 64 + d] = f2b(o / l);
}

// ---------------- gather rows by VQ index (fp32) ----------------
__global__ __launch_bounds__(128) void gather_kernel(
    const float* __restrict__ x2, const int* __restrict__ idx, float* __restrict__ out)
{
  int t = blockIdx.x;
  int b = t >> 11;
  int code = idx[t];
  const float4* src = (const float4*)(x2 + ((size_t)(b * M_ + code) << 9));
  float4* dst = (float4*)(out + ((size_t)t << 9));
  dst[threadIdx.x] = src[threadIdx.x];
}

// ---------------- scalars ----------------
__global__ void scalars_kernel(const float* __restrict__ counts,
                               const double* __restrict__ commit_partial,
                               float* __restrict__ out_tail)
{
  int tid = threadIdx.x;
  double cs = 0.0;
#pragma unroll
  for (int i = 0; i < 8; i++) cs += commit_partial[tid + i * 1024];
  double p = (double)counts[tid] / 8192.0;
  double e = p * log(p + 1e-10);
  for (int off = 32; off; off >>= 1) {
    cs += __shfl_down(cs, off);
    e  += __shfl_down(e, off);
  }
  __shared__ double redc[16], rede[16];
  if ((tid & 63) == 0) { redc[tid >> 6] = cs; rede[tid >> 6] = e; }
  __syncthreads();
  if (tid == 0) {
    double sc = 0.0, se = 0.0;
    for (int i = 0; i < 16; i++) { sc += redc[i]; se += rede[i]; }
    out_tail[0] = (float)(sc / (8192.0 * 512.0));
    out_tail[1] = (float)exp(-se);
  }
}

extern "C" void kernel_launch(void* const* d_in, const int* in_sizes, int n_in,
                              void* d_out, int out_size, void* d_ws, size_t ws_size,
                              hipStream_t stream) {
  const float* ctx      = (const float*)d_in[0];
  const void*  mask_raw = d_in[1];
  const float* codebook = (const float*)d_in[2];
  const float* norm_g   = (const float*)d_in[3];
  const float* norm_b   = (const float*)d_in[4];
  const float* cnorm_g  = (const float*)d_in[5];
  const float* cnorm_b  = (const float*)d_in[6];
  const float* wq       = (const float*)d_in[7];
  const float* wkv      = (const float*)d_in[8];
  const float* wo       = (const float*)d_in[9];
  const float* wo_b     = (const float*)d_in[10];
  const float* a_norm_g = (const float*)d_in[11];
  const float* a_norm_b = (const float*)d_in[12];
  const float* a_qkv    = (const float*)d_in[13];
  const float* a_out    = (const float*)d_in[14];
  const float* f_norm_g = (const float*)d_in[15];
  const float* f_norm_b = (const float*)d_in[16];
  const float* f_w1     = (const float*)d_in[17];
  const float* f_w2     = (const float*)d_in[18];
  float* out = (float*)d_out;

  char* ws = (char*)d_ws;
  int*    mask_flag  = (int*)(ws + 64);
  float*  counts     = (float*)(ws + 128);
  double* code_sq    = (double*)(ws + 128 + 4096);
  float*  csqf       = (float*)(ws + 128 + 4096 + 8192);
  int*    indices    = (int*)(ws + 128 + 4096 + 8192 + 4096);
  int*    mask_norm  = (int*)(ws + 128 + 4096 + 8192 + 4096 + 32768);
  int2*   cand       = (int2*)(ws + 128 + 4096 + 8192 + 4096 + 32768 + 32768);
  double* commit_partial = (double*)(ws + 128 + 4096 + 8192 + 4096 + 32768 + 32768 + 65536);
  float*  attn_ml    = (float*)(ws + 262144);

  char* pool = ws + (1 << 20);
  u16*   vqA  = (u16*)(pool);
  u16*   vqBT = (u16*)(pool + ((size_t)26 << 20));
  float* vqS  = (float*)(pool + ((size_t)30 << 20));
  char* regA  = pool;
  char* regB  = pool + ((size_t)16 << 20);
  char* regC  = pool + ((size_t)24 << 20);
  char* regD  = pool + ((size_t)32 << 20);
  char* regE  = pool + ((size_t)40 << 20);
  char* regF  = pool + ((size_t)44 << 20);
  size_t woff = (1 << 20) + ((size_t)64 << 20);
  u16* wqT    = (u16*)(ws + woff); woff += (size_t)512 * 512 * 2;
  u16* wkvT   = (u16*)(ws + woff); woff += (size_t)1024 * 512 * 2;
  u16* woT    = (u16*)(ws + woff); woff += (size_t)512 * 512 * 2;
  u16* aqkvT  = (u16*)(ws + woff); woff += (size_t)1536 * 512 * 2;
  u16* aoutT  = (u16*)(ws + woff); woff += (size_t)512 * 512 * 2;
  u16* fw1T   = (u16*)(ws + woff); woff += (size_t)1024 * 512 * 2;
  u16* fw2T   = (u16*)(ws + woff); woff += (size_t)512 * 1024 * 2;
  u16* xq_b   = (u16*)(ws + woff); woff += (size_t)1024 * 512 * 2;
  u16* qs_b   = (u16*)(ws + woff); woff += (size_t)1024 * 512 * 2;

  u16* kv_b     = (u16*)regA;
  u16* qkv2_b   = (u16*)regA;
  u16* ctx_ln_b = (u16*)regB;
  u16* VtS      = (u16*)regB;
  u16* VtX      = (u16*)regC;
  float* x1_f   = (float*)regC;
  float* x0_f   = (float*)regD;
  u16* att_out_b = (u16*)regE;
  u16* h_b       = (u16*)regE;
  u16* o2_b      = (u16*)regE;
  u16* hf_b      = (u16*)regE;
  u16* g_b      = (u16*)regF;
  float* x2_f   = (float*)(pool + ((size_t)52 << 20));
  float* attn_part = (float*)regF;

  // ---- VQ ----
  zero_init_kernel<<<1, 1024, 0, stream>>>(counts);
  mask_detect_kernel<<<1, 256, 0, stream>>>((const unsigned char*)mask_raw, mask_flag);
  mask_norm_kernel<<<32, 256, 0, stream>>>(mask_raw, mask_flag, mask_norm);
  code_sq_kernel<<<1024, 128, 0, stream>>>(codebook, code_sq, csqf);
  vq_split_x_kernel<<<8192, 256, 0, stream>>>(ctx, vqA);
  vq_split_c_kernel<<<1024, 256, 0, stream>>>(codebook, vqBT);
  gemm_bf16_kernel<<<dim3(8, 64), 256, 0, stream>>>(vqA, vqBT, nullptr, nullptr,
                                                    vqS, nullptr, 8192, 1024, 1536, 0);
  vq_top2_kernel<<<8192, 256, 0, stream>>>(vqS, csqf, cand);
  vq_refine_kernel<<<2048, 256, 0, stream>>>(ctx, codebook, code_sq, cand, indices);
  commit_hist_kernel<<<8192, 128, 0, stream>>>(ctx, codebook, indices, commit_partial, counts);

  // ---- weight conversion ----
  WJobs jobs;
  jobs.src[0] = wq;    jobs.dst[0] = wqT;   jobs.K[0] = 512;  jobs.N[0] = 512;
  jobs.src[1] = wkv;   jobs.dst[1] = wkvT;  jobs.K[1] = 512;  jobs.N[1] = 1024;
  jobs.src[2] = wo;    jobs.dst[2] = woT;   jobs.K[2] = 512;  jobs.N[2] = 512;
  jobs.src[3] = a_qkv; jobs.dst[3] = aqkvT; jobs.K[3] = 512;  jobs.N[3] = 1536;
  jobs.src[4] = a_out; jobs.dst[4] = aoutT; jobs.K[4] = 512;  jobs.N[4] = 512;
  jobs.src[5] = f_w1;  jobs.dst[5] = fw1T;  jobs.K[5] = 512;  jobs.N[5] = 1024;
  jobs.src[6] = f_w2;  jobs.dst[6] = fw2T;  jobs.K[6] = 1024; jobs.N[6] = 512;
  int acc_b = 0;
  for (int i = 0; i < 7; i++) {
    jobs.b0[i] = acc_b;
    acc_b += (jobs.K[i] >> 5) * (jobs.N[i] >> 5);
  }
  jobs.b0[7] = acc_b;
  wconv_all_kernel<<<acc_b, 256, 0, stream>>>(jobs);

  // ---- Cross-attention ----
  ln_rows_kernel<<<1024, 256, 0, stream>>>(codebook, norm_g, norm_b, xq_b);
  gemm_bf16_kernel<<<dim3(4, 8), 256, 0, stream>>>(xq_b, wqT, nullptr, nullptr,
                                                   nullptr, qs_b, 1024, 512, 512, 0);
  ln_rows_kernel<<<8192, 256, 0, stream>>>(ctx, cnorm_g, cnorm_b, ctx_ln_b);
  gemm_bf16_kernel<<<dim3(8, 64), 256, 0, stream>>>(ctx_ln_b, wkvT, nullptr, nullptr,
                                                    nullptr, kv_b, 8192, 1024, 512, 0);
  vt_kernel<<<dim3(64, 32), 256, 0, stream>>>(kv_b, (size_t)2048 * 1024, 1024, 512, 2048, VtX);
  attn_mfma_kernel<<<dim3(16, 8, 8), 256, 0, stream>>>(
      qs_b, 0, 512, kv_b, (size_t)2048 * 1024, 1024, 0, VtX, mask_norm,
      0.125f, attn_part, attn_ml, 2048);
  attn_combine_kernel<<<8192, 256, 0, stream>>>(attn_part, attn_ml, att_out_b, (size_t)1024 * 512);
  gemm_bf16_kernel<<<dim3(4, 32), 256, 0, stream>>>(att_out_b, woT, wo_b, nullptr,
                                                    x0_f, nullptr, 4096, 512, 512, 0);

  // ---- Transformer refinement ----
  ln_rows_kernel<<<4096, 256, 0, stream>>>(x0_f, a_norm_g, a_norm_b, h_b);
  gemm_bf16_kernel<<<dim3(12, 32), 256, 0, stream>>>(h_b, aqkvT, nullptr, nullptr,
                                                     nullptr, qkv2_b, 4096, 1536, 512, 0);
  vt_kernel<<<dim3(32, 32), 256, 0, stream>>>(qkv2_b, (size_t)1024 * 1536, 1536, 1024, 1024, VtS);
  attn_mfma_kernel<<<dim3(16, 8, 8), 256, 0, stream>>>(
      qkv2_b, (size_t)1024 * 1536, 1536, qkv2_b, (size_t)1024 * 1536, 1536, 512, VtS, nullptr,
      0.125f, attn_part, attn_ml, 1024);
  attn_combine_kernel<<<8192, 256, 0, stream>>>(attn_part, attn_ml, o2_b, (size_t)1024 * 512);
  gemm_bf16_kernel<<<dim3(4, 32), 256, 0, stream>>>(o2_b, aoutT, nullptr, x0_f,
                                                    x1_f, nullptr, 4096, 512, 512, 0);
  ln_rows_kernel<<<4096, 256, 0, stream>>>(x1_f, f_norm_g, f_norm_b, hf_b);
  gemm_bf16_kernel<<<dim3(8, 32), 256, 0, stream>>>(hf_b, fw1T, nullptr, nullptr,
                                                    nullptr, g_b, 4096, 1024, 512, 1);
  gemm_bf16_kernel<<<dim3(4, 32), 256, 0, stream>>>(g_b, fw2T, nullptr, x1_f,
                                                    x2_f, nullptr, 4096, 512, 1024, 0);

  // ---- Gather + scalars ----
  gather_kernel<<<8192, 128, 0, stream>>>(x2_f, indices, out);
  scalars_kernel<<<1, 1024, 0, stream>>>(counts, commit_partial, out + (size_t)B_ * N_ * D_);
}